// Round 10
// baseline (745.080 us; speedup 1.0000x reference)
//
#include <hip/hip_runtime.h>
#include <math.h>

// FineGrainedRetriever round 10: BM=128 / 512-thread GEMM blocks (8 waves as
// 2-row x 4-col grid). Per-thread regs unchanged (2x2 frags/wave) but W L2
// traffic halves and MFMA:barrier ratio doubles. Keeps round-9 W-preload-first
// vmcnt ordering + global_load_lds XOR-swizzled double-buffered staging.

namespace {
constexpr int E    = 200000;
constexpr int NV   = 50000;
constexpr int D    = 256;
constexpr int TWOE = 2 * E;
}

typedef __attribute__((ext_vector_type(8))) _Float16 f16x8;
typedef __attribute__((ext_vector_type(4))) _Float16 f16x4;
typedef __attribute__((ext_vector_type(16))) float f32x16;

#define MFMA16(a, b, c) __builtin_amdgcn_mfma_f32_32x32x16_f16((a), (b), (c), 0, 0, 0)

typedef const __attribute__((address_space(1))) void* gas_t;
typedef __attribute__((address_space(3))) void* las_t;

__device__ inline void gload16(const void* g, void* l) {
  __builtin_amdgcn_global_load_lds((gas_t)g, (las_t)l, 16, 0, 0);
}

// ---- edge_index dtype probe (int64 vs int32) -------------------------------
__global__ void k_detect(const void* ei_raw, int* flag) {
  __shared__ int bad;
  if (threadIdx.x == 0) bad = 0;
  __syncthreads();
  const long long* p = (const long long*)ei_raw;
  long long v = p[threadIdx.x];
  if (v < 0 || v >= (long long)NV) atomicOr(&bad, 1);
  __syncthreads();
  if (threadIdx.x == 0) *flag = bad ? 0 : 1;  // 1 => int64
}

__global__ void k_convert(const void* ei_raw, const int* __restrict__ flag,
                          int* __restrict__ ei32) {
  int i = blockIdx.x * 256 + threadIdx.x;
  if (i >= TWOE) return;
  if (*flag) ei32[i] = (int)((const long long*)ei_raw)[i];
  else       ei32[i] = ((const int*)ei_raw)[i];
}

// ---- CSR build -------------------------------------------------------------
__global__ void k_deg(const int* __restrict__ ei32, int* __restrict__ deg) {
  int de = blockIdx.x * 256 + threadIdx.x;
  if (de >= TWOE) return;
  int dst = (de < E) ? ei32[E + de] : ei32[de - E];
  atomicAdd(&deg[dst], 1);
}

__global__ __launch_bounds__(1024) void k_scan(const int* __restrict__ deg,
                                               int* __restrict__ off) {
  __shared__ int wsum[16];
  __shared__ int carryS;
  int tid = threadIdx.x;
  int lane = tid & 63, wv = tid >> 6;
  if (tid == 0) carryS = 0;
  __syncthreads();
  for (int base = 0; base < NV; base += 1024) {
    int i = base + tid;
    int v = (i < NV) ? deg[i] : 0;
    int s = v;
#pragma unroll
    for (int d = 1; d < 64; d <<= 1) {
      int t = __shfl_up(s, d);
      if (lane >= d) s += t;
    }
    if (lane == 63) wsum[wv] = s;
    int carry = carryS;
    __syncthreads();
    if (wv == 0) {
      int ws = (lane < 16) ? wsum[lane] : 0;
#pragma unroll
      for (int d = 1; d < 16; d <<= 1) {
        int t = __shfl_up(ws, d);
        if (lane >= d) ws += t;
      }
      if (lane < 16) wsum[lane] = ws;
    }
    __syncthreads();
    int wexcl = (wv == 0) ? 0 : wsum[wv - 1];
    if (i < NV) off[i] = carry + wexcl + s - v;
    if (tid == 1023) carryS = carry + wsum[15];
    __syncthreads();
  }
  if (tid == 0) off[NV] = carryS;
}

__global__ void k_fill(const int* __restrict__ ei32, const int* __restrict__ off,
                       int* __restrict__ cursor, int* __restrict__ eidA,
                       int* __restrict__ srcA) {
  int de = blockIdx.x * 256 + threadIdx.x;
  if (de >= TWOE) return;
  int dst = (de < E) ? ei32[E + de] : ei32[de - E];
  int p = atomicAdd(&cursor[dst], 1);
  int idx = off[dst] + p;
  eidA[idx] = de;
  srcA[idx] = ei32[de];
}

__global__ void k_rinv(const int* __restrict__ off, float* __restrict__ rinv) {
  int n = blockIdx.x * 256 + threadIdx.x;
  if (n < NV) {
    int d = off[n + 1] - off[n];
    rinv[n] = 1.f / fmaxf((float)d, 1.f);
  }
}

// ---- f32 -> f16 copy (8 elems/thread) --------------------------------------
__global__ void k_conv16(const float* __restrict__ x, _Float16* __restrict__ y,
                         int n8) {
  int i = blockIdx.x * 256 + threadIdx.x;
  if (i >= n8) return;
  const float4* p = (const float4*)x;
  float4 a = p[2 * i], b = p[2 * i + 1];
  f16x8 o;
  o[0] = (_Float16)a.x; o[1] = (_Float16)a.y; o[2] = (_Float16)a.z; o[3] = (_Float16)a.w;
  o[4] = (_Float16)b.x; o[5] = (_Float16)b.y; o[6] = (_Float16)b.z; o[7] = (_Float16)b.w;
  ((f16x8*)y)[i] = o;
}

// ---- gather: hsum[n] = sum fwd ea16 rows (f32); hid16 = sum rev; degrev ----
__global__ __launch_bounds__(256) void k_gath_h(
    const _Float16* __restrict__ ea16, const _Float16* __restrict__ tmp16,
    const int* __restrict__ eidA, const int* __restrict__ off,
    float* __restrict__ hsum, _Float16* __restrict__ hid16,
    float* __restrict__ degrev) {
  int n = blockIdx.x * 4 + (threadIdx.x >> 6);
  if (n >= NV) return;
  int l = threadIdx.x & 63;
  float4 fs = {0.f, 0.f, 0.f, 0.f}, hv = {0.f, 0.f, 0.f, 0.f};
  int o0 = off[n], o1 = off[n + 1];
  int dr = 0;
  for (int j = o0; j < o1; j++) {
    int de = eidA[j];
    if (de < E) {
      f16x4 v = ((const f16x4*)(ea16 + (size_t)de * D))[l];
      fs.x += (float)v[0]; fs.y += (float)v[1];
      fs.z += (float)v[2]; fs.w += (float)v[3];
    } else {
      f16x4 v = ((const f16x4*)(tmp16 + (size_t)(de - E) * D))[l];
      hv.x += (float)v[0]; hv.y += (float)v[1];
      hv.z += (float)v[2]; hv.w += (float)v[3];
      dr++;
    }
  }
  ((float4*)(hsum + (size_t)n * D))[l] = fs;
  f16x4 ho;
  ho[0] = (_Float16)hv.x; ho[1] = (_Float16)hv.y;
  ho[2] = (_Float16)hv.z; ho[3] = (_Float16)hv.w;
  ((f16x4*)(hid16 + (size_t)n * D))[l] = ho;
  if (l == 0) degrev[n] = (float)dr;
}

// ---- per-layer aggregate: agg16[n] = (sum_j x16[src_j] + hsum[n])*rinv[n] --
__global__ __launch_bounds__(256) void k_agg(
    const _Float16* __restrict__ x16, const int* __restrict__ srcA,
    const int* __restrict__ off, const float* __restrict__ hsum,
    const float* __restrict__ rinv, _Float16* __restrict__ agg16) {
  int n = blockIdx.x * 4 + (threadIdx.x >> 6);
  if (n >= NV) return;
  int l = threadIdx.x & 63;
  float4 s = ((const float4*)(hsum + (size_t)n * D))[l];
  int o0 = off[n], o1 = off[n + 1];
  for (int j = o0; j < o1; j++) {
    int src = srcA[j];
    f16x4 v = ((const f16x4*)(x16 + (size_t)src * D))[l];
    s.x += (float)v[0]; s.y += (float)v[1];
    s.z += (float)v[2]; s.w += (float)v[3];
  }
  float r = rinv[n];
  f16x4 o;
  o[0] = (_Float16)(s.x * r); o[1] = (_Float16)(s.y * r);
  o[2] = (_Float16)(s.z * r); o[3] = (_Float16)(s.w * r);
  ((f16x4*)(agg16 + (size_t)n * D))[l] = o;
}

// ---- weight prep: W[K][256] f32 -> Wf [K/8][256][8] f16 --------------------
__global__ __launch_bounds__(256) void k_wprep(const float* __restrict__ W,
                                               _Float16* __restrict__ Wf) {
  __shared__ float tl[32][260];
  int tid = threadIdx.x;
  int k0 = blockIdx.x * 32;
#pragma unroll
  for (int i = 0; i < 32; i++) tl[i][tid] = W[(size_t)(k0 + i) * 256 + tid];
  __syncthreads();
  f16x8* WfV = (f16x8*)Wf;
#pragma unroll
  for (int kg = 0; kg < 4; kg++) {
    f16x8 p;
#pragma unroll
    for (int j = 0; j < 8; j++) p[j] = (_Float16)tl[kg * 8 + j][tid];
    WfV[(size_t)((k0 >> 3) + kg) * 256 + tid] = p;
  }
}

// ---- qW[n] = q @ pred_W1[:256,n] + pred_b1[n] ------------------------------
__global__ void k_qw(const float* __restrict__ q, const float* __restrict__ W1,
                     const float* __restrict__ b1, float* __restrict__ qW) {
  __shared__ float ql[D];
  int n = threadIdx.x;
  ql[n] = q[n];
  __syncthreads();
  float s = b1[n];
  for (int k = 0; k < D; k++) s += ql[k] * W1[(size_t)k * D + n];
  qW[n] = s;
}

// ---- f16 MFMA GEMM, BM=128 / 512 threads, gload_lds, W-preload-first -------
enum AM { AF16, AF16D };
enum EP { EP_RELU16, EP_ADDC, EP_HE2, EP_PROJ2 };

// stage one 128x64 f16 K-step tile (16KB) into ldsbuf, source-XOR-swizzled
template<int AMODE>
__device__ inline void stageA(const _Float16* __restrict__ A0,
                              const _Float16* __restrict__ A1,
                              int m0, int t, int tid, _Float16* ldsbuf) {
  const _Float16* src;
  int kbase;
  if (AMODE == AF16D && t >= 4) { src = A1; kbase = (t - 4) * 64; }
  else                          { src = A0; kbase = t * 64; }
  const int l  = tid & 63;
  const int w  = tid >> 6;               // 0..7
  const int r8 = l >> 3;                 // row within 8-row chunk
  const int kg = (l & 7) ^ r8;           // swizzled source k-group (0..7)
#pragma unroll
  for (int j = 0; j < 2; j++) {
    const int c = w * 2 + j;             // chunk 0..15 (8 rows, 1KB each)
    const int row = c * 8 + r8;
    gload16(src + (size_t)(m0 + row) * 256 + kbase + kg * 8,
            ldsbuf + c * 512);           // wave-uniform LDS base, lane*16B
  }
}

template<int AMODE, int EPI>
__global__ __launch_bounds__(512, ((EPI == EP_HE2 || EPI == EP_PROJ2) ? 2 : 4))
void k_gemm(
    const _Float16* __restrict__ A0, const _Float16* __restrict__ A1,
    const float* __restrict__ addm, const float* __restrict__ rv,
    const _Float16* __restrict__ Wf, const _Float16* __restrict__ Wf2,
    const float* __restrict__ bias, const float* __restrict__ qW,
    float* __restrict__ outf, _Float16* __restrict__ o16a,
    _Float16* __restrict__ o16b, int M, int K) {
  constexpr bool DUAL = (EPI == EP_HE2 || EPI == EP_PROJ2);
  __shared__ _Float16 AS[2 * 8192];      // 32 KB double-buffered 128x64 A-tile
  const int tid = threadIdx.x;
  const int w = tid >> 6;                // wave 0..7
  const int wr = w >> 2;                 // wave row 0..1
  const int wc = w & 3;                  // wave col 0..3
  const int lane31 = tid & 31;
  const int hw = (tid >> 5) & 1;
  const int m0 = blockIdx.x * 128;
  const int col0 = (wc << 6) + lane31;
  const int col1 = col0 + 32;
  const int rbase = wr << 6;             // wave-local row base (0 or 64)

  f32x16 acc[2][2], acc2[2][2];
#pragma unroll
  for (int a = 0; a < 2; a++)
#pragma unroll
    for (int b = 0; b < 2; b++)
#pragma unroll
      for (int i = 0; i < 16; i++) { acc[a][b][i] = 0.f; acc2[a][b][i] = 0.f; }

  const f16x8* WV  = (const f16x8*)Wf;
  const f16x8* WV2 = (const f16x8*)Wf2;
  const int nt = K >> 6;
  const int sw = lane31 & 7;             // row&7 for both row frags

  stageA<AMODE>(A0, A1, m0, 0, tid, AS);
  __syncthreads();

  for (int t = 0; t < nt; ++t) {
    const int k0 = t * 64;
    // (1) preload ALL W-frags of this step FIRST (older VMEM than staging)
    f16x8 wb0[4], wb1[4], wc0[4], wc1[4];
#pragma unroll
    for (int ks = 0; ks < 4; ks++) {
      const int kgl = 2 * ks + hw;
      size_t wi = (size_t)((k0 >> 3) + kgl) * 256;
      wb0[ks] = WV[wi + col0];
      wb1[ks] = WV[wi + col1];
      if (DUAL) { wc0[ks] = WV2[wi + col0]; wc1[ks] = WV2[wi + col1]; }
    }
    __builtin_amdgcn_sched_barrier(0);
    // (2) issue next tile's staging (younger; drains only at step-end barrier)
    if (t + 1 < nt)
      stageA<AMODE>(A0, A1, m0, t + 1, tid, AS + ((t + 1) & 1) * 8192);
    __builtin_amdgcn_sched_barrier(0);
    // (3) MFMA burst on current buffer
    const f16x8* cb = (const f16x8*)(AS + (t & 1) * 8192);
#pragma unroll
    for (int ks = 0; ks < 4; ks++) {
      const int kgl = 2 * ks + hw;
      f16x8 a0 = cb[(rbase + lane31) * 8 + (kgl ^ sw)];
      f16x8 a1 = cb[(rbase + lane31 + 32) * 8 + (kgl ^ sw)];
      acc[0][0] = MFMA16(a0, wb0[ks], acc[0][0]);
      acc[0][1] = MFMA16(a0, wb1[ks], acc[0][1]);
      acc[1][0] = MFMA16(a1, wb0[ks], acc[1][0]);
      acc[1][1] = MFMA16(a1, wb1[ks], acc[1][1]);
      if (DUAL) {
        acc2[0][0] = MFMA16(a0, wc0[ks], acc2[0][0]);
        acc2[0][1] = MFMA16(a0, wc1[ks], acc2[0][1]);
        acc2[1][0] = MFMA16(a1, wc0[ks], acc2[1][0]);
        acc2[1][1] = MFMA16(a1, wc1[ks], acc2[1][1]);
      }
    }
    __syncthreads();
  }

  const int rw0 = m0 + rbase + 4 * hw;   // epilogue row base
  if (EPI == EP_RELU16) {
    float b0v = bias[col0], b1v = bias[col1];
#pragma unroll
    for (int rf = 0; rf < 2; rf++)
#pragma unroll
      for (int g = 0; g < 4; g++)
#pragma unroll
        for (int qq = 0; qq < 4; qq++) {
          int row = rw0 + 32 * rf + qq + 8 * g;
          if (row < M) {
            o16a[(size_t)row * 256 + col0] =
                (_Float16)fmaxf(acc[rf][0][4 * g + qq] + b0v, 0.f);
            o16a[(size_t)row * 256 + col1] =
                (_Float16)fmaxf(acc[rf][1][4 * g + qq] + b1v, 0.f);
          }
        }
  }
  if (EPI == EP_ADDC) {
    float b0v = bias[col0], b1v = bias[col1];
#pragma unroll
    for (int rf = 0; rf < 2; rf++)
#pragma unroll
      for (int g = 0; g < 4; g++)
#pragma unroll
        for (int qq = 0; qq < 4; qq++) {
          int row = rw0 + 32 * rf + qq + 8 * g;
          if (row < M) {
            float dr = rv[row];
            outf[(size_t)row * 256 + col0] =
                acc[rf][0][4 * g + qq] + addm[(size_t)row * 256 + col0] + dr * b0v;
            outf[(size_t)row * 256 + col1] =
                acc[rf][1][4 * g + qq] + addm[(size_t)row * 256 + col1] + dr * b1v;
          }
        }
  }
  if (EPI == EP_HE2) {
#pragma unroll
    for (int rf = 0; rf < 2; rf++)
#pragma unroll
      for (int g = 0; g < 4; g++)
#pragma unroll
        for (int qq = 0; qq < 4; qq++) {
          int row = rw0 + 32 * rf + qq + 8 * g;
          if (row < M) {
            o16a[(size_t)row * 256 + col0] = (_Float16)acc[rf][0][4 * g + qq];
            o16a[(size_t)row * 256 + col1] = (_Float16)acc[rf][1][4 * g + qq];
            o16b[(size_t)row * 256 + col0] = (_Float16)acc2[rf][0][4 * g + qq];
            o16b[(size_t)row * 256 + col1] = (_Float16)acc2[rf][1][4 * g + qq];
          }
        }
  }
  if (EPI == EP_PROJ2) {
    float b0v = bias[col0], b1v = bias[col1];
    float q0 = qW[col0], q1 = qW[col1];
#pragma unroll
    for (int rf = 0; rf < 2; rf++)
#pragma unroll
      for (int g = 0; g < 4; g++)
#pragma unroll
        for (int qq = 0; qq < 4; qq++) {
          int row = rw0 + 32 * rf + qq + 8 * g;
          if (row < M) {
            o16a[(size_t)row * 256 + col0] =
                (_Float16)fmaxf(acc[rf][0][4 * g + qq] + b0v, 0.f);
            o16a[(size_t)row * 256 + col1] =
                (_Float16)fmaxf(acc[rf][1][4 * g + qq] + b1v, 0.f);
            o16b[(size_t)row * 256 + col0] = (_Float16)(acc2[rf][0][4 * g + qq] + q0);
            o16b[(size_t)row * 256 + col1] = (_Float16)(acc2[rf][1][4 * g + qq] + q1);
          }
        }
  }
}

// ---- lean edge combine: logits/sampled from ea2q16 + HEh/HEt gathers -------
__global__ __launch_bounds__(256) void k_edge(
    const _Float16* __restrict__ ea2q, const _Float16* __restrict__ HEh,
    const _Float16* __restrict__ HEt, const int* __restrict__ ei32,
    const float* __restrict__ pW2, const float* __restrict__ pb2,
    const float* __restrict__ noise, float* __restrict__ dout) {
  int e = blockIdx.x * 4 + (threadIdx.x >> 6);
  int l = threadIdx.x & 63;
  int h = ei32[e], t = ei32[E + e];
  f16x4 a  = ((const f16x4*)(ea2q + (size_t)e * 256))[l];
  f16x4 hv = ((const f16x4*)(HEh + (size_t)h * 256))[l];
  f16x4 tv = ((const f16x4*)(HEt + (size_t)t * 256))[l];
  float4 wv = ((const float4*)pW2)[l];
  float s = fmaxf((float)a[0] + (float)hv[0] + (float)tv[0], 0.f) * wv.x
          + fmaxf((float)a[1] + (float)hv[1] + (float)tv[1], 0.f) * wv.y
          + fmaxf((float)a[2] + (float)hv[2] + (float)tv[2], 0.f) * wv.z
          + fmaxf((float)a[3] + (float)hv[3] + (float)tv[3], 0.f) * wv.w;
#pragma unroll
  for (int m = 1; m <= 32; m <<= 1) s += __shfl_xor(s, m);
  if (l == 0) {
    float lg = s + pb2[0];
    float nz = noise[e];
    float rn = logf(nz) - logf(1.f - nz);
    dout[e] = lg;
    dout[E + e] = 1.f / (1.f + expf(-(lg + rn)));
  }
}

extern "C" void kernel_launch(void* const* d_in, const int* in_sizes, int n_in,
                              void* d_out, int out_size, void* d_ws, size_t ws_size,
                              hipStream_t stream) {
  const float* entity = (const float*)d_in[0];
  const float* ea     = (const float*)d_in[1];
  const float* q      = (const float*)d_in[2];
  const float* noise  = (const float*)d_in[3];
  const float* W_pr1  = (const float*)d_in[4];
  const float* b_pr1  = (const float*)d_in[5];
  const float* W_pr2  = (const float*)d_in[6];
  const float* b_pr2  = (const float*)d_in[7];
  const float* sW0    = (const float*)d_in[8];
  const float* sb0    = (const float*)d_in[9];
  const float* sW1    = (const float*)d_in[10];
  const float* sb1    = (const float*)d_in[11];
  const float* pW1    = (const float*)d_in[12];
  const float* pb1    = (const float*)d_in[13];
  const float* pW2    = (const float*)d_in[14];
  const float* pb2    = (const float*)d_in[15];
  const void*  ei_raw = d_in[16];

  char* ws = (char*)d_ws;
  const size_t EDH = (size_t)E * D * 2;    // 102.4 MB f16 edge matrix
  const size_t NDB = (size_t)NV * D * 4;   // 51.2 MB f32 node matrix
  const size_t NDH = (size_t)NV * D * 2;   // 25.6 MB f16 node matrix
  const size_t PAD = 128 * 256 * 2;        // OOB tile-read slack (64 KB)
  size_t off_b = 0;
  char* r0  = ws + off_b; off_b += EDH + PAD;        // ea16
  char* r1a = ws + off_b; off_b += EDH + PAD;        // tmp16
  char* r1b = ws + off_b; off_b += EDH + PAD;        // ea2q16
  char* r2  = ws + off_b; off_b += NDB + PAD;        // hsum f32 -> HEh16|HEt16
  char* r3  = ws + off_b; off_b += NDH + PAD;        // hid16 -> agg16
  char* r4  = ws + off_b; off_b += NDH + PAD;        // ent16 -> out116
  char* r5  = ws + off_b; off_b += NDH + PAD;        // out016
  auto alloc_w = [&](int K) { _Float16* p = (_Float16*)(ws + off_b);
                              off_b += (size_t)K * 256 * 2; return p; };
  _Float16* Wpr1f = alloc_w(256);
  _Float16* Wpr2f = alloc_w(256);
  _Float16* sW0f  = alloc_w(512);
  _Float16* sW1f  = alloc_w(512);
  _Float16* Whehf = alloc_w(512);
  _Float16* Whetf = alloc_w(512);
  _Float16* Weaf  = alloc_w(256);
  float* rinv   = (float*)(ws + off_b); off_b += (size_t)NV * 4;
  float* degrev = (float*)(ws + off_b); off_b += (size_t)NV * 4;
  float* qW     = (float*)(ws + off_b); off_b += 1024;
  int*   ei32   = (int*)(ws + off_b);   off_b += (size_t)TWOE * 4;
  int*   eidA   = (int*)(ws + off_b);   off_b += (size_t)TWOE * 4;
  int*   srcA   = (int*)(ws + off_b);   off_b += (size_t)TWOE * 4;
  int*   offA   = (int*)(ws + off_b);   off_b += (size_t)(NV + 1) * 4;
  int*   deg    = (int*)(ws + off_b);   off_b += (size_t)NV * 4;
  int*   cursor = (int*)(ws + off_b);   off_b += (size_t)NV * 4;
  int*   flag   = (int*)(ws + off_b);   off_b += 64;

  // lifetime aliases
  _Float16* ea16   = (_Float16*)r0;          // conv -> PROJ2/gath_h
  _Float16* tmp16  = (_Float16*)r1a;         // PROJ2 -> gath_h
  _Float16* ea2q16 = (_Float16*)r1b;         // PROJ2 -> k_edge
  float*    hsum   = (float*)r2;             // gath -> ADDC -> agg0/agg1
  _Float16* HEh16  = (_Float16*)r2;          // HE2 -> k_edge
  _Float16* HEt16  = (_Float16*)(r2 + NDH);
  _Float16* hid16  = (_Float16*)r3;          // gath -> ADDC
  _Float16* agg16  = (_Float16*)r3;          // agg -> sage (per layer)
  _Float16* ent16  = (_Float16*)r4;          // conv -> agg0/sage0
  _Float16* out116 = (_Float16*)r4;          // sage1 -> HE2
  _Float16* out016 = (_Float16*)r5;          // sage0 -> agg1/sage1/HE2

  // ---- indices & CSR ----
  k_detect<<<1, 256, 0, stream>>>(ei_raw, flag);
  k_convert<<<(TWOE + 255) / 256, 256, 0, stream>>>(ei_raw, flag, ei32);
  hipMemsetAsync(deg, 0, (size_t)NV * 4, stream);
  hipMemsetAsync(cursor, 0, (size_t)NV * 4, stream);
  k_deg<<<(TWOE + 255) / 256, 256, 0, stream>>>(ei32, deg);
  k_scan<<<1, 1024, 0, stream>>>(deg, offA);
  k_fill<<<(TWOE + 255) / 256, 256, 0, stream>>>(ei32, offA, cursor, eidA, srcA);
  k_rinv<<<(NV + 255) / 256, 256, 0, stream>>>(offA, rinv);

  // ---- weight prep + f16 shadows ----
  k_wprep<<<256 / 32, 256, 0, stream>>>(W_pr1, Wpr1f);
  k_wprep<<<256 / 32, 256, 0, stream>>>(W_pr2, Wpr2f);
  k_wprep<<<512 / 32, 256, 0, stream>>>(sW0, sW0f);
  k_wprep<<<512 / 32, 256, 0, stream>>>(sW1, sW1f);
  k_wprep<<<512 / 32, 256, 0, stream>>>(pW1 + 256 * 256, Whehf);
  k_wprep<<<512 / 32, 256, 0, stream>>>(pW1 + 1024 * 256, Whetf);
  k_wprep<<<256 / 32, 256, 0, stream>>>(pW1 + 768 * 256, Weaf);
  k_conv16<<<(NV * D / 8 + 255) / 256, 256, 0, stream>>>(entity, ent16, NV * D / 8);
  k_conv16<<<(E * D / 8 + 255) / 256, 256, 0, stream>>>(ea, ea16, E * D / 8);
  k_qw<<<1, 256, 0, stream>>>(q, pW1, pb1, qW);

  // ---- fused proj+EA2: tmp16 = relu(ea@Wpr1+b1); ea2q16 = ea@Wea + qW ----
  k_gemm<AF16, EP_PROJ2><<<(E + 127) / 128, 512, 0, stream>>>(
      ea16, nullptr, nullptr, nullptr, Wpr1f, Weaf, b_pr1, qW,
      nullptr, tmp16, ea2q16, E, 256);
  // gather: hsum = sum_fwd ea16 (f32); hid16 = sum_rev tmp16; degrev
  k_gath_h<<<(NV + 3) / 4, 256, 0, stream>>>(ea16, tmp16, eidA, offA, hsum, hid16, degrev);
  // hsum += hid16 @ Wpr2 + degrev*b_pr2   (in place)
  k_gemm<AF16, EP_ADDC><<<(NV + 127) / 128, 512, 0, stream>>>(
      hid16, nullptr, hsum, degrev, Wpr2f, nullptr, b_pr2, nullptr,
      hsum, nullptr, nullptr, NV, 256);

  // ---- layer 0 ----
  k_agg<<<(NV + 3) / 4, 256, 0, stream>>>(ent16, srcA, offA, hsum, rinv, agg16);
  k_gemm<AF16D, EP_RELU16><<<(NV + 127) / 128, 512, 0, stream>>>(
      ent16, agg16, nullptr, nullptr, sW0f, nullptr, sb0, nullptr,
      nullptr, out016, nullptr, NV, 512);
  // ---- layer 1 ----
  k_agg<<<(NV + 3) / 4, 256, 0, stream>>>(out016, srcA, offA, hsum, rinv, agg16);
  k_gemm<AF16D, EP_RELU16><<<(NV + 127) / 128, 512, 0, stream>>>(
      out016, agg16, nullptr, nullptr, sW1f, nullptr, sb1, nullptr,
      nullptr, out116, nullptr, NV, 512);

  // ---- HE dual-weight GEMM: HEh16/HEt16 (into hsum region; hsum dead) ----
  k_gemm<AF16D, EP_HE2><<<(NV + 127) / 128, 512, 0, stream>>>(
      out016, out116, nullptr, nullptr, Whehf, Whetf, nullptr, nullptr,
      nullptr, HEh16, HEt16, NV, 512);

  // ---- lean edge combine ----
  k_edge<<<E / 4, 256, 0, stream>>>(ea2q16, HEh16, HEt16, ei32, pW2, pb2, noise,
                                    (float*)d_out);
}

// Round 11
// 632.694 us; speedup vs baseline: 1.1776x; 1.1776x over previous
//
#include <hip/hip_runtime.h>
#include <math.h>

// FineGrainedRetriever round 11: gather-family overhaul. GEMM core = round-9
// (BM=64/256thr, W-preload-first vmcnt ordering, gload_lds XOR staging).
// (1) layer-0 x-gather merged into k_gath_h (same CSR walk) -> layer-0 k_agg
//     pass deleted; (2) ADDC epilogue emits hsum16 AND agg0=(hsum+xsum0)*rinv;
// (3) all gathers half-wave-per-row f16x8 (full 512B row/load, 2 rows/wave);
// (4) k_edge loop-free: one edge per half-wave, grid E/8; (5) hsum f16.

namespace {
constexpr int E    = 200000;
constexpr int NV   = 50000;
constexpr int D    = 256;
constexpr int TWOE = 2 * E;
}

typedef __attribute__((ext_vector_type(8))) _Float16 f16x8;
typedef __attribute__((ext_vector_type(4))) _Float16 f16x4;
typedef __attribute__((ext_vector_type(16))) float f32x16;

#define MFMA16(a, b, c) __builtin_amdgcn_mfma_f32_32x32x16_f16((a), (b), (c), 0, 0, 0)

typedef const __attribute__((address_space(1))) void* gas_t;
typedef __attribute__((address_space(3))) void* las_t;

__device__ inline void gload16(const void* g, void* l) {
  __builtin_amdgcn_global_load_lds((gas_t)g, (las_t)l, 16, 0, 0);
}

// ---- edge_index dtype probe (int64 vs int32) -------------------------------
__global__ void k_detect(const void* ei_raw, int* flag) {
  __shared__ int bad;
  if (threadIdx.x == 0) bad = 0;
  __syncthreads();
  const long long* p = (const long long*)ei_raw;
  long long v = p[threadIdx.x];
  if (v < 0 || v >= (long long)NV) atomicOr(&bad, 1);
  __syncthreads();
  if (threadIdx.x == 0) *flag = bad ? 0 : 1;  // 1 => int64
}

__global__ void k_convert(const void* ei_raw, const int* __restrict__ flag,
                          int* __restrict__ ei32) {
  int i = blockIdx.x * 256 + threadIdx.x;
  if (i >= TWOE) return;
  if (*flag) ei32[i] = (int)((const long long*)ei_raw)[i];
  else       ei32[i] = ((const int*)ei_raw)[i];
}

// ---- CSR build -------------------------------------------------------------
__global__ void k_deg(const int* __restrict__ ei32, int* __restrict__ deg) {
  int de = blockIdx.x * 256 + threadIdx.x;
  if (de >= TWOE) return;
  int dst = (de < E) ? ei32[E + de] : ei32[de - E];
  atomicAdd(&deg[dst], 1);
}

__global__ __launch_bounds__(1024) void k_scan(const int* __restrict__ deg,
                                               int* __restrict__ off) {
  __shared__ int wsum[16];
  __shared__ int carryS;
  int tid = threadIdx.x;
  int lane = tid & 63, wv = tid >> 6;
  if (tid == 0) carryS = 0;
  __syncthreads();
  for (int base = 0; base < NV; base += 1024) {
    int i = base + tid;
    int v = (i < NV) ? deg[i] : 0;
    int s = v;
#pragma unroll
    for (int d = 1; d < 64; d <<= 1) {
      int t = __shfl_up(s, d);
      if (lane >= d) s += t;
    }
    if (lane == 63) wsum[wv] = s;
    int carry = carryS;
    __syncthreads();
    if (wv == 0) {
      int ws = (lane < 16) ? wsum[lane] : 0;
#pragma unroll
      for (int d = 1; d < 16; d <<= 1) {
        int t = __shfl_up(ws, d);
        if (lane >= d) ws += t;
      }
      if (lane < 16) wsum[lane] = ws;
    }
    __syncthreads();
    int wexcl = (wv == 0) ? 0 : wsum[wv - 1];
    if (i < NV) off[i] = carry + wexcl + s - v;
    if (tid == 1023) carryS = carry + wsum[15];
    __syncthreads();
  }
  if (tid == 0) off[NV] = carryS;
}

__global__ void k_fill(const int* __restrict__ ei32, const int* __restrict__ off,
                       int* __restrict__ cursor, int* __restrict__ eidA,
                       int* __restrict__ srcA) {
  int de = blockIdx.x * 256 + threadIdx.x;
  if (de >= TWOE) return;
  int dst = (de < E) ? ei32[E + de] : ei32[de - E];
  int p = atomicAdd(&cursor[dst], 1);
  int idx = off[dst] + p;
  eidA[idx] = de;
  srcA[idx] = ei32[de];
}

__global__ void k_rinv(const int* __restrict__ off, float* __restrict__ rinv) {
  int n = blockIdx.x * 256 + threadIdx.x;
  if (n < NV) {
    int d = off[n + 1] - off[n];
    rinv[n] = 1.f / fmaxf((float)d, 1.f);
  }
}

// ---- f32 -> f16 copy (8 elems/thread) --------------------------------------
__global__ void k_conv16(const float* __restrict__ x, _Float16* __restrict__ y,
                         int n8) {
  int i = blockIdx.x * 256 + threadIdx.x;
  if (i >= n8) return;
  const float4* p = (const float4*)x;
  float4 a = p[2 * i], b = p[2 * i + 1];
  f16x8 o;
  o[0] = (_Float16)a.x; o[1] = (_Float16)a.y; o[2] = (_Float16)a.z; o[3] = (_Float16)a.w;
  o[4] = (_Float16)b.x; o[5] = (_Float16)b.y; o[6] = (_Float16)b.z; o[7] = (_Float16)b.w;
  ((f16x8*)y)[i] = o;
}

// ---- merged gather: per node n (half-wave): hsum (fwd ea), hid (rev tmp),
// ---- xsum0 (ent16[src] over ALL list entries), degrev -----------------------
__global__ __launch_bounds__(256) void k_gath_h(
    const _Float16* __restrict__ ea16, const _Float16* __restrict__ tmp16,
    const _Float16* __restrict__ ent16,
    const int* __restrict__ eidA, const int* __restrict__ srcA,
    const int* __restrict__ off,
    _Float16* __restrict__ hsum16, _Float16* __restrict__ hid16,
    _Float16* __restrict__ xsum16, float* __restrict__ degrev) {
  int n = blockIdx.x * 8 + (threadIdx.x >> 5);
  if (n >= NV) return;
  int l = threadIdx.x & 31;
  float fs[8], hv[8], xs[8];
#pragma unroll
  for (int k2 = 0; k2 < 8; k2++) { fs[k2] = 0.f; hv[k2] = 0.f; xs[k2] = 0.f; }
  int o0 = off[n], o1 = off[n + 1];
  int dr = 0;
#pragma unroll 2
  for (int j = o0; j < o1; j++) {
    int de = eidA[j];
    int src = srcA[j];
    f16x8 xv = ((const f16x8*)(ent16 + (size_t)src * D))[l];
#pragma unroll
    for (int k2 = 0; k2 < 8; k2++) xs[k2] += (float)xv[k2];
    if (de < E) {
      f16x8 v = ((const f16x8*)(ea16 + (size_t)de * D))[l];
#pragma unroll
      for (int k2 = 0; k2 < 8; k2++) fs[k2] += (float)v[k2];
    } else {
      f16x8 v = ((const f16x8*)(tmp16 + (size_t)(de - E) * D))[l];
#pragma unroll
      for (int k2 = 0; k2 < 8; k2++) hv[k2] += (float)v[k2];
      dr++;
    }
  }
  f16x8 of, oh, ox;
#pragma unroll
  for (int k2 = 0; k2 < 8; k2++) {
    of[k2] = (_Float16)fs[k2]; oh[k2] = (_Float16)hv[k2]; ox[k2] = (_Float16)xs[k2];
  }
  ((f16x8*)(hsum16 + (size_t)n * D))[l] = of;
  ((f16x8*)(hid16 + (size_t)n * D))[l] = oh;
  ((f16x8*)(xsum16 + (size_t)n * D))[l] = ox;
  if (l == 0) degrev[n] = (float)dr;
}

// ---- layer-1 aggregate: agg16[n] = (sum_j x16[src_j] + hsum16[n])*rinv[n] --
__global__ __launch_bounds__(256) void k_agg(
    const _Float16* __restrict__ x16, const int* __restrict__ srcA,
    const int* __restrict__ off, const _Float16* __restrict__ hsum16,
    const float* __restrict__ rinv, _Float16* __restrict__ agg16) {
  int n = blockIdx.x * 8 + (threadIdx.x >> 5);
  if (n >= NV) return;
  int l = threadIdx.x & 31;
  f16x8 h = ((const f16x8*)(hsum16 + (size_t)n * D))[l];
  float s[8];
#pragma unroll
  for (int k2 = 0; k2 < 8; k2++) s[k2] = (float)h[k2];
  int o0 = off[n], o1 = off[n + 1];
#pragma unroll 4
  for (int j = o0; j < o1; j++) {
    int src = srcA[j];
    f16x8 v = ((const f16x8*)(x16 + (size_t)src * D))[l];
#pragma unroll
    for (int k2 = 0; k2 < 8; k2++) s[k2] += (float)v[k2];
  }
  float r = rinv[n];
  f16x8 o;
#pragma unroll
  for (int k2 = 0; k2 < 8; k2++) o[k2] = (_Float16)(s[k2] * r);
  ((f16x8*)(agg16 + (size_t)n * D))[l] = o;
}

// ---- weight prep: W[K][256] f32 -> Wf [K/8][256][8] f16 --------------------
__global__ __launch_bounds__(256) void k_wprep(const float* __restrict__ W,
                                               _Float16* __restrict__ Wf) {
  __shared__ float tl[32][260];
  int tid = threadIdx.x;
  int k0 = blockIdx.x * 32;
#pragma unroll
  for (int i = 0; i < 32; i++) tl[i][tid] = W[(size_t)(k0 + i) * 256 + tid];
  __syncthreads();
  f16x8* WfV = (f16x8*)Wf;
#pragma unroll
  for (int kg = 0; kg < 4; kg++) {
    f16x8 p;
#pragma unroll
    for (int j = 0; j < 8; j++) p[j] = (_Float16)tl[kg * 8 + j][tid];
    WfV[(size_t)((k0 >> 3) + kg) * 256 + tid] = p;
  }
}

// ---- qW[n] = q @ pred_W1[:256,n] + pred_b1[n] ------------------------------
__global__ void k_qw(const float* __restrict__ q, const float* __restrict__ W1,
                     const float* __restrict__ b1, float* __restrict__ qW) {
  __shared__ float ql[D];
  int n = threadIdx.x;
  ql[n] = q[n];
  __syncthreads();
  float s = b1[n];
  for (int k = 0; k < D; k++) s += ql[k] * W1[(size_t)k * D + n];
  qW[n] = s;
}

// ---- f16 MFMA GEMM (round-9 core): BM=64, gload_lds, W-preload-first -------
enum AM { AF16, AF16D };
enum EP { EP_RELU16, EP_ADDC, EP_HE2, EP_PROJ2 };

// stage one 64x64 f16 K-step tile into ldsbuf (8KB), source-XOR-swizzled
template<int AMODE>
__device__ inline void stageA(const _Float16* __restrict__ A0,
                              const _Float16* __restrict__ A1,
                              int m0, int t, int tid, _Float16* ldsbuf) {
  const _Float16* src;
  int kbase;
  if (AMODE == AF16D && t >= 4) { src = A1; kbase = (t - 4) * 64; }
  else                          { src = A0; kbase = t * 64; }
  const int l  = tid & 63;
  const int w  = tid >> 6;
  const int r8 = l >> 3;                 // row within 8-row chunk
  const int kg = (l & 7) ^ r8;           // swizzled source k-group (0..7)
#pragma unroll
  for (int j = 0; j < 2; j++) {
    const int c = w * 2 + j;             // chunk 0..7 (8 rows, 1KB each)
    const int row = c * 8 + r8;
    gload16(src + (size_t)(m0 + row) * 256 + kbase + kg * 8,
            ldsbuf + c * 512);           // wave-uniform LDS base, lane*16B
  }
}

template<int AMODE, int EPI>
__global__ __launch_bounds__(256, ((EPI == EP_HE2 || EPI == EP_PROJ2) ? 2 : 4))
void k_gemm(
    const _Float16* __restrict__ A0, const _Float16* __restrict__ A1,
    const _Float16* __restrict__ addm16, const _Float16* __restrict__ xs16,
    const float* __restrict__ degrev, const float* __restrict__ rinv,
    const _Float16* __restrict__ Wf, const _Float16* __restrict__ Wf2,
    const float* __restrict__ bias, const float* __restrict__ qW,
    _Float16* __restrict__ o16a, _Float16* __restrict__ o16b, int M, int K) {
  constexpr bool DUAL = (EPI == EP_HE2 || EPI == EP_PROJ2);
  __shared__ _Float16 AS[2 * 4096];      // 16 KB double-buffered A-tile
  const int tid = threadIdx.x;
  const int w = tid >> 6;
  const int lane31 = tid & 31;
  const int hw = (tid >> 5) & 1;
  const int m0 = blockIdx.x * 64;
  const int col0 = (w << 6) + lane31;
  const int col1 = col0 + 32;

  f32x16 acc[2][2], acc2[2][2];
#pragma unroll
  for (int a = 0; a < 2; a++)
#pragma unroll
    for (int b = 0; b < 2; b++)
#pragma unroll
      for (int i = 0; i < 16; i++) { acc[a][b][i] = 0.f; acc2[a][b][i] = 0.f; }

  const f16x8* WV  = (const f16x8*)Wf;
  const f16x8* WV2 = (const f16x8*)Wf2;
  const int nt = K >> 6;
  const int sw = lane31 & 7;             // row&7 for both row frags

  stageA<AMODE>(A0, A1, m0, 0, tid, AS);
  __syncthreads();

  for (int t = 0; t < nt; ++t) {
    const int k0 = t * 64;
    // (1) preload ALL W-frags of this step FIRST (older VMEM than staging)
    f16x8 wb0[4], wb1[4], wc0[4], wc1[4];
#pragma unroll
    for (int ks = 0; ks < 4; ks++) {
      const int kgl = 2 * ks + hw;
      size_t wi = (size_t)((k0 >> 3) + kgl) * 256;
      wb0[ks] = WV[wi + col0];
      wb1[ks] = WV[wi + col1];
      if (DUAL) { wc0[ks] = WV2[wi + col0]; wc1[ks] = WV2[wi + col1]; }
    }
    __builtin_amdgcn_sched_barrier(0);
    // (2) issue next tile's staging (younger; drains only at step-end barrier)
    if (t + 1 < nt)
      stageA<AMODE>(A0, A1, m0, t + 1, tid, AS + ((t + 1) & 1) * 4096);
    __builtin_amdgcn_sched_barrier(0);
    // (3) MFMA burst on current buffer
    const f16x8* cb = (const f16x8*)(AS + (t & 1) * 4096);
#pragma unroll
    for (int ks = 0; ks < 4; ks++) {
      const int kgl = 2 * ks + hw;
      f16x8 a0 = cb[lane31 * 8 + (kgl ^ sw)];
      f16x8 a1 = cb[(lane31 + 32) * 8 + (kgl ^ sw)];
      acc[0][0] = MFMA16(a0, wb0[ks], acc[0][0]);
      acc[0][1] = MFMA16(a0, wb1[ks], acc[0][1]);
      acc[1][0] = MFMA16(a1, wb0[ks], acc[1][0]);
      acc[1][1] = MFMA16(a1, wb1[ks], acc[1][1]);
      if (DUAL) {
        acc2[0][0] = MFMA16(a0, wc0[ks], acc2[0][0]);
        acc2[0][1] = MFMA16(a0, wc1[ks], acc2[0][1]);
        acc2[1][0] = MFMA16(a1, wc0[ks], acc2[1][0]);
        acc2[1][1] = MFMA16(a1, wc1[ks], acc2[1][1]);
      }
    }
    __syncthreads();
  }

  if (EPI == EP_RELU16) {
    float b0v = bias[col0], b1v = bias[col1];
#pragma unroll
    for (int rf = 0; rf < 2; rf++)
#pragma unroll
      for (int g = 0; g < 4; g++)
#pragma unroll
        for (int qq = 0; qq < 4; qq++) {
          int row = m0 + 32 * rf + qq + 8 * g + 4 * hw;
          if (row < M) {
            o16a[(size_t)row * 256 + col0] =
                (_Float16)fmaxf(acc[rf][0][4 * g + qq] + b0v, 0.f);
            o16a[(size_t)row * 256 + col1] =
                (_Float16)fmaxf(acc[rf][1][4 * g + qq] + b1v, 0.f);
          }
        }
  }
  if (EPI == EP_ADDC) {
    // h = acc + hsum16 + degrev*bias  -> o16a (in-place hsum16)
    // agg0 = (h + xsum0) * rinv       -> o16b
    float b0v = bias[col0], b1v = bias[col1];
#pragma unroll
    for (int rf = 0; rf < 2; rf++)
#pragma unroll
      for (int g = 0; g < 4; g++)
#pragma unroll
        for (int qq = 0; qq < 4; qq++) {
          int row = m0 + 32 * rf + qq + 8 * g + 4 * hw;
          if (row < M) {
            float dr = degrev[row], rv = rinv[row];
            size_t i0 = (size_t)row * 256 + col0;
            size_t i1 = (size_t)row * 256 + col1;
            float h0 = acc[rf][0][4 * g + qq] + (float)addm16[i0] + dr * b0v;
            float h1 = acc[rf][1][4 * g + qq] + (float)addm16[i1] + dr * b1v;
            o16a[i0] = (_Float16)h0;
            o16a[i1] = (_Float16)h1;
            o16b[i0] = (_Float16)((h0 + (float)xs16[i0]) * rv);
            o16b[i1] = (_Float16)((h1 + (float)xs16[i1]) * rv);
          }
        }
  }
  if (EPI == EP_HE2) {
#pragma unroll
    for (int rf = 0; rf < 2; rf++)
#pragma unroll
      for (int g = 0; g < 4; g++)
#pragma unroll
        for (int qq = 0; qq < 4; qq++) {
          int row = m0 + 32 * rf + qq + 8 * g + 4 * hw;
          if (row < M) {
            o16a[(size_t)row * 256 + col0] = (_Float16)acc[rf][0][4 * g + qq];
            o16a[(size_t)row * 256 + col1] = (_Float16)acc[rf][1][4 * g + qq];
            o16b[(size_t)row * 256 + col0] = (_Float16)acc2[rf][0][4 * g + qq];
            o16b[(size_t)row * 256 + col1] = (_Float16)acc2[rf][1][4 * g + qq];
          }
        }
  }
  if (EPI == EP_PROJ2) {
    float b0v = bias[col0], b1v = bias[col1];
    float q0 = qW[col0], q1 = qW[col1];
#pragma unroll
    for (int rf = 0; rf < 2; rf++)
#pragma unroll
      for (int g = 0; g < 4; g++)
#pragma unroll
        for (int qq = 0; qq < 4; qq++) {
          int row = m0 + 32 * rf + qq + 8 * g + 4 * hw;
          if (row < M) {
            o16a[(size_t)row * 256 + col0] =
                (_Float16)fmaxf(acc[rf][0][4 * g + qq] + b0v, 0.f);
            o16a[(size_t)row * 256 + col1] =
                (_Float16)fmaxf(acc[rf][1][4 * g + qq] + b1v, 0.f);
            o16b[(size_t)row * 256 + col0] = (_Float16)(acc2[rf][0][4 * g + qq] + q0);
            o16b[(size_t)row * 256 + col1] = (_Float16)(acc2[rf][1][4 * g + qq] + q1);
          }
        }
  }
}

// ---- edge combine: one edge per half-wave (32 lanes x f16x8), loop-free ----
__global__ __launch_bounds__(256) void k_edge(
    const _Float16* __restrict__ ea2q, const _Float16* __restrict__ HEh,
    const _Float16* __restrict__ HEt, const int* __restrict__ ei32,
    const float* __restrict__ pW2, const float* __restrict__ pb2,
    const float* __restrict__ noise, float* __restrict__ dout) {
  int e = blockIdx.x * 8 + (threadIdx.x >> 5);
  int l = threadIdx.x & 31;
  int h = ei32[e], t = ei32[E + e];
  f16x8 a  = ((const f16x8*)(ea2q + (size_t)e * 256))[l];
  f16x8 hv = ((const f16x8*)(HEh + (size_t)h * 256))[l];
  f16x8 tv = ((const f16x8*)(HEt + (size_t)t * 256))[l];
  const float4* wp = (const float4*)(pW2 + l * 8);
  float4 w0 = wp[0], w1 = wp[1];
  float wv[8] = {w0.x, w0.y, w0.z, w0.w, w1.x, w1.y, w1.z, w1.w};
  float s = 0.f;
#pragma unroll
  for (int j = 0; j < 8; j++)
    s += fmaxf((float)a[j] + (float)hv[j] + (float)tv[j], 0.f) * wv[j];
#pragma unroll
  for (int m = 1; m <= 16; m <<= 1) s += __shfl_xor(s, m);
  if (l == 0) {
    float lg = s + pb2[0];
    float nz = noise[e];
    float rn = logf(nz) - logf(1.f - nz);
    dout[e] = lg;
    dout[E + e] = 1.f / (1.f + expf(-(lg + rn)));
  }
}

extern "C" void kernel_launch(void* const* d_in, const int* in_sizes, int n_in,
                              void* d_out, int out_size, void* d_ws, size_t ws_size,
                              hipStream_t stream) {
  const float* entity = (const float*)d_in[0];
  const float* ea     = (const float*)d_in[1];
  const float* q      = (const float*)d_in[2];
  const float* noise  = (const float*)d_in[3];
  const float* W_pr1  = (const float*)d_in[4];
  const float* b_pr1  = (const float*)d_in[5];
  const float* W_pr2  = (const float*)d_in[6];
  const float* b_pr2  = (const float*)d_in[7];
  const float* sW0    = (const float*)d_in[8];
  const float* sb0    = (const float*)d_in[9];
  const float* sW1    = (const float*)d_in[10];
  const float* sb1    = (const float*)d_in[11];
  const float* pW1    = (const float*)d_in[12];
  const float* pb1    = (const float*)d_in[13];
  const float* pW2    = (const float*)d_in[14];
  const float* pb2    = (const float*)d_in[15];
  const void*  ei_raw = d_in[16];

  char* ws = (char*)d_ws;
  const size_t EDH = (size_t)E * D * 2;    // 102.4 MB f16 edge matrix
  const size_t NDH = (size_t)NV * D * 2;   // 25.6 MB f16 node matrix
  const size_t PAD = 64 * 256 * 2;         // OOB tile-read slack (32 KB)
  size_t off_b = 0;
  char* r0  = ws + off_b; off_b += EDH + PAD;        // ea16
  char* r1a = ws + off_b; off_b += EDH + PAD;        // tmp16
  char* r1b = ws + off_b; off_b += EDH + PAD;        // ea2q16
  char* r2  = ws + off_b; off_b += 2 * NDH + PAD;    // hsum16 -> HEh16|HEt16
  char* r3  = ws + off_b; off_b += NDH + PAD;        // hid16 -> agg016 -> agg16
  char* r4  = ws + off_b; off_b += NDH + PAD;        // ent16 -> out116
  char* r5  = ws + off_b; off_b += NDH + PAD;        // out016
  char* r6  = ws + off_b; off_b += NDH + PAD;        // xsum016
  auto alloc_w = [&](int K) { _Float16* p = (_Float16*)(ws + off_b);
                              off_b += (size_t)K * 256 * 2; return p; };
  _Float16* Wpr1f = alloc_w(256);
  _Float16* Wpr2f = alloc_w(256);
  _Float16* sW0f  = alloc_w(512);
  _Float16* sW1f  = alloc_w(512);
  _Float16* Whehf = alloc_w(512);
  _Float16* Whetf = alloc_w(512);
  _Float16* Weaf  = alloc_w(256);
  float* rinv   = (float*)(ws + off_b); off_b += (size_t)NV * 4;
  float* degrev = (float*)(ws + off_b); off_b += (size_t)NV * 4;
  float* qW     = (float*)(ws + off_b); off_b += 1024;
  int*   ei32   = (int*)(ws + off_b);   off_b += (size_t)TWOE * 4;
  int*   eidA   = (int*)(ws + off_b);   off_b += (size_t)TWOE * 4;
  int*   srcA   = (int*)(ws + off_b);   off_b += (size_t)TWOE * 4;
  int*   offA   = (int*)(ws + off_b);   off_b += (size_t)(NV + 1) * 4;
  int*   deg    = (int*)(ws + off_b);   off_b += (size_t)NV * 4;
  int*   cursor = (int*)(ws + off_b);   off_b += (size_t)NV * 4;
  int*   flag   = (int*)(ws + off_b);   off_b += 64;

  // lifetime aliases
  _Float16* ea16   = (_Float16*)r0;          // conv -> PROJ2/gath_h
  _Float16* tmp16  = (_Float16*)r1a;         // PROJ2 -> gath_h
  _Float16* ea2q16 = (_Float16*)r1b;         // PROJ2 -> k_edge
  _Float16* hsum16 = (_Float16*)r2;          // gath -> ADDC(in-place) -> agg1
  _Float16* HEh16  = (_Float16*)r2;          // HE2 -> k_edge (hsum dead)
  _Float16* HEt16  = (_Float16*)(r2 + NDH);
  _Float16* hid16  = (_Float16*)r3;          // gath -> ADDC (A)
  _Float16* agg016 = (_Float16*)r3;          // ADDC epi -> sage0 (row-safe)
  _Float16* agg16  = (_Float16*)r3;          // k_agg -> sage1
  _Float16* ent16  = (_Float16*)r4;          // conv -> gath/sage0
  _Float16* out116 = (_Float16*)r4;          // sage1 -> HE2
  _Float16* out016 = (_Float16*)r5;          // sage0 -> agg1/sage1/HE2
  _Float16* xsum16 = (_Float16*)r6;          // gath -> ADDC epi

  // ---- indices & CSR ----
  k_detect<<<1, 256, 0, stream>>>(ei_raw, flag);
  k_convert<<<(TWOE + 255) / 256, 256, 0, stream>>>(ei_raw, flag, ei32);
  hipMemsetAsync(deg, 0, (size_t)NV * 4, stream);
  hipMemsetAsync(cursor, 0, (size_t)NV * 4, stream);
  k_deg<<<(TWOE + 255) / 256, 256, 0, stream>>>(ei32, deg);
  k_scan<<<1, 1024, 0, stream>>>(deg, offA);
  k_fill<<<(TWOE + 255) / 256, 256, 0, stream>>>(ei32, offA, cursor, eidA, srcA);
  k_rinv<<<(NV + 255) / 256, 256, 0, stream>>>(offA, rinv);

  // ---- weight prep + f16 shadows ----
  k_wprep<<<256 / 32, 256, 0, stream>>>(W_pr1, Wpr1f);
  k_wprep<<<256 / 32, 256, 0, stream>>>(W_pr2, Wpr2f);
  k_wprep<<<512 / 32, 256, 0, stream>>>(sW0, sW0f);
  k_wprep<<<512 / 32, 256, 0, stream>>>(sW1, sW1f);
  k_wprep<<<512 / 32, 256, 0, stream>>>(pW1 + 256 * 256, Whehf);
  k_wprep<<<512 / 32, 256, 0, stream>>>(pW1 + 1024 * 256, Whetf);
  k_wprep<<<256 / 32, 256, 0, stream>>>(pW1 + 768 * 256, Weaf);
  k_conv16<<<(NV * D / 8 + 255) / 256, 256, 0, stream>>>(entity, ent16, NV * D / 8);
  k_conv16<<<(E * D / 8 + 255) / 256, 256, 0, stream>>>(ea, ea16, E * D / 8);
  k_qw<<<1, 256, 0, stream>>>(q, pW1, pb1, qW);

  // ---- fused proj+EA2: tmp16 = relu(ea@Wpr1+b1); ea2q16 = ea@Wea + qW ----
  k_gemm<AF16, EP_PROJ2><<<E / 64, 256, 0, stream>>>(
      ea16, nullptr, nullptr, nullptr, nullptr, nullptr, Wpr1f, Weaf,
      b_pr1, qW, tmp16, ea2q16, E, 256);

  // ---- merged gather: hsum16, hid16, xsum16, degrev ----
  k_gath_h<<<(NV + 7) / 8, 256, 0, stream>>>(
      ea16, tmp16, ent16, eidA, srcA, offA, hsum16, hid16, xsum16, degrev);

  // ---- ADDC+mix: hsum16 += hid16@Wpr2 + degrev*b2 (in place);
  //      agg016 = (hsum16 + xsum16) * rinv  (over hid16 region, row-safe) ----
  k_gemm<AF16, EP_ADDC><<<(NV + 63) / 64, 256, 0, stream>>>(
      hid16, nullptr, hsum16, xsum16, degrev, rinv, Wpr2f, nullptr,
      b_pr2, nullptr, hsum16, agg016, NV, 256);

  // ---- layer 0 ----
  k_gemm<AF16D, EP_RELU16><<<(NV + 63) / 64, 256, 0, stream>>>(
      ent16, agg016, nullptr, nullptr, nullptr, nullptr, sW0f, nullptr,
      sb0, nullptr, out016, nullptr, NV, 512);
  // ---- layer 1 ----
  k_agg<<<(NV + 7) / 8, 256, 0, stream>>>(out016, srcA, offA, hsum16, rinv, agg16);
  k_gemm<AF16D, EP_RELU16><<<(NV + 63) / 64, 256, 0, stream>>>(
      out016, agg16, nullptr, nullptr, nullptr, nullptr, sW1f, nullptr,
      sb1, nullptr, out116, nullptr, NV, 512);

  // ---- HE dual-weight GEMM: HEh16/HEt16 (hsum region; hsum dead) ----
  k_gemm<AF16D, EP_HE2><<<(NV + 63) / 64, 256, 0, stream>>>(
      out016, out116, nullptr, nullptr, nullptr, nullptr, Whehf, Whetf,
      nullptr, nullptr, HEh16, HEt16, NV, 512);

  // ---- edge combine ----
  k_edge<<<E / 8, 256, 0, stream>>>(ea2q16, HEh16, HEt16, ei32, pW2, pb2, noise,
                                    (float*)d_out);
}

// Round 12
// 625.817 us; speedup vs baseline: 1.1906x; 1.0110x over previous
//
#include <hip/hip_runtime.h>
#include <math.h>

// FineGrainedRetriever round 12: row-aligned GEMM-chain fusion.
// k_fuse0 = ADDC + sage0: P1 hid16@Wpr2 -> hsum16(global) + agg0 (LDS, staged
// A-layout); P2 out016 = relu([ent16|agg0]@sW0+b). agg0 never hits HBM.
// k_fuse1 = sage1 + HE2: P1 out116 = relu([out016|agg16]@sW1+b) -> LDS only;
// P2 HEh/HEt = [out016|out116]@{Wheh,Whet}. out116 never hits HBM.
// PROJ2 / gathers / k_edge / CSR unchanged from round 11.

namespace {
constexpr int E    = 200000;
constexpr int NV   = 50000;
constexpr int D    = 256;
constexpr int TWOE = 2 * E;
}

typedef __attribute__((ext_vector_type(8))) _Float16 f16x8;
typedef __attribute__((ext_vector_type(4))) _Float16 f16x4;
typedef __attribute__((ext_vector_type(16))) float f32x16;

#define MFMA16(a, b, c) __builtin_amdgcn_mfma_f32_32x32x16_f16((a), (b), (c), 0, 0, 0)

typedef const __attribute__((address_space(1))) void* gas_t;
typedef __attribute__((address_space(3))) void* las_t;

__device__ inline void gload16(const void* g, void* l) {
  __builtin_amdgcn_global_load_lds((gas_t)g, (las_t)l, 16, 0, 0);
}

// ---- edge_index dtype probe (int64 vs int32) -------------------------------
__global__ void k_detect(const void* ei_raw, int* flag) {
  __shared__ int bad;
  if (threadIdx.x == 0) bad = 0;
  __syncthreads();
  const long long* p = (const long long*)ei_raw;
  long long v = p[threadIdx.x];
  if (v < 0 || v >= (long long)NV) atomicOr(&bad, 1);
  __syncthreads();
  if (threadIdx.x == 0) *flag = bad ? 0 : 1;  // 1 => int64
}

__global__ void k_convert(const void* ei_raw, const int* __restrict__ flag,
                          int* __restrict__ ei32) {
  int i = blockIdx.x * 256 + threadIdx.x;
  if (i >= TWOE) return;
  if (*flag) ei32[i] = (int)((const long long*)ei_raw)[i];
  else       ei32[i] = ((const int*)ei_raw)[i];
}

// ---- CSR build -------------------------------------------------------------
__global__ void k_deg(const int* __restrict__ ei32, int* __restrict__ deg) {
  int de = blockIdx.x * 256 + threadIdx.x;
  if (de >= TWOE) return;
  int dst = (de < E) ? ei32[E + de] : ei32[de - E];
  atomicAdd(&deg[dst], 1);
}

__global__ __launch_bounds__(1024) void k_scan(const int* __restrict__ deg,
                                               int* __restrict__ off) {
  __shared__ int wsum[16];
  __shared__ int carryS;
  int tid = threadIdx.x;
  int lane = tid & 63, wv = tid >> 6;
  if (tid == 0) carryS = 0;
  __syncthreads();
  for (int base = 0; base < NV; base += 1024) {
    int i = base + tid;
    int v = (i < NV) ? deg[i] : 0;
    int s = v;
#pragma unroll
    for (int d = 1; d < 64; d <<= 1) {
      int t = __shfl_up(s, d);
      if (lane >= d) s += t;
    }
    if (lane == 63) wsum[wv] = s;
    int carry = carryS;
    __syncthreads();
    if (wv == 0) {
      int ws = (lane < 16) ? wsum[lane] : 0;
#pragma unroll
      for (int d = 1; d < 16; d <<= 1) {
        int t = __shfl_up(ws, d);
        if (lane >= d) ws += t;
      }
      if (lane < 16) wsum[lane] = ws;
    }
    __syncthreads();
    int wexcl = (wv == 0) ? 0 : wsum[wv - 1];
    if (i < NV) off[i] = carry + wexcl + s - v;
    if (tid == 1023) carryS = carry + wsum[15];
    __syncthreads();
  }
  if (tid == 0) off[NV] = carryS;
}

__global__ void k_fill(const int* __restrict__ ei32, const int* __restrict__ off,
                       int* __restrict__ cursor, int* __restrict__ eidA,
                       int* __restrict__ srcA) {
  int de = blockIdx.x * 256 + threadIdx.x;
  if (de >= TWOE) return;
  int dst = (de < E) ? ei32[E + de] : ei32[de - E];
  int p = atomicAdd(&cursor[dst], 1);
  int idx = off[dst] + p;
  eidA[idx] = de;
  srcA[idx] = ei32[de];
}

__global__ void k_rinv(const int* __restrict__ off, float* __restrict__ rinv) {
  int n = blockIdx.x * 256 + threadIdx.x;
  if (n < NV) {
    int d = off[n + 1] - off[n];
    rinv[n] = 1.f / fmaxf((float)d, 1.f);
  }
}

// ---- f32 -> f16 copy (8 elems/thread) --------------------------------------
__global__ void k_conv16(const float* __restrict__ x, _Float16* __restrict__ y,
                         int n8) {
  int i = blockIdx.x * 256 + threadIdx.x;
  if (i >= n8) return;
  const float4* p = (const float4*)x;
  float4 a = p[2 * i], b = p[2 * i + 1];
  f16x8 o;
  o[0] = (_Float16)a.x; o[1] = (_Float16)a.y; o[2] = (_Float16)a.z; o[3] = (_Float16)a.w;
  o[4] = (_Float16)b.x; o[5] = (_Float16)b.y; o[6] = (_Float16)b.z; o[7] = (_Float16)b.w;
  ((f16x8*)y)[i] = o;
}

// ---- merged gather: per node n (half-wave): hsum (fwd ea), hid (rev tmp),
// ---- xsum0 (ent16[src] over ALL list entries), degrev -----------------------
__global__ __launch_bounds__(256) void k_gath_h(
    const _Float16* __restrict__ ea16, const _Float16* __restrict__ tmp16,
    const _Float16* __restrict__ ent16,
    const int* __restrict__ eidA, const int* __restrict__ srcA,
    const int* __restrict__ off,
    _Float16* __restrict__ hsum16, _Float16* __restrict__ hid16,
    _Float16* __restrict__ xsum16, float* __restrict__ degrev) {
  int n = blockIdx.x * 8 + (threadIdx.x >> 5);
  if (n >= NV) return;
  int l = threadIdx.x & 31;
  float fs[8], hv[8], xs[8];
#pragma unroll
  for (int k2 = 0; k2 < 8; k2++) { fs[k2] = 0.f; hv[k2] = 0.f; xs[k2] = 0.f; }
  int o0 = off[n], o1 = off[n + 1];
  int dr = 0;
#pragma unroll 2
  for (int j = o0; j < o1; j++) {
    int de = eidA[j];
    int src = srcA[j];
    f16x8 xv = ((const f16x8*)(ent16 + (size_t)src * D))[l];
#pragma unroll
    for (int k2 = 0; k2 < 8; k2++) xs[k2] += (float)xv[k2];
    if (de < E) {
      f16x8 v = ((const f16x8*)(ea16 + (size_t)de * D))[l];
#pragma unroll
      for (int k2 = 0; k2 < 8; k2++) fs[k2] += (float)v[k2];
    } else {
      f16x8 v = ((const f16x8*)(tmp16 + (size_t)(de - E) * D))[l];
#pragma unroll
      for (int k2 = 0; k2 < 8; k2++) hv[k2] += (float)v[k2];
      dr++;
    }
  }
  f16x8 of, oh, ox;
#pragma unroll
  for (int k2 = 0; k2 < 8; k2++) {
    of[k2] = (_Float16)fs[k2]; oh[k2] = (_Float16)hv[k2]; ox[k2] = (_Float16)xs[k2];
  }
  ((f16x8*)(hsum16 + (size_t)n * D))[l] = of;
  ((f16x8*)(hid16 + (size_t)n * D))[l] = oh;
  ((f16x8*)(xsum16 + (size_t)n * D))[l] = ox;
  if (l == 0) degrev[n] = (float)dr;
}

// ---- layer-1 aggregate: agg16[n] = (sum_j x16[src_j] + hsum16[n])*rinv[n] --
__global__ __launch_bounds__(256) void k_agg(
    const _Float16* __restrict__ x16, const int* __restrict__ srcA,
    const int* __restrict__ off, const _Float16* __restrict__ hsum16,
    const float* __restrict__ rinv, _Float16* __restrict__ agg16) {
  int n = blockIdx.x * 8 + (threadIdx.x >> 5);
  if (n >= NV) return;
  int l = threadIdx.x & 31;
  f16x8 h = ((const f16x8*)(hsum16 + (size_t)n * D))[l];
  float s[8];
#pragma unroll
  for (int k2 = 0; k2 < 8; k2++) s[k2] = (float)h[k2];
  int o0 = off[n], o1 = off[n + 1];
#pragma unroll 4
  for (int j = o0; j < o1; j++) {
    int src = srcA[j];
    f16x8 v = ((const f16x8*)(x16 + (size_t)src * D))[l];
#pragma unroll
    for (int k2 = 0; k2 < 8; k2++) s[k2] += (float)v[k2];
  }
  float r = rinv[n];
  f16x8 o;
#pragma unroll
  for (int k2 = 0; k2 < 8; k2++) o[k2] = (_Float16)(s[k2] * r);
  ((f16x8*)(agg16 + (size_t)n * D))[l] = o;
}

// ---- weight prep: W[K][256] f32 -> Wf [K/8][256][8] f16 --------------------
__global__ __launch_bounds__(256) void k_wprep(const float* __restrict__ W,
                                               _Float16* __restrict__ Wf) {
  __shared__ float tl[32][260];
  int tid = threadIdx.x;
  int k0 = blockIdx.x * 32;
#pragma unroll
  for (int i = 0; i < 32; i++) tl[i][tid] = W[(size_t)(k0 + i) * 256 + tid];
  __syncthreads();
  f16x8* WfV = (f16x8*)Wf;
#pragma unroll
  for (int kg = 0; kg < 4; kg++) {
    f16x8 p;
#pragma unroll
    for (int j = 0; j < 8; j++) p[j] = (_Float16)tl[kg * 8 + j][tid];
    WfV[(size_t)((k0 >> 3) + kg) * 256 + tid] = p;
  }
}

// ---- qW[n] = q @ pred_W1[:256,n] + pred_b1[n] ------------------------------
__global__ void k_qw(const float* __restrict__ q, const float* __restrict__ W1,
                     const float* __restrict__ b1, float* __restrict__ qW) {
  __shared__ float ql[D];
  int n = threadIdx.x;
  ql[n] = q[n];
  __syncthreads();
  float s = b1[n];
  for (int k = 0; k < D; k++) s += ql[k] * W1[(size_t)k * D + n];
  qW[n] = s;
}

// ---- staging: one 64x64 f16 K-step tile into ldsbuf (8KB), src-XOR-swizzled
enum AM { AF16, AF16D };

template<int AMODE>
__device__ inline void stageA(const _Float16* __restrict__ A0,
                              const _Float16* __restrict__ A1,
                              int m0, int t, int tid, _Float16* ldsbuf) {
  const _Float16* src;
  int kbase;
  if (AMODE == AF16D && t >= 4) { src = A1; kbase = (t - 4) * 64; }
  else                          { src = A0; kbase = t * 64; }
  const int l  = tid & 63;
  const int w  = tid >> 6;
  const int r8 = l >> 3;                 // row within 8-row chunk
  const int kg = (l & 7) ^ r8;           // swizzled source k-group (0..7)
#pragma unroll
  for (int j = 0; j < 2; j++) {
    const int c = w * 2 + j;             // chunk 0..7 (8 rows, 1KB each)
    const int row = c * 8 + r8;
    gload16(src + (size_t)(m0 + row) * 256 + kbase + kg * 8,
            ldsbuf + c * 512);           // wave-uniform LDS base, lane*16B
  }
}

// ---- PROJ2 GEMM (unchanged round-9 core): dual-weight over ea16 ------------
__global__ __launch_bounds__(256, 2) void k_proj2(
    const _Float16* __restrict__ A0,
    const _Float16* __restrict__ Wf, const _Float16* __restrict__ Wf2,
    const float* __restrict__ bias, const float* __restrict__ qW,
    _Float16* __restrict__ o16a, _Float16* __restrict__ o16b, int M) {
  __shared__ _Float16 AS[2 * 4096];
  const int tid = threadIdx.x;
  const int w = tid >> 6;
  const int lane31 = tid & 31;
  const int hw = (tid >> 5) & 1;
  const int m0 = blockIdx.x * 64;
  const int col0 = (w << 6) + lane31;
  const int col1 = col0 + 32;
  const int sw = lane31 & 7;

  f32x16 acc[2][2], acc2[2][2];
#pragma unroll
  for (int a = 0; a < 2; a++)
#pragma unroll
    for (int b = 0; b < 2; b++)
#pragma unroll
      for (int i = 0; i < 16; i++) { acc[a][b][i] = 0.f; acc2[a][b][i] = 0.f; }

  const f16x8* WV  = (const f16x8*)Wf;
  const f16x8* WV2 = (const f16x8*)Wf2;

  stageA<AF16>(A0, nullptr, m0, 0, tid, AS);
  __syncthreads();
  for (int t = 0; t < 4; ++t) {
    const int k0 = t * 64;
    f16x8 wb0[4], wb1[4], wc0[4], wc1[4];
#pragma unroll
    for (int ks = 0; ks < 4; ks++) {
      const int kgl = 2 * ks + hw;
      size_t wi = (size_t)((k0 >> 3) + kgl) * 256;
      wb0[ks] = WV[wi + col0];  wb1[ks] = WV[wi + col1];
      wc0[ks] = WV2[wi + col0]; wc1[ks] = WV2[wi + col1];
    }
    __builtin_amdgcn_sched_barrier(0);
    if (t + 1 < 4) stageA<AF16>(A0, nullptr, m0, t + 1, tid, AS + ((t + 1) & 1) * 4096);
    __builtin_amdgcn_sched_barrier(0);
    const f16x8* cb = (const f16x8*)(AS + (t & 1) * 4096);
#pragma unroll
    for (int ks = 0; ks < 4; ks++) {
      const int kgl = 2 * ks + hw;
      f16x8 a0 = cb[lane31 * 8 + (kgl ^ sw)];
      f16x8 a1 = cb[(lane31 + 32) * 8 + (kgl ^ sw)];
      acc[0][0] = MFMA16(a0, wb0[ks], acc[0][0]);
      acc[0][1] = MFMA16(a0, wb1[ks], acc[0][1]);
      acc[1][0] = MFMA16(a1, wb0[ks], acc[1][0]);
      acc[1][1] = MFMA16(a1, wb1[ks], acc[1][1]);
      acc2[0][0] = MFMA16(a0, wc0[ks], acc2[0][0]);
      acc2[0][1] = MFMA16(a0, wc1[ks], acc2[0][1]);
      acc2[1][0] = MFMA16(a1, wc0[ks], acc2[1][0]);
      acc2[1][1] = MFMA16(a1, wc1[ks], acc2[1][1]);
    }
    __syncthreads();
  }
  float b0v = bias[col0], b1v = bias[col1];
  float q0 = qW[col0], q1 = qW[col1];
#pragma unroll
  for (int rf = 0; rf < 2; rf++)
#pragma unroll
    for (int g = 0; g < 4; g++)
#pragma unroll
      for (int qq = 0; qq < 4; qq++) {
        int row = m0 + 32 * rf + qq + 8 * g + 4 * hw;
        if (row < M) {
          o16a[(size_t)row * 256 + col0] =
              (_Float16)fmaxf(acc[rf][0][4 * g + qq] + b0v, 0.f);
          o16a[(size_t)row * 256 + col1] =
              (_Float16)fmaxf(acc[rf][1][4 * g + qq] + b1v, 0.f);
          o16b[(size_t)row * 256 + col0] = (_Float16)(acc2[rf][0][4 * g + qq] + q0);
          o16b[(size_t)row * 256 + col1] = (_Float16)(acc2[rf][1][4 * g + qq] + q1);
        }
      }
}

// ---- fused ADDC + sage0 ----------------------------------------------------
// P1: acc = hid16 @ Wpr2 (K=256); h = acc + hsum16 + degrev*b2 -> hsum16;
//     agg0 = (h + xsum16)*rinv -> LDS tiles (staged A layout).
// P2: out016 = relu([ent16 (staged) | agg0 (LDS)] @ sW0 + b0).
__global__ __launch_bounds__(256, 2) void k_fuse0(
    const _Float16* __restrict__ hid16, const _Float16* __restrict__ ent16,
    _Float16* __restrict__ hsum16, const _Float16* __restrict__ xsum16,
    const float* __restrict__ degrev, const float* __restrict__ rinv,
    const _Float16* __restrict__ Wpr2f, const float* __restrict__ bpr2,
    const _Float16* __restrict__ sW0f, const float* __restrict__ sb0,
    _Float16* __restrict__ out016, int M) {
  __shared__ _Float16 AS[2 * 4096];      // 16 KB staging dbuf
  __shared__ _Float16 AGG[4 * 4096];     // 32 KB: 4 K-tiles of agg0
  const int tid = threadIdx.x;
  const int w = tid >> 6;
  const int lane31 = tid & 31;
  const int hw = (tid >> 5) & 1;
  const int m0 = blockIdx.x * 64;
  const int col0 = (w << 6) + lane31;
  const int col1 = col0 + 32;
  const int sw = lane31 & 7;
  const int kgA = lane31 >> 3, kjA = lane31 & 7;

  f32x16 acc[2][2];
#pragma unroll
  for (int a = 0; a < 2; a++)
#pragma unroll
    for (int b = 0; b < 2; b++)
#pragma unroll
      for (int i = 0; i < 16; i++) acc[a][b][i] = 0.f;

  // ---- P1: hid16 @ Wpr2 ----
  {
    const f16x8* WV = (const f16x8*)Wpr2f;
    stageA<AF16>(hid16, nullptr, m0, 0, tid, AS);
    __syncthreads();
    for (int t = 0; t < 4; ++t) {
      const int k0 = t * 64;
      f16x8 wb0[4], wb1[4];
#pragma unroll
      for (int ks = 0; ks < 4; ks++) {
        const int kgl = 2 * ks + hw;
        size_t wi = (size_t)((k0 >> 3) + kgl) * 256;
        wb0[ks] = WV[wi + col0]; wb1[ks] = WV[wi + col1];
      }
      __builtin_amdgcn_sched_barrier(0);
      if (t + 1 < 4) stageA<AF16>(hid16, nullptr, m0, t + 1, tid, AS + ((t + 1) & 1) * 4096);
      __builtin_amdgcn_sched_barrier(0);
      const f16x8* cb = (const f16x8*)(AS + (t & 1) * 4096);
#pragma unroll
      for (int ks = 0; ks < 4; ks++) {
        const int kgl = 2 * ks + hw;
        f16x8 a0 = cb[lane31 * 8 + (kgl ^ sw)];
        f16x8 a1 = cb[(lane31 + 32) * 8 + (kgl ^ sw)];
        acc[0][0] = MFMA16(a0, wb0[ks], acc[0][0]);
        acc[0][1] = MFMA16(a0, wb1[ks], acc[0][1]);
        acc[1][0] = MFMA16(a1, wb0[ks], acc[1][0]);
        acc[1][1] = MFMA16(a1, wb1[ks], acc[1][1]);
      }
      __syncthreads();
    }
  }
  // prologue-stage P2 tile0 early (overlaps with epilogue below)
  stageA<AF16>(ent16, nullptr, m0, 0, tid, AS);
  // ---- P1 epilogue: hsum16 (global) + agg0 (LDS, staged layout) ----
  {
    float b0v = bpr2[col0], b1v = bpr2[col1];
    _Float16* AGGw = AGG + (w << 12);    // tile w (4096 f16)
#pragma unroll
    for (int rf = 0; rf < 2; rf++)
#pragma unroll
      for (int g = 0; g < 4; g++)
#pragma unroll
        for (int qq = 0; qq < 4; qq++) {
          int rowloc = 32 * rf + qq + 8 * g + 4 * hw;
          int row = m0 + rowloc;
          float a0 = 0.f, a1 = 0.f;
          if (row < M) {
            float dr = degrev[row], rv = rinv[row];
            size_t i0 = (size_t)row * 256 + col0;
            size_t i1 = (size_t)row * 256 + col1;
            float h0 = acc[rf][0][4 * g + qq] + (float)hsum16[i0] + dr * b0v;
            float h1 = acc[rf][1][4 * g + qq] + (float)hsum16[i1] + dr * b1v;
            hsum16[i0] = (_Float16)h0;
            hsum16[i1] = (_Float16)h1;
            a0 = (h0 + (float)xsum16[i0]) * rv;
            a1 = (h1 + (float)xsum16[i1]) * rv;
          }
          int rsw = rowloc & 7;
          AGGw[rowloc * 64 + ((kgA ^ rsw) << 3) + kjA] = (_Float16)a0;
          AGGw[rowloc * 64 + (((kgA + 4) ^ rsw) << 3) + kjA] = (_Float16)a1;
          acc[rf][0][4 * g + qq] = 0.f;
          acc[rf][1][4 * g + qq] = 0.f;
        }
  }
  __syncthreads();
  // ---- P2: [ent16 | agg0] @ sW0, K=512 ----
  {
    const f16x8* WV = (const f16x8*)sW0f;
    for (int tt = 0; tt < 8; ++tt) {
      f16x8 wb0[4], wb1[4];
#pragma unroll
      for (int ks = 0; ks < 4; ks++) {
        const int kgl = 2 * ks + hw;
        size_t wi = (size_t)(tt * 8 + kgl) * 256;
        wb0[ks] = WV[wi + col0]; wb1[ks] = WV[wi + col1];
      }
      __builtin_amdgcn_sched_barrier(0);
      if (tt + 1 < 4) stageA<AF16>(ent16, nullptr, m0, tt + 1, tid, AS + ((tt + 1) & 1) * 4096);
      __builtin_amdgcn_sched_barrier(0);
      const f16x8* cb = (tt < 4) ? (const f16x8*)(AS + (tt & 1) * 4096)
                                 : (const f16x8*)(AGG + ((tt - 4) << 12));
#pragma unroll
      for (int ks = 0; ks < 4; ks++) {
        const int kgl = 2 * ks + hw;
        f16x8 a0 = cb[lane31 * 8 + (kgl ^ sw)];
        f16x8 a1 = cb[(lane31 + 32) * 8 + (kgl ^ sw)];
        acc[0][0] = MFMA16(a0, wb0[ks], acc[0][0]);
        acc[0][1] = MFMA16(a0, wb1[ks], acc[0][1]);
        acc[1][0] = MFMA16(a1, wb0[ks], acc[1][0]);
        acc[1][1] = MFMA16(a1, wb1[ks], acc[1][1]);
      }
      __syncthreads();
    }
    float b0v = sb0[col0], b1v = sb0[col1];
#pragma unroll
    for (int rf = 0; rf < 2; rf++)
#pragma unroll
      for (int g = 0; g < 4; g++)
#pragma unroll
        for (int qq = 0; qq < 4; qq++) {
          int row = m0 + 32 * rf + qq + 8 * g + 4 * hw;
          if (row < M) {
            out016[(size_t)row * 256 + col0] =
                (_Float16)fmaxf(acc[rf][0][4 * g + qq] + b0v, 0.f);
            out016[(size_t)row * 256 + col1] =
                (_Float16)fmaxf(acc[rf][1][4 * g + qq] + b1v, 0.f);
          }
        }
  }
}

// ---- fused sage1 + HE2 -----------------------------------------------------
// P1: out116 = relu([out016|agg16] @ sW1 + b1) -> LDS tiles ONLY (no global).
// P2: HEh/HEt = [out016 (staged) | out116 (LDS)] @ {Wheh, Whet}.
__global__ __launch_bounds__(256, 2) void k_fuse1(
    const _Float16* __restrict__ out016, const _Float16* __restrict__ agg16,
    const _Float16* __restrict__ sW1f, const float* __restrict__ sb1,
    const _Float16* __restrict__ Whehf, const _Float16* __restrict__ Whetf,
    _Float16* __restrict__ HEh16, _Float16* __restrict__ HEt16, int M) {
  __shared__ _Float16 AS[2 * 4096];      // 16 KB staging dbuf
  __shared__ _Float16 OUT[4 * 4096];     // 32 KB: 4 K-tiles of out116
  const int tid = threadIdx.x;
  const int w = tid >> 6;
  const int lane31 = tid & 31;
  const int hw = (tid >> 5) & 1;
  const int m0 = blockIdx.x * 64;
  const int col0 = (w << 6) + lane31;
  const int col1 = col0 + 32;
  const int sw = lane31 & 7;
  const int kgA = lane31 >> 3, kjA = lane31 & 7;

  f32x16 acc[2][2], acc2[2][2];
#pragma unroll
  for (int a = 0; a < 2; a++)
#pragma unroll
    for (int b = 0; b < 2; b++)
#pragma unroll
      for (int i = 0; i < 16; i++) { acc[a][b][i] = 0.f; acc2[a][b][i] = 0.f; }

  // ---- P1: [out016|agg16] @ sW1, K=512 ----
  {
    const f16x8* WV = (const f16x8*)sW1f;
    stageA<AF16D>(out016, agg16, m0, 0, tid, AS);
    __syncthreads();
    for (int t = 0; t < 8; ++t) {
      f16x8 wb0[4], wb1[4];
#pragma unroll
      for (int ks = 0; ks < 4; ks++) {
        const int kgl = 2 * ks + hw;
        size_t wi = (size_t)(t * 8 + kgl) * 256;
        wb0[ks] = WV[wi + col0]; wb1[ks] = WV[wi + col1];
      }
      __builtin_amdgcn_sched_barrier(0);
      if (t + 1 < 8) stageA<AF16D>(out016, agg16, m0, t + 1, tid, AS + ((t + 1) & 1) * 4096);
      __builtin_amdgcn_sched_barrier(0);
      const f16x8* cb = (const f16x8*)(AS + (t & 1) * 4096);
#pragma unroll
      for (int ks = 0; ks < 4; ks++) {
        const int kgl = 2 * ks + hw;
        f16x8 a0 = cb[lane31 * 8 + (kgl ^ sw)];
        f16x8 a1 = cb[(lane31 + 32) * 8 + (kgl ^ sw)];
        acc[0][0] = MFMA16(a0, wb0[ks], acc[0][0]);
        acc[0][1] = MFMA16(a0, wb1[ks], acc[0][1]);
        acc[1][0] = MFMA16(a1, wb0[ks], acc[1][0]);
        acc[1][1] = MFMA16(a1, wb1[ks], acc[1][1]);
      }
      __syncthreads();
    }
  }
  // prologue-stage P2 tile0 early
  stageA<AF16>(out016, nullptr, m0, 0, tid, AS);
  // ---- P1 epilogue: out116 -> LDS tiles only ----
  {
    float b0v = sb1[col0], b1v = sb1[col1];
    _Float16* OUTw = OUT + (w << 12);
#pragma unroll
    for (int rf = 0; rf < 2; rf++)
#pragma unroll
      for (int g = 0; g < 4; g++)
#pragma unroll
        for (int qq = 0; qq < 4; qq++) {
          int rowloc = 32 * rf + qq + 8 * g + 4 * hw;
          float v0 = fmaxf(acc[rf][0][4 * g + qq] + b0v, 0.f);
          float v1 = fmaxf(acc[rf][1][4 * g + qq] + b1v, 0.f);
          int rsw = rowloc & 7;
          OUTw[rowloc * 64 + ((kgA ^ rsw) << 3) + kjA] = (_Float16)v0;
          OUTw[rowloc * 64 + (((kgA + 4) ^ rsw) << 3) + kjA] = (_Float16)v1;
          acc[rf][0][4 * g + qq] = 0.f;
          acc[rf][1][4 * g + qq] = 0.f;
        }
  }
  __syncthreads();
  // ---- P2: [out016 | out116] @ {Wheh, Whet}, K=512, dual ----
  {
    const f16x8* WV  = (const f16x8*)Whehf;
    const f16x8* WV2 = (const f16x8*)Whetf;
    for (int tt = 0; tt < 8; ++tt) {
      f16x8 wb0[4], wb1[4], wc0[4], wc1[4];
#pragma unroll
      for (int ks = 0; ks < 4; ks++) {
        const int kgl = 2 * ks + hw;
        size_t wi = (size_t)(tt * 8 + kgl) * 256;
        wb0[ks] = WV[wi + col0];  wb1[ks] = WV[wi + col1];
        wc0[ks] = WV2[wi + col0]; wc1[ks] = WV2[wi + col1];
      }
      __builtin_amdgcn_sched_barrier(0);
      if (tt + 1 < 4) stageA<AF16>(out016, nullptr, m0, tt + 1, tid, AS + ((tt + 1) & 1) * 4096);
      __builtin_amdgcn_sched_barrier(0);
      const f16x8* cb = (tt < 4) ? (const f16x8*)(AS + (tt & 1) * 4096)
                                 : (const f16x8*)(OUT + ((tt - 4) << 12));
#pragma unroll
      for (int ks = 0; ks < 4; ks++) {
        const int kgl = 2 * ks + hw;
        f16x8 a0 = cb[lane31 * 8 + (kgl ^ sw)];
        f16x8 a1 = cb[(lane31 + 32) * 8 + (kgl ^ sw)];
        acc[0][0] = MFMA16(a0, wb0[ks], acc[0][0]);
        acc[0][1] = MFMA16(a0, wb1[ks], acc[0][1]);
        acc[1][0] = MFMA16(a1, wb0[ks], acc[1][0]);
        acc[1][1] = MFMA16(a1, wb1[ks], acc[1][1]);
        acc2[0][0] = MFMA16(a0, wc0[ks], acc2[0][0]);
        acc2[0][1] = MFMA16(a0, wc1[ks], acc2[0][1]);
        acc2[1][0] = MFMA16(a1, wc0[ks], acc2[1][0]);
        acc2[1][1] = MFMA16(a1, wc1[ks], acc2[1][1]);
      }
      __syncthreads();
    }
#pragma unroll
    for (int rf = 0; rf < 2; rf++)
#pragma unroll
      for (int g = 0; g < 4; g++)
#pragma unroll
        for (int qq = 0; qq < 4; qq++) {
          int row = m0 + 32 * rf + qq + 8 * g + 4 * hw;
          if (row < M) {
            HEh16[(size_t)row * 256 + col0] = (_Float16)acc[rf][0][4 * g + qq];
            HEh16[(size_t)row * 256 + col1] = (_Float16)acc[rf][1][4 * g + qq];
            HEt16[(size_t)row * 256 + col0] = (_Float16)acc2[rf][0][4 * g + qq];
            HEt16[(size_t)row * 256 + col1] = (_Float16)acc2[rf][1][4 * g + qq];
          }
        }
  }
}

// ---- edge combine: one edge per half-wave (32 lanes x f16x8), loop-free ----
__global__ __launch_bounds__(256) void k_edge(
    const _Float16* __restrict__ ea2q, const _Float16* __restrict__ HEh,
    const _Float16* __restrict__ HEt, const int* __restrict__ ei32,
    const float* __restrict__ pW2, const float* __restrict__ pb2,
    const float* __restrict__ noise, float* __restrict__ dout) {
  int e = blockIdx.x * 8 + (threadIdx.x >> 5);
  int l = threadIdx.x & 31;
  int h = ei32[e], t = ei32[E + e];
  f16x8 a  = ((const f16x8*)(ea2q + (size_t)e * 256))[l];
  f16x8 hv = ((const f16x8*)(HEh + (size_t)h * 256))[l];
  f16x8 tv = ((const f16x8*)(HEt + (size_t)t * 256))[l];
  const float4* wp = (const float4*)(pW2 + l * 8);
  float4 w0 = wp[0], w1 = wp[1];
  float wv[8] = {w0.x, w0.y, w0.z, w0.w, w1.x, w1.y, w1.z, w1.w};
  float s = 0.f;
#pragma unroll
  for (int j = 0; j < 8; j++)
    s += fmaxf((float)a[j] + (float)hv[j] + (float)tv[j], 0.f) * wv[j];
#pragma unroll
  for (int m = 1; m <= 16; m <<= 1) s += __shfl_xor(s, m);
  if (l == 0) {
    float lg = s + pb2[0];
    float nz = noise[e];
    float rn = logf(nz) - logf(1.f - nz);
    dout[e] = lg;
    dout[E + e] = 1.f / (1.f + expf(-(lg + rn)));
  }
}

extern "C" void kernel_launch(void* const* d_in, const int* in_sizes, int n_in,
                              void* d_out, int out_size, void* d_ws, size_t ws_size,
                              hipStream_t stream) {
  const float* entity = (const float*)d_in[0];
  const float* ea     = (const float*)d_in[1];
  const float* q      = (const float*)d_in[2];
  const float* noise  = (const float*)d_in[3];
  const float* W_pr1  = (const float*)d_in[4];
  const float* b_pr1  = (const float*)d_in[5];
  const float* W_pr2  = (const float*)d_in[6];
  const float* b_pr2  = (const float*)d_in[7];
  const float* sW0    = (const float*)d_in[8];
  const float* sb0    = (const float*)d_in[9];
  const float* sW1    = (const float*)d_in[10];
  const float* sb1    = (const float*)d_in[11];
  const float* pW1    = (const float*)d_in[12];
  const float* pb1    = (const float*)d_in[13];
  const float* pW2    = (const float*)d_in[14];
  const float* pb2    = (const float*)d_in[15];
  const void*  ei_raw = d_in[16];

  char* ws = (char*)d_ws;
  const size_t EDH = (size_t)E * D * 2;    // 102.4 MB f16 edge matrix
  const size_t NDH = (size_t)NV * D * 2;   // 25.6 MB f16 node matrix
  const size_t PAD = 64 * 256 * 2;         // OOB tile-read slack (32 KB)
  size_t off_b = 0;
  char* r0  = ws + off_b; off_b += EDH + PAD;        // ea16
  char* r1a = ws + off_b; off_b += EDH + PAD;        // tmp16
  char* r1b = ws + off_b; off_b += EDH + PAD;        // ea2q16
  char* r2  = ws + off_b; off_b += 2 * NDH + PAD;    // hsum16 -> HEh16|HEt16
  char* r3  = ws + off_b; off_b += NDH + PAD;        // hid16 -> agg16
  char* r4  = ws + off_b; off_b += NDH + PAD;        // ent16
  char* r5  = ws + off_b; off_b += NDH + PAD;        // out016
  char* r6  = ws + off_b; off_b += NDH + PAD;        // xsum16
  auto alloc_w = [&](int K) { _Float16* p = (_Float16*)(ws + off_b);
                              off_b += (size_t)K * 256 * 2; return p; };
  _Float16* Wpr1f = alloc_w(256);
  _Float16* Wpr2f = alloc_w(256);
  _Float16* sW0f  = alloc_w(512);
  _Float16* sW1f  = alloc_w(512);
  _Float16* Whehf = alloc_w(512);
  _Float16* Whetf = alloc_w(512);
  _Float16* Weaf  = alloc_w(256);
  float* rinv   = (float*)(ws + off_b); off_b += (size_t)NV * 4;
  float* degrev = (float*)(ws + off_b); off_b += (size_t)NV * 4;
  float* qW     = (float*)(ws + off_b); off_b += 1024;
  int*   ei32   = (int*)(ws + off_b);   off_b += (size_t)TWOE * 4;
  int*   eidA   = (int*)(ws + off_b);   off_b += (size_t)TWOE * 4;
  int*   srcA   = (int*)(ws + off_b);   off_b += (size_t)TWOE * 4;
  int*   offA   = (int*)(ws + off_b);   off_b += (size_t)(NV + 1) * 4;
  int*   deg    = (int*)(ws + off_b);   off_b += (size_t)NV * 4;
  int*   cursor = (int*)(ws + off_b);   off_b += (size_t)NV * 4;
  int*   flag   = (int*)(ws + off_b);   off_b += 64;

  // lifetime aliases
  _Float16* ea16   = (_Float16*)r0;          // conv -> PROJ2/gath_h
  _Float16* tmp16  = (_Float16*)r1a;         // PROJ2 -> gath_h
  _Float16* ea2q16 = (_Float16*)r1b;         // PROJ2 -> k_edge
  _Float16* hsum16 = (_Float16*)r2;          // gath -> fuse0(in-place) -> agg1
  _Float16* HEh16  = (_Float16*)r2;          // fuse1 -> k_edge (hsum dead)
  _Float16* HEt16  = (_Float16*)(r2 + NDH);
  _Float16* hid16  = (_Float16*)r3;          // gath -> fuse0 P1
  _Float16* agg16  = (_Float16*)r3;          // k_agg -> fuse1 P1 (hid dead)
  _Float16* ent16  = (_Float16*)r4;          // conv -> gath/fuse0 P2
  _Float16* out016 = (_Float16*)r5;          // fuse0 -> agg1/fuse1
  _Float16* xsum16 = (_Float16*)r6;          // gath -> fuse0 epi

  // ---- indices & CSR ----
  k_detect<<<1, 256, 0, stream>>>(ei_raw, flag);
  k_convert<<<(TWOE + 255) / 256, 256, 0, stream>>>(ei_raw, flag, ei32);
  hipMemsetAsync(deg, 0, (size_t)NV * 4, stream);
  hipMemsetAsync(cursor, 0, (size_t)NV * 4, stream);
  k_deg<<<(TWOE + 255) / 256, 256, 0, stream>>>(ei32, deg);
  k_scan<<<1, 1024, 0, stream>>>(deg, offA);
  k_fill<<<(TWOE + 255) / 256, 256, 0, stream>>>(ei32, offA, cursor, eidA, srcA);
  k_rinv<<<(NV + 255) / 256, 256, 0, stream>>>(offA, rinv);

  // ---- weight prep + f16 shadows ----
  k_wprep<<<256 / 32, 256, 0, stream>>>(W_pr1, Wpr1f);
  k_wprep<<<256 / 32, 256, 0, stream>>>(W_pr2, Wpr2f);
  k_wprep<<<512 / 32, 256, 0, stream>>>(sW0, sW0f);
  k_wprep<<<512 / 32, 256, 0, stream>>>(sW1, sW1f);
  k_wprep<<<512 / 32, 256, 0, stream>>>(pW1 + 256 * 256, Whehf);
  k_wprep<<<512 / 32, 256, 0, stream>>>(pW1 + 1024 * 256, Whetf);
  k_wprep<<<256 / 32, 256, 0, stream>>>(pW1 + 768 * 256, Weaf);
  k_conv16<<<(NV * D / 8 + 255) / 256, 256, 0, stream>>>(entity, ent16, NV * D / 8);
  k_conv16<<<(E * D / 8 + 255) / 256, 256, 0, stream>>>(ea, ea16, E * D / 8);
  k_qw<<<1, 256, 0, stream>>>(q, pW1, pb1, qW);

  // ---- fused proj+EA2: tmp16 = relu(ea@Wpr1+b1); ea2q16 = ea@Wea + qW ----
  k_proj2<<<E / 64, 256, 0, stream>>>(ea16, Wpr1f, Weaf, b_pr1, qW,
                                      tmp16, ea2q16, E);

  // ---- merged gather: hsum16, hid16, xsum16, degrev ----
  k_gath_h<<<(NV + 7) / 8, 256, 0, stream>>>(
      ea16, tmp16, ent16, eidA, srcA, offA, hsum16, hid16, xsum16, degrev);

  // ---- fused ADDC + sage0 ----
  k_fuse0<<<(NV + 63) / 64, 256, 0, stream>>>(
      hid16, ent16, hsum16, xsum16, degrev, rinv, Wpr2f, b_pr2,
      sW0f, sb0, out016, NV);

  // ---- layer-1 aggregate ----
  k_agg<<<(NV + 7) / 8, 256, 0, stream>>>(out016, srcA, offA, hsum16, rinv, agg16);

  // ---- fused sage1 + HE2 ----
  k_fuse1<<<(NV + 63) / 64, 256, 0, stream>>>(
      out016, agg16, sW1f, sb1, Whehf, Whetf, HEh16, HEt16, NV);

  // ---- edge combine ----
  k_edge<<<E / 8, 256, 0, stream>>>(ea2q16, HEh16, HEt16, ei32, pW2, pb2, noise,
                                    (float*)d_out);
}

// Round 13
// 611.180 us; speedup vs baseline: 1.2191x; 1.0240x over previous
//
#include <hip/hip_runtime.h>
#include <math.h>

// FineGrainedRetriever round 13: occupancy round. PROJ2 dual-weight kernel split
// into two single-weight passes (blockIdx.y selects weight/epilogue): 64 acc
// AGPRs instead of 128 -> 3 waves/SIMD (launch_bounds(256,3)). k_fuse0 also
// bumped to 3 waves/SIMD (single-weight phases). fuse1 (dual P2, LDS-resident
// out116) stays at 2. Gathers / k_edge / CSR unchanged from round 12.

namespace {
constexpr int E    = 200000;
constexpr int NV   = 50000;
constexpr int D    = 256;
constexpr int TWOE = 2 * E;
}

typedef __attribute__((ext_vector_type(8))) _Float16 f16x8;
typedef __attribute__((ext_vector_type(4))) _Float16 f16x4;
typedef __attribute__((ext_vector_type(16))) float f32x16;

#define MFMA16(a, b, c) __builtin_amdgcn_mfma_f32_32x32x16_f16((a), (b), (c), 0, 0, 0)

typedef const __attribute__((address_space(1))) void* gas_t;
typedef __attribute__((address_space(3))) void* las_t;

__device__ inline void gload16(const void* g, void* l) {
  __builtin_amdgcn_global_load_lds((gas_t)g, (las_t)l, 16, 0, 0);
}

// ---- edge_index dtype probe (int64 vs int32) -------------------------------
__global__ void k_detect(const void* ei_raw, int* flag) {
  __shared__ int bad;
  if (threadIdx.x == 0) bad = 0;
  __syncthreads();
  const long long* p = (const long long*)ei_raw;
  long long v = p[threadIdx.x];
  if (v < 0 || v >= (long long)NV) atomicOr(&bad, 1);
  __syncthreads();
  if (threadIdx.x == 0) *flag = bad ? 0 : 1;  // 1 => int64
}

__global__ void k_convert(const void* ei_raw, const int* __restrict__ flag,
                          int* __restrict__ ei32) {
  int i = blockIdx.x * 256 + threadIdx.x;
  if (i >= TWOE) return;
  if (*flag) ei32[i] = (int)((const long long*)ei_raw)[i];
  else       ei32[i] = ((const int*)ei_raw)[i];
}

// ---- CSR build -------------------------------------------------------------
__global__ void k_deg(const int* __restrict__ ei32, int* __restrict__ deg) {
  int de = blockIdx.x * 256 + threadIdx.x;
  if (de >= TWOE) return;
  int dst = (de < E) ? ei32[E + de] : ei32[de - E];
  atomicAdd(&deg[dst], 1);
}

__global__ __launch_bounds__(1024) void k_scan(const int* __restrict__ deg,
                                               int* __restrict__ off) {
  __shared__ int wsum[16];
  __shared__ int carryS;
  int tid = threadIdx.x;
  int lane = tid & 63, wv = tid >> 6;
  if (tid == 0) carryS = 0;
  __syncthreads();
  for (int base = 0; base < NV; base += 1024) {
    int i = base + tid;
    int v = (i < NV) ? deg[i] : 0;
    int s = v;
#pragma unroll
    for (int d = 1; d < 64; d <<= 1) {
      int t = __shfl_up(s, d);
      if (lane >= d) s += t;
    }
    if (lane == 63) wsum[wv] = s;
    int carry = carryS;
    __syncthreads();
    if (wv == 0) {
      int ws = (lane < 16) ? wsum[lane] : 0;
#pragma unroll
      for (int d = 1; d < 16; d <<= 1) {
        int t = __shfl_up(ws, d);
        if (lane >= d) ws += t;
      }
      if (lane < 16) wsum[lane] = ws;
    }
    __syncthreads();
    int wexcl = (wv == 0) ? 0 : wsum[wv - 1];
    if (i < NV) off[i] = carry + wexcl + s - v;
    if (tid == 1023) carryS = carry + wsum[15];
    __syncthreads();
  }
  if (tid == 0) off[NV] = carryS;
}

__global__ void k_fill(const int* __restrict__ ei32, const int* __restrict__ off,
                       int* __restrict__ cursor, int* __restrict__ eidA,
                       int* __restrict__ srcA) {
  int de = blockIdx.x * 256 + threadIdx.x;
  if (de >= TWOE) return;
  int dst = (de < E) ? ei32[E + de] : ei32[de - E];
  int p = atomicAdd(&cursor[dst], 1);
  int idx = off[dst] + p;
  eidA[idx] = de;
  srcA[idx] = ei32[de];
}

__global__ void k_rinv(const int* __restrict__ off, float* __restrict__ rinv) {
  int n = blockIdx.x * 256 + threadIdx.x;
  if (n < NV) {
    int d = off[n + 1] - off[n];
    rinv[n] = 1.f / fmaxf((float)d, 1.f);
  }
}

// ---- f32 -> f16 copy (8 elems/thread) --------------------------------------
__global__ void k_conv16(const float* __restrict__ x, _Float16* __restrict__ y,
                         int n8) {
  int i = blockIdx.x * 256 + threadIdx.x;
  if (i >= n8) return;
  const float4* p = (const float4*)x;
  float4 a = p[2 * i], b = p[2 * i + 1];
  f16x8 o;
  o[0] = (_Float16)a.x; o[1] = (_Float16)a.y; o[2] = (_Float16)a.z; o[3] = (_Float16)a.w;
  o[4] = (_Float16)b.x; o[5] = (_Float16)b.y; o[6] = (_Float16)b.z; o[7] = (_Float16)b.w;
  ((f16x8*)y)[i] = o;
}

// ---- merged gather: per node n (half-wave): hsum (fwd ea), hid (rev tmp),
// ---- xsum0 (ent16[src] over ALL list entries), degrev -----------------------
__global__ __launch_bounds__(256) void k_gath_h(
    const _Float16* __restrict__ ea16, const _Float16* __restrict__ tmp16,
    const _Float16* __restrict__ ent16,
    const int* __restrict__ eidA, const int* __restrict__ srcA,
    const int* __restrict__ off,
    _Float16* __restrict__ hsum16, _Float16* __restrict__ hid16,
    _Float16* __restrict__ xsum16, float* __restrict__ degrev) {
  int n = blockIdx.x * 8 + (threadIdx.x >> 5);
  if (n >= NV) return;
  int l = threadIdx.x & 31;
  float fs[8], hv[8], xs[8];
#pragma unroll
  for (int k2 = 0; k2 < 8; k2++) { fs[k2] = 0.f; hv[k2] = 0.f; xs[k2] = 0.f; }
  int o0 = off[n], o1 = off[n + 1];
  int dr = 0;
#pragma unroll 2
  for (int j = o0; j < o1; j++) {
    int de = eidA[j];
    int src = srcA[j];
    f16x8 xv = ((const f16x8*)(ent16 + (size_t)src * D))[l];
#pragma unroll
    for (int k2 = 0; k2 < 8; k2++) xs[k2] += (float)xv[k2];
    if (de < E) {
      f16x8 v = ((const f16x8*)(ea16 + (size_t)de * D))[l];
#pragma unroll
      for (int k2 = 0; k2 < 8; k2++) fs[k2] += (float)v[k2];
    } else {
      f16x8 v = ((const f16x8*)(tmp16 + (size_t)(de - E) * D))[l];
#pragma unroll
      for (int k2 = 0; k2 < 8; k2++) hv[k2] += (float)v[k2];
      dr++;
    }
  }
  f16x8 of, oh, ox;
#pragma unroll
  for (int k2 = 0; k2 < 8; k2++) {
    of[k2] = (_Float16)fs[k2]; oh[k2] = (_Float16)hv[k2]; ox[k2] = (_Float16)xs[k2];
  }
  ((f16x8*)(hsum16 + (size_t)n * D))[l] = of;
  ((f16x8*)(hid16 + (size_t)n * D))[l] = oh;
  ((f16x8*)(xsum16 + (size_t)n * D))[l] = ox;
  if (l == 0) degrev[n] = (float)dr;
}

// ---- layer-1 aggregate: agg16[n] = (sum_j x16[src_j] + hsum16[n])*rinv[n] --
__global__ __launch_bounds__(256) void k_agg(
    const _Float16* __restrict__ x16, const int* __restrict__ srcA,
    const int* __restrict__ off, const _Float16* __restrict__ hsum16,
    const float* __restrict__ rinv, _Float16* __restrict__ agg16) {
  int n = blockIdx.x * 8 + (threadIdx.x >> 5);
  if (n >= NV) return;
  int l = threadIdx.x & 31;
  f16x8 h = ((const f16x8*)(hsum16 + (size_t)n * D))[l];
  float s[8];
#pragma unroll
  for (int k2 = 0; k2 < 8; k2++) s[k2] = (float)h[k2];
  int o0 = off[n], o1 = off[n + 1];
#pragma unroll 4
  for (int j = o0; j < o1; j++) {
    int src = srcA[j];
    f16x8 v = ((const f16x8*)(x16 + (size_t)src * D))[l];
#pragma unroll
    for (int k2 = 0; k2 < 8; k2++) s[k2] += (float)v[k2];
  }
  float r = rinv[n];
  f16x8 o;
#pragma unroll
  for (int k2 = 0; k2 < 8; k2++) o[k2] = (_Float16)(s[k2] * r);
  ((f16x8*)(agg16 + (size_t)n * D))[l] = o;
}

// ---- weight prep: W[K][256] f32 -> Wf [K/8][256][8] f16 --------------------
__global__ __launch_bounds__(256) void k_wprep(const float* __restrict__ W,
                                               _Float16* __restrict__ Wf) {
  __shared__ float tl[32][260];
  int tid = threadIdx.x;
  int k0 = blockIdx.x * 32;
#pragma unroll
  for (int i = 0; i < 32; i++) tl[i][tid] = W[(size_t)(k0 + i) * 256 + tid];
  __syncthreads();
  f16x8* WfV = (f16x8*)Wf;
#pragma unroll
  for (int kg = 0; kg < 4; kg++) {
    f16x8 p;
#pragma unroll
    for (int j = 0; j < 8; j++) p[j] = (_Float16)tl[kg * 8 + j][tid];
    WfV[(size_t)((k0 >> 3) + kg) * 256 + tid] = p;
  }
}

// ---- qW[n] = q @ pred_W1[:256,n] + pred_b1[n] ------------------------------
__global__ void k_qw(const float* __restrict__ q, const float* __restrict__ W1,
                     const float* __restrict__ b1, float* __restrict__ qW) {
  __shared__ float ql[D];
  int n = threadIdx.x;
  ql[n] = q[n];
  __syncthreads();
  float s = b1[n];
  for (int k = 0; k < D; k++) s += ql[k] * W1[(size_t)k * D + n];
  qW[n] = s;
}

// ---- staging: one 64x64 f16 K-step tile into ldsbuf (8KB), src-XOR-swizzled
enum AM { AF16, AF16D };

template<int AMODE>
__device__ inline void stageA(const _Float16* __restrict__ A0,
                              const _Float16* __restrict__ A1,
                              int m0, int t, int tid, _Float16* ldsbuf) {
  const _Float16* src;
  int kbase;
  if (AMODE == AF16D && t >= 4) { src = A1; kbase = (t - 4) * 64; }
  else                          { src = A0; kbase = t * 64; }
  const int l  = tid & 63;
  const int w  = tid >> 6;
  const int r8 = l >> 3;                 // row within 8-row chunk
  const int kg = (l & 7) ^ r8;           // swizzled source k-group (0..7)
#pragma unroll
  for (int j = 0; j < 2; j++) {
    const int c = w * 2 + j;             // chunk 0..7 (8 rows, 1KB each)
    const int row = c * 8 + r8;
    gload16(src + (size_t)(m0 + row) * 256 + kbase + kg * 8,
            ldsbuf + c * 512);           // wave-uniform LDS base, lane*16B
  }
}

// ---- proj single-weight GEMM (blockIdx.y selects weight/epilogue) ----------
// y=0: tmp16 = relu(ea16 @ Wpr1 + b_pr1);  y=1: ea2q16 = ea16 @ Wea + qW.
__global__ __launch_bounds__(256, 3) void k_proj1w(
    const _Float16* __restrict__ A0,
    const _Float16* __restrict__ Wf0, const _Float16* __restrict__ Wf1,
    const float* __restrict__ bias, const float* __restrict__ qW,
    _Float16* __restrict__ o16a, _Float16* __restrict__ o16b, int M) {
  __shared__ _Float16 AS[2 * 4096];
  const int tid = threadIdx.x;
  const int w = tid >> 6;
  const int lane31 = tid & 31;
  const int hw = (tid >> 5) & 1;
  const int m0 = blockIdx.x * 64;
  const int y = blockIdx.y;
  const int col0 = (w << 6) + lane31;
  const int col1 = col0 + 32;
  const int sw = lane31 & 7;

  f32x16 acc[2][2];
#pragma unroll
  for (int a = 0; a < 2; a++)
#pragma unroll
    for (int b = 0; b < 2; b++)
#pragma unroll
      for (int i = 0; i < 16; i++) acc[a][b][i] = 0.f;

  const f16x8* WV = (const f16x8*)(y == 0 ? Wf0 : Wf1);

  stageA<AF16>(A0, nullptr, m0, 0, tid, AS);
  __syncthreads();
  for (int t = 0; t < 4; ++t) {
    const int k0 = t * 64;
    f16x8 wb0[4], wb1[4];
#pragma unroll
    for (int ks = 0; ks < 4; ks++) {
      const int kgl = 2 * ks + hw;
      size_t wi = (size_t)((k0 >> 3) + kgl) * 256;
      wb0[ks] = WV[wi + col0]; wb1[ks] = WV[wi + col1];
    }
    __builtin_amdgcn_sched_barrier(0);
    if (t + 1 < 4) stageA<AF16>(A0, nullptr, m0, t + 1, tid, AS + ((t + 1) & 1) * 4096);
    __builtin_amdgcn_sched_barrier(0);
    const f16x8* cb = (const f16x8*)(AS + (t & 1) * 4096);
#pragma unroll
    for (int ks = 0; ks < 4; ks++) {
      const int kgl = 2 * ks + hw;
      f16x8 a0 = cb[lane31 * 8 + (kgl ^ sw)];
      f16x8 a1 = cb[(lane31 + 32) * 8 + (kgl ^ sw)];
      acc[0][0] = MFMA16(a0, wb0[ks], acc[0][0]);
      acc[0][1] = MFMA16(a0, wb1[ks], acc[0][1]);
      acc[1][0] = MFMA16(a1, wb0[ks], acc[1][0]);
      acc[1][1] = MFMA16(a1, wb1[ks], acc[1][1]);
    }
    __syncthreads();
  }
  if (y == 0) {
    float b0v = bias[col0], b1v = bias[col1];
#pragma unroll
    for (int rf = 0; rf < 2; rf++)
#pragma unroll
      for (int g = 0; g < 4; g++)
#pragma unroll
        for (int qq = 0; qq < 4; qq++) {
          int row = m0 + 32 * rf + qq + 8 * g + 4 * hw;
          if (row < M) {
            o16a[(size_t)row * 256 + col0] =
                (_Float16)fmaxf(acc[rf][0][4 * g + qq] + b0v, 0.f);
            o16a[(size_t)row * 256 + col1] =
                (_Float16)fmaxf(acc[rf][1][4 * g + qq] + b1v, 0.f);
          }
        }
  } else {
    float q0 = qW[col0], q1 = qW[col1];
#pragma unroll
    for (int rf = 0; rf < 2; rf++)
#pragma unroll
      for (int g = 0; g < 4; g++)
#pragma unroll
        for (int qq = 0; qq < 4; qq++) {
          int row = m0 + 32 * rf + qq + 8 * g + 4 * hw;
          if (row < M) {
            o16b[(size_t)row * 256 + col0] = (_Float16)(acc[rf][0][4 * g + qq] + q0);
            o16b[(size_t)row * 256 + col1] = (_Float16)(acc[rf][1][4 * g + qq] + q1);
          }
        }
  }
}

// ---- fused ADDC + sage0 (single-weight phases -> 3 waves/SIMD) -------------
__global__ __launch_bounds__(256, 3) void k_fuse0(
    const _Float16* __restrict__ hid16, const _Float16* __restrict__ ent16,
    _Float16* __restrict__ hsum16, const _Float16* __restrict__ xsum16,
    const float* __restrict__ degrev, const float* __restrict__ rinv,
    const _Float16* __restrict__ Wpr2f, const float* __restrict__ bpr2,
    const _Float16* __restrict__ sW0f, const float* __restrict__ sb0,
    _Float16* __restrict__ out016, int M) {
  __shared__ _Float16 AS[2 * 4096];      // 16 KB staging dbuf
  __shared__ _Float16 AGG[4 * 4096];     // 32 KB: 4 K-tiles of agg0
  const int tid = threadIdx.x;
  const int w = tid >> 6;
  const int lane31 = tid & 31;
  const int hw = (tid >> 5) & 1;
  const int m0 = blockIdx.x * 64;
  const int col0 = (w << 6) + lane31;
  const int col1 = col0 + 32;
  const int sw = lane31 & 7;
  const int kgA = lane31 >> 3, kjA = lane31 & 7;

  f32x16 acc[2][2];
#pragma unroll
  for (int a = 0; a < 2; a++)
#pragma unroll
    for (int b = 0; b < 2; b++)
#pragma unroll
      for (int i = 0; i < 16; i++) acc[a][b][i] = 0.f;

  // ---- P1: hid16 @ Wpr2 ----
  {
    const f16x8* WV = (const f16x8*)Wpr2f;
    stageA<AF16>(hid16, nullptr, m0, 0, tid, AS);
    __syncthreads();
    for (int t = 0; t < 4; ++t) {
      const int k0 = t * 64;
      f16x8 wb0[4], wb1[4];
#pragma unroll
      for (int ks = 0; ks < 4; ks++) {
        const int kgl = 2 * ks + hw;
        size_t wi = (size_t)((k0 >> 3) + kgl) * 256;
        wb0[ks] = WV[wi + col0]; wb1[ks] = WV[wi + col1];
      }
      __builtin_amdgcn_sched_barrier(0);
      if (t + 1 < 4) stageA<AF16>(hid16, nullptr, m0, t + 1, tid, AS + ((t + 1) & 1) * 4096);
      __builtin_amdgcn_sched_barrier(0);
      const f16x8* cb = (const f16x8*)(AS + (t & 1) * 4096);
#pragma unroll
      for (int ks = 0; ks < 4; ks++) {
        const int kgl = 2 * ks + hw;
        f16x8 a0 = cb[lane31 * 8 + (kgl ^ sw)];
        f16x8 a1 = cb[(lane31 + 32) * 8 + (kgl ^ sw)];
        acc[0][0] = MFMA16(a0, wb0[ks], acc[0][0]);
        acc[0][1] = MFMA16(a0, wb1[ks], acc[0][1]);
        acc[1][0] = MFMA16(a1, wb0[ks], acc[1][0]);
        acc[1][1] = MFMA16(a1, wb1[ks], acc[1][1]);
      }
      __syncthreads();
    }
  }
  // prologue-stage P2 tile0 early (overlaps with epilogue below)
  stageA<AF16>(ent16, nullptr, m0, 0, tid, AS);
  // ---- P1 epilogue: hsum16 (global) + agg0 (LDS, staged layout) ----
  {
    float b0v = bpr2[col0], b1v = bpr2[col1];
    _Float16* AGGw = AGG + (w << 12);    // tile w (4096 f16)
#pragma unroll
    for (int rf = 0; rf < 2; rf++)
#pragma unroll
      for (int g = 0; g < 4; g++)
#pragma unroll
        for (int qq = 0; qq < 4; qq++) {
          int rowloc = 32 * rf + qq + 8 * g + 4 * hw;
          int row = m0 + rowloc;
          float a0 = 0.f, a1 = 0.f;
          if (row < M) {
            float dr = degrev[row], rv = rinv[row];
            size_t i0 = (size_t)row * 256 + col0;
            size_t i1 = (size_t)row * 256 + col1;
            float h0 = acc[rf][0][4 * g + qq] + (float)hsum16[i0] + dr * b0v;
            float h1 = acc[rf][1][4 * g + qq] + (float)hsum16[i1] + dr * b1v;
            hsum16[i0] = (_Float16)h0;
            hsum16[i1] = (_Float16)h1;
            a0 = (h0 + (float)xsum16[i0]) * rv;
            a1 = (h1 + (float)xsum16[i1]) * rv;
          }
          int rsw = rowloc & 7;
          AGGw[rowloc * 64 + ((kgA ^ rsw) << 3) + kjA] = (_Float16)a0;
          AGGw[rowloc * 64 + (((kgA + 4) ^ rsw) << 3) + kjA] = (_Float16)a1;
          acc[rf][0][4 * g + qq] = 0.f;
          acc[rf][1][4 * g + qq] = 0.f;
        }
  }
  __syncthreads();
  // ---- P2: [ent16 | agg0] @ sW0, K=512 ----
  {
    const f16x8* WV = (const f16x8*)sW0f;
    for (int tt = 0; tt < 8; ++tt) {
      f16x8 wb0[4], wb1[4];
#pragma unroll
      for (int ks = 0; ks < 4; ks++) {
        const int kgl = 2 * ks + hw;
        size_t wi = (size_t)(tt * 8 + kgl) * 256;
        wb0[ks] = WV[wi + col0]; wb1[ks] = WV[wi + col1];
      }
      __builtin_amdgcn_sched_barrier(0);
      if (tt + 1 < 4) stageA<AF16>(ent16, nullptr, m0, tt + 1, tid, AS + ((tt + 1) & 1) * 4096);
      __builtin_amdgcn_sched_barrier(0);
      const f16x8* cb = (tt < 4) ? (const f16x8*)(AS + (tt & 1) * 4096)
                                 : (const f16x8*)(AGG + ((tt - 4) << 12));
#pragma unroll
      for (int ks = 0; ks < 4; ks++) {
        const int kgl = 2 * ks + hw;
        f16x8 a0 = cb[lane31 * 8 + (kgl ^ sw)];
        f16x8 a1 = cb[(lane31 + 32) * 8 + (kgl ^ sw)];
        acc[0][0] = MFMA16(a0, wb0[ks], acc[0][0]);
        acc[0][1] = MFMA16(a0, wb1[ks], acc[0][1]);
        acc[1][0] = MFMA16(a1, wb0[ks], acc[1][0]);
        acc[1][1] = MFMA16(a1, wb1[ks], acc[1][1]);
      }
      __syncthreads();
    }
    float b0v = sb0[col0], b1v = sb0[col1];
#pragma unroll
    for (int rf = 0; rf < 2; rf++)
#pragma unroll
      for (int g = 0; g < 4; g++)
#pragma unroll
        for (int qq = 0; qq < 4; qq++) {
          int row = m0 + 32 * rf + qq + 8 * g + 4 * hw;
          if (row < M) {
            out016[(size_t)row * 256 + col0] =
                (_Float16)fmaxf(acc[rf][0][4 * g + qq] + b0v, 0.f);
            out016[(size_t)row * 256 + col1] =
                (_Float16)fmaxf(acc[rf][1][4 * g + qq] + b1v, 0.f);
          }
        }
  }
}

// ---- fused sage1 + HE2 (dual P2 -> stays 2 waves/SIMD) ---------------------
__global__ __launch_bounds__(256, 2) void k_fuse1(
    const _Float16* __restrict__ out016, const _Float16* __restrict__ agg16,
    const _Float16* __restrict__ sW1f, const float* __restrict__ sb1,
    const _Float16* __restrict__ Whehf, const _Float16* __restrict__ Whetf,
    _Float16* __restrict__ HEh16, _Float16* __restrict__ HEt16, int M) {
  __shared__ _Float16 AS[2 * 4096];      // 16 KB staging dbuf
  __shared__ _Float16 OUT[4 * 4096];     // 32 KB: 4 K-tiles of out116
  const int tid = threadIdx.x;
  const int w = tid >> 6;
  const int lane31 = tid & 31;
  const int hw = (tid >> 5) & 1;
  const int m0 = blockIdx.x * 64;
  const int col0 = (w << 6) + lane31;
  const int col1 = col0 + 32;
  const int sw = lane31 & 7;
  const int kgA = lane31 >> 3, kjA = lane31 & 7;

  f32x16 acc[2][2], acc2[2][2];
#pragma unroll
  for (int a = 0; a < 2; a++)
#pragma unroll
    for (int b = 0; b < 2; b++)
#pragma unroll
      for (int i = 0; i < 16; i++) { acc[a][b][i] = 0.f; acc2[a][b][i] = 0.f; }

  // ---- P1: [out016|agg16] @ sW1, K=512 ----
  {
    const f16x8* WV = (const f16x8*)sW1f;
    stageA<AF16D>(out016, agg16, m0, 0, tid, AS);
    __syncthreads();
    for (int t = 0; t < 8; ++t) {
      f16x8 wb0[4], wb1[4];
#pragma unroll
      for (int ks = 0; ks < 4; ks++) {
        const int kgl = 2 * ks + hw;
        size_t wi = (size_t)(t * 8 + kgl) * 256;
        wb0[ks] = WV[wi + col0]; wb1[ks] = WV[wi + col1];
      }
      __builtin_amdgcn_sched_barrier(0);
      if (t + 1 < 8) stageA<AF16D>(out016, agg16, m0, t + 1, tid, AS + ((t + 1) & 1) * 4096);
      __builtin_amdgcn_sched_barrier(0);
      const f16x8* cb = (const f16x8*)(AS + (t & 1) * 4096);
#pragma unroll
      for (int ks = 0; ks < 4; ks++) {
        const int kgl = 2 * ks + hw;
        f16x8 a0 = cb[lane31 * 8 + (kgl ^ sw)];
        f16x8 a1 = cb[(lane31 + 32) * 8 + (kgl ^ sw)];
        acc[0][0] = MFMA16(a0, wb0[ks], acc[0][0]);
        acc[0][1] = MFMA16(a0, wb1[ks], acc[0][1]);
        acc[1][0] = MFMA16(a1, wb0[ks], acc[1][0]);
        acc[1][1] = MFMA16(a1, wb1[ks], acc[1][1]);
      }
      __syncthreads();
    }
  }
  // prologue-stage P2 tile0 early
  stageA<AF16>(out016, nullptr, m0, 0, tid, AS);
  // ---- P1 epilogue: out116 -> LDS tiles only ----
  {
    float b0v = sb1[col0], b1v = sb1[col1];
    _Float16* OUTw = OUT + (w << 12);
#pragma unroll
    for (int rf = 0; rf < 2; rf++)
#pragma unroll
      for (int g = 0; g < 4; g++)
#pragma unroll
        for (int qq = 0; qq < 4; qq++) {
          int rowloc = 32 * rf + qq + 8 * g + 4 * hw;
          float v0 = fmaxf(acc[rf][0][4 * g + qq] + b0v, 0.f);
          float v1 = fmaxf(acc[rf][1][4 * g + qq] + b1v, 0.f);
          int rsw = rowloc & 7;
          OUTw[rowloc * 64 + ((kgA ^ rsw) << 3) + kjA] = (_Float16)v0;
          OUTw[rowloc * 64 + (((kgA + 4) ^ rsw) << 3) + kjA] = (_Float16)v1;
          acc[rf][0][4 * g + qq] = 0.f;
          acc[rf][1][4 * g + qq] = 0.f;
        }
  }
  __syncthreads();
  // ---- P2: [out016 | out116] @ {Wheh, Whet}, K=512, dual ----
  {
    const f16x8* WV  = (const f16x8*)Whehf;
    const f16x8* WV2 = (const f16x8*)Whetf;
    for (int tt = 0; tt < 8; ++tt) {
      f16x8 wb0[4], wb1[4], wc0[4], wc1[4];
#pragma unroll
      for (int ks = 0; ks < 4; ks++) {
        const int kgl = 2 * ks + hw;
        size_t wi = (size_t)(tt * 8 + kgl) * 256;
        wb0[ks] = WV[wi + col0];  wb1[ks] = WV[wi + col1];
        wc0[ks] = WV2[wi + col0]; wc1[ks] = WV2[wi + col1];
      }
      __builtin_amdgcn_sched_barrier(0);
      if (tt + 1 < 4) stageA<AF16>(out016, nullptr, m0, tt + 1, tid, AS + ((tt + 1) & 1) * 4096);
      __builtin_amdgcn_sched_barrier(0);
      const f16x8* cb = (tt < 4) ? (const f16x8*)(AS + (tt & 1) * 4096)
                                 : (const f16x8*)(OUT + ((tt - 4) << 12));
#pragma unroll
      for (int ks = 0; ks < 4; ks++) {
        const int kgl = 2 * ks + hw;
        f16x8 a0 = cb[lane31 * 8 + (kgl ^ sw)];
        f16x8 a1 = cb[(lane31 + 32) * 8 + (kgl ^ sw)];
        acc[0][0] = MFMA16(a0, wb0[ks], acc[0][0]);
        acc[0][1] = MFMA16(a0, wb1[ks], acc[0][1]);
        acc[1][0] = MFMA16(a1, wb0[ks], acc[1][0]);
        acc[1][1] = MFMA16(a1, wb1[ks], acc[1][1]);
        acc2[0][0] = MFMA16(a0, wc0[ks], acc2[0][0]);
        acc2[0][1] = MFMA16(a0, wc1[ks], acc2[0][1]);
        acc2[1][0] = MFMA16(a1, wc0[ks], acc2[1][0]);
        acc2[1][1] = MFMA16(a1, wc1[ks], acc2[1][1]);
      }
      __syncthreads();
    }
#pragma unroll
    for (int rf = 0; rf < 2; rf++)
#pragma unroll
      for (int g = 0; g < 4; g++)
#pragma unroll
        for (int qq = 0; qq < 4; qq++) {
          int row = m0 + 32 * rf + qq + 8 * g + 4 * hw;
          if (row < M) {
            HEh16[(size_t)row * 256 + col0] = (_Float16)acc[rf][0][4 * g + qq];
            HEh16[(size_t)row * 256 + col1] = (_Float16)acc[rf][1][4 * g + qq];
            HEt16[(size_t)row * 256 + col0] = (_Float16)acc2[rf][0][4 * g + qq];
            HEt16[(size_t)row * 256 + col1] = (_Float16)acc2[rf][1][4 * g + qq];
          }
        }
  }
}

// ---- edge combine: one edge per half-wave (32 lanes x f16x8), loop-free ----
__global__ __launch_bounds__(256) void k_edge(
    const _Float16* __restrict__ ea2q, const _Float16* __restrict__ HEh,
    const _Float16* __restrict__ HEt, const int* __restrict__ ei32,
    const float* __restrict__ pW2, const float* __restrict__ pb2,
    const float* __restrict__ noise, float* __restrict__ dout) {
  int e = blockIdx.x * 8 + (threadIdx.x >> 5);
  int l = threadIdx.x & 31;
  int h = ei32[e], t = ei32[E + e];
  f16x8 a  = ((const f16x8*)(ea2q + (size_t)e * 256))[l];
  f16x8 hv = ((const f16x8*)(HEh + (size_t)h * 256))[l];
  f16x8 tv = ((const f16x8*)(HEt + (size_t)t * 256))[l];
  const float4* wp = (const float4*)(pW2 + l * 8);
  float4 w0 = wp[0], w1 = wp[1];
  float wv[8] = {w0.x, w0.y, w0.z, w0.w, w1.x, w1.y, w1.z, w1.w};
  float s = 0.f;
#pragma unroll
  for (int j = 0; j < 8; j++)
    s += fmaxf((float)a[j] + (float)hv[j] + (float)tv[j], 0.f) * wv[j];
#pragma unroll
  for (int m = 1; m <= 16; m <<= 1) s += __shfl_xor(s, m);
  if (l == 0) {
    float lg = s + pb2[0];
    float nz = noise[e];
    float rn = logf(nz) - logf(1.f - nz);
    dout[e] = lg;
    dout[E + e] = 1.f / (1.f + expf(-(lg + rn)));
  }
}

extern "C" void kernel_launch(void* const* d_in, const int* in_sizes, int n_in,
                              void* d_out, int out_size, void* d_ws, size_t ws_size,
                              hipStream_t stream) {
  const float* entity = (const float*)d_in[0];
  const float* ea     = (const float*)d_in[1];
  const float* q      = (const float*)d_in[2];
  const float* noise  = (const float*)d_in[3];
  const float* W_pr1  = (const float*)d_in[4];
  const float* b_pr1  = (const float*)d_in[5];
  const float* W_pr2  = (const float*)d_in[6];
  const float* b_pr2  = (const float*)d_in[7];
  const float* sW0    = (const float*)d_in[8];
  const float* sb0    = (const float*)d_in[9];
  const float* sW1    = (const float*)d_in[10];
  const float* sb1    = (const float*)d_in[11];
  const float* pW1    = (const float*)d_in[12];
  const float* pb1    = (const float*)d_in[13];
  const float* pW2    = (const float*)d_in[14];
  const float* pb2    = (const float*)d_in[15];
  const void*  ei_raw = d_in[16];

  char* ws = (char*)d_ws;
  const size_t EDH = (size_t)E * D * 2;    // 102.4 MB f16 edge matrix
  const size_t NDH = (size_t)NV * D * 2;   // 25.6 MB f16 node matrix
  const size_t PAD = 64 * 256 * 2;         // OOB tile-read slack (32 KB)
  size_t off_b = 0;
  char* r0  = ws + off_b; off_b += EDH + PAD;        // ea16
  char* r1a = ws + off_b; off_b += EDH + PAD;        // tmp16
  char* r1b = ws + off_b; off_b += EDH + PAD;        // ea2q16
  char* r2  = ws + off_b; off_b += 2 * NDH + PAD;    // hsum16 -> HEh16|HEt16
  char* r3  = ws + off_b; off_b += NDH + PAD;        // hid16 -> agg16
  char* r4  = ws + off_b; off_b += NDH + PAD;        // ent16
  char* r5  = ws + off_b; off_b += NDH + PAD;        // out016
  char* r6  = ws + off_b; off_b += NDH + PAD;        // xsum16
  auto alloc_w = [&](int K) { _Float16* p = (_Float16*)(ws + off_b);
                              off_b += (size_t)K * 256 * 2; return p; };
  _Float16* Wpr1f = alloc_w(256);
  _Float16* Wpr2f = alloc_w(256);
  _Float16* sW0f  = alloc_w(512);
  _Float16* sW1f  = alloc_w(512);
  _Float16* Whehf = alloc_w(512);
  _Float16* Whetf = alloc_w(512);
  _Float16* Weaf  = alloc_w(256);
  float* rinv   = (float*)(ws + off_b); off_b += (size_t)NV * 4;
  float* degrev = (float*)(ws + off_b); off_b += (size_t)NV * 4;
  float* qW     = (float*)(ws + off_b); off_b += 1024;
  int*   ei32   = (int*)(ws + off_b);   off_b += (size_t)TWOE * 4;
  int*   eidA   = (int*)(ws + off_b);   off_b += (size_t)TWOE * 4;
  int*   srcA   = (int*)(ws + off_b);   off_b += (size_t)TWOE * 4;
  int*   offA   = (int*)(ws + off_b);   off_b += (size_t)(NV + 1) * 4;
  int*   deg    = (int*)(ws + off_b);   off_b += (size_t)NV * 4;
  int*   cursor = (int*)(ws + off_b);   off_b += (size_t)NV * 4;
  int*   flag   = (int*)(ws + off_b);   off_b += 64;

  // lifetime aliases
  _Float16* ea16   = (_Float16*)r0;          // conv -> proj/gath_h
  _Float16* tmp16  = (_Float16*)r1a;         // proj(y=0) -> gath_h
  _Float16* ea2q16 = (_Float16*)r1b;         // proj(y=1) -> k_edge
  _Float16* hsum16 = (_Float16*)r2;          // gath -> fuse0(in-place) -> agg1
  _Float16* HEh16  = (_Float16*)r2;          // fuse1 -> k_edge (hsum dead)
  _Float16* HEt16  = (_Float16*)(r2 + NDH);
  _Float16* hid16  = (_Float16*)r3;          // gath -> fuse0 P1
  _Float16* agg16  = (_Float16*)r3;          // k_agg -> fuse1 P1 (hid dead)
  _Float16* ent16  = (_Float16*)r4;          // conv -> gath/fuse0 P2
  _Float16* out016 = (_Float16*)r5;          // fuse0 -> agg1/fuse1
  _Float16* xsum16 = (_Float16*)r6;          // gath -> fuse0 epi

  // ---- indices & CSR ----
  k_detect<<<1, 256, 0, stream>>>(ei_raw, flag);
  k_convert<<<(TWOE + 255) / 256, 256, 0, stream>>>(ei_raw, flag, ei32);
  hipMemsetAsync(deg, 0, (size_t)NV * 4, stream);
  hipMemsetAsync(cursor, 0, (size_t)NV * 4, stream);
  k_deg<<<(TWOE + 255) / 256, 256, 0, stream>>>(ei32, deg);
  k_scan<<<1, 1024, 0, stream>>>(deg, offA);
  k_fill<<<(TWOE + 255) / 256, 256, 0, stream>>>(ei32, offA, cursor, eidA, srcA);
  k_rinv<<<(NV + 255) / 256, 256, 0, stream>>>(offA, rinv);

  // ---- weight prep + f16 shadows ----
  k_wprep<<<256 / 32, 256, 0, stream>>>(W_pr1, Wpr1f);
  k_wprep<<<256 / 32, 256, 0, stream>>>(W_pr2, Wpr2f);
  k_wprep<<<512 / 32, 256, 0, stream>>>(sW0, sW0f);
  k_wprep<<<512 / 32, 256, 0, stream>>>(sW1, sW1f);
  k_wprep<<<512 / 32, 256, 0, stream>>>(pW1 + 256 * 256, Whehf);
  k_wprep<<<512 / 32, 256, 0, stream>>>(pW1 + 1024 * 256, Whetf);
  k_wprep<<<256 / 32, 256, 0, stream>>>(pW1 + 768 * 256, Weaf);
  k_conv16<<<(NV * D / 8 + 255) / 256, 256, 0, stream>>>(entity, ent16, NV * D / 8);
  k_conv16<<<(E * D / 8 + 255) / 256, 256, 0, stream>>>(ea, ea16, E * D / 8);
  k_qw<<<1, 256, 0, stream>>>(q, pW1, pb1, qW);

  // ---- proj single-weight x2: tmp16 (y=0), ea2q16 (y=1) ----
  k_proj1w<<<dim3(E / 64, 2), 256, 0, stream>>>(
      ea16, Wpr1f, Weaf, b_pr1, qW, tmp16, ea2q16, E);

  // ---- merged gather: hsum16, hid16, xsum16, degrev ----
  k_gath_h<<<(NV + 7) / 8, 256, 0, stream>>>(
      ea16, tmp16, ent16, eidA, srcA, offA, hsum16, hid16, xsum16, degrev);

  // ---- fused ADDC + sage0 ----
  k_fuse0<<<(NV + 63) / 64, 256, 0, stream>>>(
      hid16, ent16, hsum16, xsum16, degrev, rinv, Wpr2f, b_pr2,
      sW0f, sb0, out016, NV);

  // ---- layer-1 aggregate ----
  k_agg<<<(NV + 7) / 8, 256, 0, stream>>>(out016, srcA, offA, hsum16, rinv, agg16);

  // ---- fused sage1 + HE2 ----
  k_fuse1<<<(NV + 63) / 64, 256, 0, stream>>>(
      out016, agg16, sW1f, sb1, Whehf, Whetf, HEh16, HEt16, NV);

  // ---- edge combine ----
  k_edge<<<E / 8, 256, 0, stream>>>(ea2q16, HEh16, HEt16, ei32, pW2, pb2, noise,
                                    (float*)d_out);
}

// Round 14
// 603.915 us; speedup vs baseline: 1.2337x; 1.0120x over previous
//
#include <hip/hip_runtime.h>
#include <math.h>

// FineGrainedRetriever round 14: ea2q16 eliminated. The EA2 GEMM (depends only
// on ea16+qW) is deferred to pipeline end and fused with the edge combine:
// K-loop -> acc+qW dumped to a 32KB LDS tile -> per-half-wave gather of
// HEh/HEt + relu-dot(pW2) + sampling, all in one kernel at 3 waves/SIMD.
// Deletes k_edge + a 204MB L3 round-trip. Everything else = round 13.

namespace {
constexpr int E    = 200000;
constexpr int NV   = 50000;
constexpr int D    = 256;
constexpr int TWOE = 2 * E;
}

typedef __attribute__((ext_vector_type(8))) _Float16 f16x8;
typedef __attribute__((ext_vector_type(4))) _Float16 f16x4;
typedef __attribute__((ext_vector_type(16))) float f32x16;

#define MFMA16(a, b, c) __builtin_amdgcn_mfma_f32_32x32x16_f16((a), (b), (c), 0, 0, 0)

typedef const __attribute__((address_space(1))) void* gas_t;
typedef __attribute__((address_space(3))) void* las_t;

__device__ inline void gload16(const void* g, void* l) {
  __builtin_amdgcn_global_load_lds((gas_t)g, (las_t)l, 16, 0, 0);
}

// ---- edge_index dtype probe (int64 vs int32) -------------------------------
__global__ void k_detect(const void* ei_raw, int* flag) {
  __shared__ int bad;
  if (threadIdx.x == 0) bad = 0;
  __syncthreads();
  const long long* p = (const long long*)ei_raw;
  long long v = p[threadIdx.x];
  if (v < 0 || v >= (long long)NV) atomicOr(&bad, 1);
  __syncthreads();
  if (threadIdx.x == 0) *flag = bad ? 0 : 1;  // 1 => int64
}

__global__ void k_convert(const void* ei_raw, const int* __restrict__ flag,
                          int* __restrict__ ei32) {
  int i = blockIdx.x * 256 + threadIdx.x;
  if (i >= TWOE) return;
  if (*flag) ei32[i] = (int)((const long long*)ei_raw)[i];
  else       ei32[i] = ((const int*)ei_raw)[i];
}

// ---- CSR build -------------------------------------------------------------
__global__ void k_deg(const int* __restrict__ ei32, int* __restrict__ deg) {
  int de = blockIdx.x * 256 + threadIdx.x;
  if (de >= TWOE) return;
  int dst = (de < E) ? ei32[E + de] : ei32[de - E];
  atomicAdd(&deg[dst], 1);
}

__global__ __launch_bounds__(1024) void k_scan(const int* __restrict__ deg,
                                               int* __restrict__ off) {
  __shared__ int wsum[16];
  __shared__ int carryS;
  int tid = threadIdx.x;
  int lane = tid & 63, wv = tid >> 6;
  if (tid == 0) carryS = 0;
  __syncthreads();
  for (int base = 0; base < NV; base += 1024) {
    int i = base + tid;
    int v = (i < NV) ? deg[i] : 0;
    int s = v;
#pragma unroll
    for (int d = 1; d < 64; d <<= 1) {
      int t = __shfl_up(s, d);
      if (lane >= d) s += t;
    }
    if (lane == 63) wsum[wv] = s;
    int carry = carryS;
    __syncthreads();
    if (wv == 0) {
      int ws = (lane < 16) ? wsum[lane] : 0;
#pragma unroll
      for (int d = 1; d < 16; d <<= 1) {
        int t = __shfl_up(ws, d);
        if (lane >= d) ws += t;
      }
      if (lane < 16) wsum[lane] = ws;
    }
    __syncthreads();
    int wexcl = (wv == 0) ? 0 : wsum[wv - 1];
    if (i < NV) off[i] = carry + wexcl + s - v;
    if (tid == 1023) carryS = carry + wsum[15];
    __syncthreads();
  }
  if (tid == 0) off[NV] = carryS;
}

__global__ void k_fill(const int* __restrict__ ei32, const int* __restrict__ off,
                       int* __restrict__ cursor, int* __restrict__ eidA,
                       int* __restrict__ srcA) {
  int de = blockIdx.x * 256 + threadIdx.x;
  if (de >= TWOE) return;
  int dst = (de < E) ? ei32[E + de] : ei32[de - E];
  int p = atomicAdd(&cursor[dst], 1);
  int idx = off[dst] + p;
  eidA[idx] = de;
  srcA[idx] = ei32[de];
}

__global__ void k_rinv(const int* __restrict__ off, float* __restrict__ rinv) {
  int n = blockIdx.x * 256 + threadIdx.x;
  if (n < NV) {
    int d = off[n + 1] - off[n];
    rinv[n] = 1.f / fmaxf((float)d, 1.f);
  }
}

// ---- f32 -> f16 copy (8 elems/thread) --------------------------------------
__global__ void k_conv16(const float* __restrict__ x, _Float16* __restrict__ y,
                         int n8) {
  int i = blockIdx.x * 256 + threadIdx.x;
  if (i >= n8) return;
  const float4* p = (const float4*)x;
  float4 a = p[2 * i], b = p[2 * i + 1];
  f16x8 o;
  o[0] = (_Float16)a.x; o[1] = (_Float16)a.y; o[2] = (_Float16)a.z; o[3] = (_Float16)a.w;
  o[4] = (_Float16)b.x; o[5] = (_Float16)b.y; o[6] = (_Float16)b.z; o[7] = (_Float16)b.w;
  ((f16x8*)y)[i] = o;
}

// ---- merged gather: per node n (half-wave): hsum (fwd ea), hid (rev tmp),
// ---- xsum0 (ent16[src] over ALL list entries), degrev -----------------------
__global__ __launch_bounds__(256) void k_gath_h(
    const _Float16* __restrict__ ea16, const _Float16* __restrict__ tmp16,
    const _Float16* __restrict__ ent16,
    const int* __restrict__ eidA, const int* __restrict__ srcA,
    const int* __restrict__ off,
    _Float16* __restrict__ hsum16, _Float16* __restrict__ hid16,
    _Float16* __restrict__ xsum16, float* __restrict__ degrev) {
  int n = blockIdx.x * 8 + (threadIdx.x >> 5);
  if (n >= NV) return;
  int l = threadIdx.x & 31;
  float fs[8], hv[8], xs[8];
#pragma unroll
  for (int k2 = 0; k2 < 8; k2++) { fs[k2] = 0.f; hv[k2] = 0.f; xs[k2] = 0.f; }
  int o0 = off[n], o1 = off[n + 1];
  int dr = 0;
#pragma unroll 2
  for (int j = o0; j < o1; j++) {
    int de = eidA[j];
    int src = srcA[j];
    f16x8 xv = ((const f16x8*)(ent16 + (size_t)src * D))[l];
#pragma unroll
    for (int k2 = 0; k2 < 8; k2++) xs[k2] += (float)xv[k2];
    if (de < E) {
      f16x8 v = ((const f16x8*)(ea16 + (size_t)de * D))[l];
#pragma unroll
      for (int k2 = 0; k2 < 8; k2++) fs[k2] += (float)v[k2];
    } else {
      f16x8 v = ((const f16x8*)(tmp16 + (size_t)(de - E) * D))[l];
#pragma unroll
      for (int k2 = 0; k2 < 8; k2++) hv[k2] += (float)v[k2];
      dr++;
    }
  }
  f16x8 of, oh, ox;
#pragma unroll
  for (int k2 = 0; k2 < 8; k2++) {
    of[k2] = (_Float16)fs[k2]; oh[k2] = (_Float16)hv[k2]; ox[k2] = (_Float16)xs[k2];
  }
  ((f16x8*)(hsum16 + (size_t)n * D))[l] = of;
  ((f16x8*)(hid16 + (size_t)n * D))[l] = oh;
  ((f16x8*)(xsum16 + (size_t)n * D))[l] = ox;
  if (l == 0) degrev[n] = (float)dr;
}

// ---- layer-1 aggregate: agg16[n] = (sum_j x16[src_j] + hsum16[n])*rinv[n] --
__global__ __launch_bounds__(256) void k_agg(
    const _Float16* __restrict__ x16, const int* __restrict__ srcA,
    const int* __restrict__ off, const _Float16* __restrict__ hsum16,
    const float* __restrict__ rinv, _Float16* __restrict__ agg16) {
  int n = blockIdx.x * 8 + (threadIdx.x >> 5);
  if (n >= NV) return;
  int l = threadIdx.x & 31;
  f16x8 h = ((const f16x8*)(hsum16 + (size_t)n * D))[l];
  float s[8];
#pragma unroll
  for (int k2 = 0; k2 < 8; k2++) s[k2] = (float)h[k2];
  int o0 = off[n], o1 = off[n + 1];
#pragma unroll 4
  for (int j = o0; j < o1; j++) {
    int src = srcA[j];
    f16x8 v = ((const f16x8*)(x16 + (size_t)src * D))[l];
#pragma unroll
    for (int k2 = 0; k2 < 8; k2++) s[k2] += (float)v[k2];
  }
  float r = rinv[n];
  f16x8 o;
#pragma unroll
  for (int k2 = 0; k2 < 8; k2++) o[k2] = (_Float16)(s[k2] * r);
  ((f16x8*)(agg16 + (size_t)n * D))[l] = o;
}

// ---- weight prep: W[K][256] f32 -> Wf [K/8][256][8] f16 --------------------
__global__ __launch_bounds__(256) void k_wprep(const float* __restrict__ W,
                                               _Float16* __restrict__ Wf) {
  __shared__ float tl[32][260];
  int tid = threadIdx.x;
  int k0 = blockIdx.x * 32;
#pragma unroll
  for (int i = 0; i < 32; i++) tl[i][tid] = W[(size_t)(k0 + i) * 256 + tid];
  __syncthreads();
  f16x8* WfV = (f16x8*)Wf;
#pragma unroll
  for (int kg = 0; kg < 4; kg++) {
    f16x8 p;
#pragma unroll
    for (int j = 0; j < 8; j++) p[j] = (_Float16)tl[kg * 8 + j][tid];
    WfV[(size_t)((k0 >> 3) + kg) * 256 + tid] = p;
  }
}

// ---- qW[n] = q @ pred_W1[:256,n] + pred_b1[n] ------------------------------
__global__ void k_qw(const float* __restrict__ q, const float* __restrict__ W1,
                     const float* __restrict__ b1, float* __restrict__ qW) {
  __shared__ float ql[D];
  int n = threadIdx.x;
  ql[n] = q[n];
  __syncthreads();
  float s = b1[n];
  for (int k = 0; k < D; k++) s += ql[k] * W1[(size_t)k * D + n];
  qW[n] = s;
}

// ---- staging: one 64x64 f16 K-step tile into ldsbuf (8KB), src-XOR-swizzled
enum AM { AF16, AF16D };

template<int AMODE>
__device__ inline void stageA(const _Float16* __restrict__ A0,
                              const _Float16* __restrict__ A1,
                              int m0, int t, int tid, _Float16* ldsbuf) {
  const _Float16* src;
  int kbase;
  if (AMODE == AF16D && t >= 4) { src = A1; kbase = (t - 4) * 64; }
  else                          { src = A0; kbase = t * 64; }
  const int l  = tid & 63;
  const int w  = tid >> 6;
  const int r8 = l >> 3;                 // row within 8-row chunk
  const int kg = (l & 7) ^ r8;           // swizzled source k-group (0..7)
#pragma unroll
  for (int j = 0; j < 2; j++) {
    const int c = w * 2 + j;             // chunk 0..7 (8 rows, 1KB each)
    const int row = c * 8 + r8;
    gload16(src + (size_t)(m0 + row) * 256 + kbase + kg * 8,
            ldsbuf + c * 512);           // wave-uniform LDS base, lane*16B
  }
}

// ---- proj pass 1: tmp16 = relu(ea16 @ Wpr1 + b_pr1) ------------------------
__global__ __launch_bounds__(256, 3) void k_projt(
    const _Float16* __restrict__ A0, const _Float16* __restrict__ Wf,
    const float* __restrict__ bias, _Float16* __restrict__ o16, int M) {
  __shared__ _Float16 AS[2 * 4096];
  const int tid = threadIdx.x;
  const int w = tid >> 6;
  const int lane31 = tid & 31;
  const int hw = (tid >> 5) & 1;
  const int m0 = blockIdx.x * 64;
  const int col0 = (w << 6) + lane31;
  const int col1 = col0 + 32;
  const int sw = lane31 & 7;

  f32x16 acc[2][2];
#pragma unroll
  for (int a = 0; a < 2; a++)
#pragma unroll
    for (int b = 0; b < 2; b++)
#pragma unroll
      for (int i = 0; i < 16; i++) acc[a][b][i] = 0.f;

  const f16x8* WV = (const f16x8*)Wf;
  stageA<AF16>(A0, nullptr, m0, 0, tid, AS);
  __syncthreads();
  for (int t = 0; t < 4; ++t) {
    const int k0 = t * 64;
    f16x8 wb0[4], wb1[4];
#pragma unroll
    for (int ks = 0; ks < 4; ks++) {
      const int kgl = 2 * ks + hw;
      size_t wi = (size_t)((k0 >> 3) + kgl) * 256;
      wb0[ks] = WV[wi + col0]; wb1[ks] = WV[wi + col1];
    }
    __builtin_amdgcn_sched_barrier(0);
    if (t + 1 < 4) stageA<AF16>(A0, nullptr, m0, t + 1, tid, AS + ((t + 1) & 1) * 4096);
    __builtin_amdgcn_sched_barrier(0);
    const f16x8* cb = (const f16x8*)(AS + (t & 1) * 4096);
#pragma unroll
    for (int ks = 0; ks < 4; ks++) {
      const int kgl = 2 * ks + hw;
      f16x8 a0 = cb[lane31 * 8 + (kgl ^ sw)];
      f16x8 a1 = cb[(lane31 + 32) * 8 + (kgl ^ sw)];
      acc[0][0] = MFMA16(a0, wb0[ks], acc[0][0]);
      acc[0][1] = MFMA16(a0, wb1[ks], acc[0][1]);
      acc[1][0] = MFMA16(a1, wb0[ks], acc[1][0]);
      acc[1][1] = MFMA16(a1, wb1[ks], acc[1][1]);
    }
    __syncthreads();
  }
  float b0v = bias[col0], b1v = bias[col1];
#pragma unroll
  for (int rf = 0; rf < 2; rf++)
#pragma unroll
    for (int g = 0; g < 4; g++)
#pragma unroll
      for (int qq = 0; qq < 4; qq++) {
        int row = m0 + 32 * rf + qq + 8 * g + 4 * hw;
        if (row < M) {
          o16[(size_t)row * 256 + col0] =
              (_Float16)fmaxf(acc[rf][0][4 * g + qq] + b0v, 0.f);
          o16[(size_t)row * 256 + col1] =
              (_Float16)fmaxf(acc[rf][1][4 * g + qq] + b1v, 0.f);
        }
      }
}

// ---- proj pass 2 + edge combine: EA2 GEMM -> LDS -> gather+dot+sample ------
__global__ __launch_bounds__(256, 3) void k_projedge(
    const _Float16* __restrict__ A0, const _Float16* __restrict__ Wf,
    const float* __restrict__ qW,
    const _Float16* __restrict__ HEh, const _Float16* __restrict__ HEt,
    const int* __restrict__ ei32, const float* __restrict__ pW2,
    const float* __restrict__ pb2, const float* __restrict__ noise,
    float* __restrict__ dout) {
  __shared__ _Float16 AS[2 * 4096];      // 16 KB staging dbuf
  __shared__ _Float16 ELDS[64 * 256];    // 32 KB EA2 tile
  __shared__ int ehS[64], etS[64];
  const int tid = threadIdx.x;
  const int w = tid >> 6;
  const int lane31 = tid & 31;
  const int hw = (tid >> 5) & 1;
  const int m0 = blockIdx.x * 64;        // edge base (E % 64 == 0)
  const int col0 = (w << 6) + lane31;
  const int col1 = col0 + 32;
  const int sw = lane31 & 7;

  if (tid < 64) { ehS[tid] = ei32[m0 + tid]; etS[tid] = ei32[E + m0 + tid]; }

  f32x16 acc[2][2];
#pragma unroll
  for (int a = 0; a < 2; a++)
#pragma unroll
    for (int b = 0; b < 2; b++)
#pragma unroll
      for (int i = 0; i < 16; i++) acc[a][b][i] = 0.f;

  const f16x8* WV = (const f16x8*)Wf;
  stageA<AF16>(A0, nullptr, m0, 0, tid, AS);
  __syncthreads();
  for (int t = 0; t < 4; ++t) {
    const int k0 = t * 64;
    f16x8 wb0[4], wb1[4];
#pragma unroll
    for (int ks = 0; ks < 4; ks++) {
      const int kgl = 2 * ks + hw;
      size_t wi = (size_t)((k0 >> 3) + kgl) * 256;
      wb0[ks] = WV[wi + col0]; wb1[ks] = WV[wi + col1];
    }
    __builtin_amdgcn_sched_barrier(0);
    if (t + 1 < 4) stageA<AF16>(A0, nullptr, m0, t + 1, tid, AS + ((t + 1) & 1) * 4096);
    __builtin_amdgcn_sched_barrier(0);
    const f16x8* cb = (const f16x8*)(AS + (t & 1) * 4096);
#pragma unroll
    for (int ks = 0; ks < 4; ks++) {
      const int kgl = 2 * ks + hw;
      f16x8 a0 = cb[lane31 * 8 + (kgl ^ sw)];
      f16x8 a1 = cb[(lane31 + 32) * 8 + (kgl ^ sw)];
      acc[0][0] = MFMA16(a0, wb0[ks], acc[0][0]);
      acc[0][1] = MFMA16(a0, wb1[ks], acc[0][1]);
      acc[1][0] = MFMA16(a1, wb0[ks], acc[1][0]);
      acc[1][1] = MFMA16(a1, wb1[ks], acc[1][1]);
    }
    __syncthreads();
  }
  // dump acc + qW into ELDS
  {
    float q0 = qW[col0], q1 = qW[col1];
#pragma unroll
    for (int rf = 0; rf < 2; rf++)
#pragma unroll
      for (int g = 0; g < 4; g++)
#pragma unroll
        for (int qq = 0; qq < 4; qq++) {
          int rowloc = 32 * rf + qq + 8 * g + 4 * hw;
          ELDS[rowloc * 256 + col0] = (_Float16)(acc[rf][0][4 * g + qq] + q0);
          ELDS[rowloc * 256 + col1] = (_Float16)(acc[rf][1][4 * g + qq] + q1);
        }
  }
  __syncthreads();
  // edge combine: half-wave per edge, 8 edges per half-wave
  const int hwv = tid >> 5;              // 0..7
  const int l = tid & 31;
  const float4* wp = (const float4*)(pW2 + l * 8);
  float4 w0 = wp[0], w1 = wp[1];
  float wv[8] = {w0.x, w0.y, w0.z, w0.w, w1.x, w1.y, w1.z, w1.w};
  float b2v = pb2[0];
#pragma unroll 2
  for (int i = 0; i < 8; i++) {
    int el = hwv * 8 + i;
    int h = ehS[el], t = etS[el];
    f16x8 a  = ((const f16x8*)(ELDS + el * 256))[l];
    f16x8 hv = ((const f16x8*)(HEh + (size_t)h * 256))[l];
    f16x8 tv = ((const f16x8*)(HEt + (size_t)t * 256))[l];
    float s = 0.f;
#pragma unroll
    for (int j = 0; j < 8; j++)
      s += fmaxf((float)a[j] + (float)hv[j] + (float)tv[j], 0.f) * wv[j];
#pragma unroll
    for (int m = 1; m <= 16; m <<= 1) s += __shfl_xor(s, m);
    if (l == 0) {
      int e = m0 + el;
      float lg = s + b2v;
      float nz = noise[e];
      float rn = logf(nz) - logf(1.f - nz);
      dout[e] = lg;
      dout[E + e] = 1.f / (1.f + expf(-(lg + rn)));
    }
  }
}

// ---- fused ADDC + sage0 (single-weight phases -> 3 waves/SIMD) -------------
__global__ __launch_bounds__(256, 3) void k_fuse0(
    const _Float16* __restrict__ hid16, const _Float16* __restrict__ ent16,
    _Float16* __restrict__ hsum16, const _Float16* __restrict__ xsum16,
    const float* __restrict__ degrev, const float* __restrict__ rinv,
    const _Float16* __restrict__ Wpr2f, const float* __restrict__ bpr2,
    const _Float16* __restrict__ sW0f, const float* __restrict__ sb0,
    _Float16* __restrict__ out016, int M) {
  __shared__ _Float16 AS[2 * 4096];      // 16 KB staging dbuf
  __shared__ _Float16 AGG[4 * 4096];     // 32 KB: 4 K-tiles of agg0
  const int tid = threadIdx.x;
  const int w = tid >> 6;
  const int lane31 = tid & 31;
  const int hw = (tid >> 5) & 1;
  const int m0 = blockIdx.x * 64;
  const int col0 = (w << 6) + lane31;
  const int col1 = col0 + 32;
  const int sw = lane31 & 7;
  const int kgA = lane31 >> 3, kjA = lane31 & 7;

  f32x16 acc[2][2];
#pragma unroll
  for (int a = 0; a < 2; a++)
#pragma unroll
    for (int b = 0; b < 2; b++)
#pragma unroll
      for (int i = 0; i < 16; i++) acc[a][b][i] = 0.f;

  // ---- P1: hid16 @ Wpr2 ----
  {
    const f16x8* WV = (const f16x8*)Wpr2f;
    stageA<AF16>(hid16, nullptr, m0, 0, tid, AS);
    __syncthreads();
    for (int t = 0; t < 4; ++t) {
      const int k0 = t * 64;
      f16x8 wb0[4], wb1[4];
#pragma unroll
      for (int ks = 0; ks < 4; ks++) {
        const int kgl = 2 * ks + hw;
        size_t wi = (size_t)((k0 >> 3) + kgl) * 256;
        wb0[ks] = WV[wi + col0]; wb1[ks] = WV[wi + col1];
      }
      __builtin_amdgcn_sched_barrier(0);
      if (t + 1 < 4) stageA<AF16>(hid16, nullptr, m0, t + 1, tid, AS + ((t + 1) & 1) * 4096);
      __builtin_amdgcn_sched_barrier(0);
      const f16x8* cb = (const f16x8*)(AS + (t & 1) * 4096);
#pragma unroll
      for (int ks = 0; ks < 4; ks++) {
        const int kgl = 2 * ks + hw;
        f16x8 a0 = cb[lane31 * 8 + (kgl ^ sw)];
        f16x8 a1 = cb[(lane31 + 32) * 8 + (kgl ^ sw)];
        acc[0][0] = MFMA16(a0, wb0[ks], acc[0][0]);
        acc[0][1] = MFMA16(a0, wb1[ks], acc[0][1]);
        acc[1][0] = MFMA16(a1, wb0[ks], acc[1][0]);
        acc[1][1] = MFMA16(a1, wb1[ks], acc[1][1]);
      }
      __syncthreads();
    }
  }
  // prologue-stage P2 tile0 early (overlaps with epilogue below)
  stageA<AF16>(ent16, nullptr, m0, 0, tid, AS);
  // ---- P1 epilogue: hsum16 (global) + agg0 (LDS, staged layout) ----
  {
    float b0v = bpr2[col0], b1v = bpr2[col1];
    _Float16* AGGw = AGG + (w << 12);    // tile w (4096 f16)
#pragma unroll
    for (int rf = 0; rf < 2; rf++)
#pragma unroll
      for (int g = 0; g < 4; g++)
#pragma unroll
        for (int qq = 0; qq < 4; qq++) {
          int rowloc = 32 * rf + qq + 8 * g + 4 * hw;
          int row = m0 + rowloc;
          float a0 = 0.f, a1 = 0.f;
          if (row < M) {
            float dr = degrev[row], rv = rinv[row];
            size_t i0 = (size_t)row * 256 + col0;
            size_t i1 = (size_t)row * 256 + col1;
            float h0 = acc[rf][0][4 * g + qq] + (float)hsum16[i0] + dr * b0v;
            float h1 = acc[rf][1][4 * g + qq] + (float)hsum16[i1] + dr * b1v;
            hsum16[i0] = (_Float16)h0;
            hsum16[i1] = (_Float16)h1;
            a0 = (h0 + (float)xsum16[i0]) * rv;
            a1 = (h1 + (float)xsum16[i1]) * rv;
          }
          int rsw = rowloc & 7;
          AGGw[rowloc * 64 + ((kgA ^ rsw) << 3) + kjA] = (_Float16)a0;
          AGGw[rowloc * 64 + (((kgA + 4) ^ rsw) << 3) + kjA] = (_Float16)a1;
          acc[rf][0][4 * g + qq] = 0.f;
          acc[rf][1][4 * g + qq] = 0.f;
        }
  }
  __syncthreads();
  // ---- P2: [ent16 | agg0] @ sW0, K=512 ----
  {
    const f16x8* WV = (const f16x8*)sW0f;
    for (int tt = 0; tt < 8; ++tt) {
      f16x8 wb0[4], wb1[4];
#pragma unroll
      for (int ks = 0; ks < 4; ks++) {
        const int kgl = 2 * ks + hw;
        size_t wi = (size_t)(tt * 8 + kgl) * 256;
        wb0[ks] = WV[wi + col0]; wb1[ks] = WV[wi + col1];
      }
      __builtin_amdgcn_sched_barrier(0);
      if (tt + 1 < 4) stageA<AF16>(ent16, nullptr, m0, tt + 1, tid, AS + ((tt + 1) & 1) * 4096);
      __builtin_amdgcn_sched_barrier(0);
      const f16x8* cb = (tt < 4) ? (const f16x8*)(AS + (tt & 1) * 4096)
                                 : (const f16x8*)(AGG + ((tt - 4) << 12));
#pragma unroll
      for (int ks = 0; ks < 4; ks++) {
        const int kgl = 2 * ks + hw;
        f16x8 a0 = cb[lane31 * 8 + (kgl ^ sw)];
        f16x8 a1 = cb[(lane31 + 32) * 8 + (kgl ^ sw)];
        acc[0][0] = MFMA16(a0, wb0[ks], acc[0][0]);
        acc[0][1] = MFMA16(a0, wb1[ks], acc[0][1]);
        acc[1][0] = MFMA16(a1, wb0[ks], acc[1][0]);
        acc[1][1] = MFMA16(a1, wb1[ks], acc[1][1]);
      }
      __syncthreads();
    }
    float b0v = sb0[col0], b1v = sb0[col1];
#pragma unroll
    for (int rf = 0; rf < 2; rf++)
#pragma unroll
      for (int g = 0; g < 4; g++)
#pragma unroll
        for (int qq = 0; qq < 4; qq++) {
          int row = m0 + 32 * rf + qq + 8 * g + 4 * hw;
          if (row < M) {
            out016[(size_t)row * 256 + col0] =
                (_Float16)fmaxf(acc[rf][0][4 * g + qq] + b0v, 0.f);
            out016[(size_t)row * 256 + col1] =
                (_Float16)fmaxf(acc[rf][1][4 * g + qq] + b1v, 0.f);
          }
        }
  }
}

// ---- fused sage1 + HE2 (dual P2 -> stays 2 waves/SIMD) ---------------------
__global__ __launch_bounds__(256, 2) void k_fuse1(
    const _Float16* __restrict__ out016, const _Float16* __restrict__ agg16,
    const _Float16* __restrict__ sW1f, const float* __restrict__ sb1,
    const _Float16* __restrict__ Whehf, const _Float16* __restrict__ Whetf,
    _Float16* __restrict__ HEh16, _Float16* __restrict__ HEt16, int M) {
  __shared__ _Float16 AS[2 * 4096];      // 16 KB staging dbuf
  __shared__ _Float16 OUT[4 * 4096];     // 32 KB: 4 K-tiles of out116
  const int tid = threadIdx.x;
  const int w = tid >> 6;
  const int lane31 = tid & 31;
  const int hw = (tid >> 5) & 1;
  const int m0 = blockIdx.x * 64;
  const int col0 = (w << 6) + lane31;
  const int col1 = col0 + 32;
  const int sw = lane31 & 7;
  const int kgA = lane31 >> 3, kjA = lane31 & 7;

  f32x16 acc[2][2], acc2[2][2];
#pragma unroll
  for (int a = 0; a < 2; a++)
#pragma unroll
    for (int b = 0; b < 2; b++)
#pragma unroll
      for (int i = 0; i < 16; i++) { acc[a][b][i] = 0.f; acc2[a][b][i] = 0.f; }

  // ---- P1: [out016|agg16] @ sW1, K=512 ----
  {
    const f16x8* WV = (const f16x8*)sW1f;
    stageA<AF16D>(out016, agg16, m0, 0, tid, AS);
    __syncthreads();
    for (int t = 0; t < 8; ++t) {
      f16x8 wb0[4], wb1[4];
#pragma unroll
      for (int ks = 0; ks < 4; ks++) {
        const int kgl = 2 * ks + hw;
        size_t wi = (size_t)(t * 8 + kgl) * 256;
        wb0[ks] = WV[wi + col0]; wb1[ks] = WV[wi + col1];
      }
      __builtin_amdgcn_sched_barrier(0);
      if (t + 1 < 8) stageA<AF16D>(out016, agg16, m0, t + 1, tid, AS + ((t + 1) & 1) * 4096);
      __builtin_amdgcn_sched_barrier(0);
      const f16x8* cb = (const f16x8*)(AS + (t & 1) * 4096);
#pragma unroll
      for (int ks = 0; ks < 4; ks++) {
        const int kgl = 2 * ks + hw;
        f16x8 a0 = cb[lane31 * 8 + (kgl ^ sw)];
        f16x8 a1 = cb[(lane31 + 32) * 8 + (kgl ^ sw)];
        acc[0][0] = MFMA16(a0, wb0[ks], acc[0][0]);
        acc[0][1] = MFMA16(a0, wb1[ks], acc[0][1]);
        acc[1][0] = MFMA16(a1, wb0[ks], acc[1][0]);
        acc[1][1] = MFMA16(a1, wb1[ks], acc[1][1]);
      }
      __syncthreads();
    }
  }
  // prologue-stage P2 tile0 early
  stageA<AF16>(out016, nullptr, m0, 0, tid, AS);
  // ---- P1 epilogue: out116 -> LDS tiles only ----
  {
    float b0v = sb1[col0], b1v = sb1[col1];
    _Float16* OUTw = OUT + (w << 12);
#pragma unroll
    for (int rf = 0; rf < 2; rf++)
#pragma unroll
      for (int g = 0; g < 4; g++)
#pragma unroll
        for (int qq = 0; qq < 4; qq++) {
          int rowloc = 32 * rf + qq + 8 * g + 4 * hw;
          float v0 = fmaxf(acc[rf][0][4 * g + qq] + b0v, 0.f);
          float v1 = fmaxf(acc[rf][1][4 * g + qq] + b1v, 0.f);
          int rsw = rowloc & 7;
          OUTw[rowloc * 64 + ((kgA ^ rsw) << 3) + kjA] = (_Float16)v0;
          OUTw[rowloc * 64 + (((kgA + 4) ^ rsw) << 3) + kjA] = (_Float16)v1;
          acc[rf][0][4 * g + qq] = 0.f;
          acc[rf][1][4 * g + qq] = 0.f;
        }
  }
  __syncthreads();
  // ---- P2: [out016 | out116] @ {Wheh, Whet}, K=512, dual ----
  {
    const f16x8* WV  = (const f16x8*)Whehf;
    const f16x8* WV2 = (const f16x8*)Whetf;
    for (int tt = 0; tt < 8; ++tt) {
      f16x8 wb0[4], wb1[4], wc0[4], wc1[4];
#pragma unroll
      for (int ks = 0; ks < 4; ks++) {
        const int kgl = 2 * ks + hw;
        size_t wi = (size_t)(tt * 8 + kgl) * 256;
        wb0[ks] = WV[wi + col0];  wb1[ks] = WV[wi + col1];
        wc0[ks] = WV2[wi + col0]; wc1[ks] = WV2[wi + col1];
      }
      __builtin_amdgcn_sched_barrier(0);
      if (tt + 1 < 4) stageA<AF16>(out016, nullptr, m0, tt + 1, tid, AS + ((tt + 1) & 1) * 4096);
      __builtin_amdgcn_sched_barrier(0);
      const f16x8* cb = (tt < 4) ? (const f16x8*)(AS + (tt & 1) * 4096)
                                 : (const f16x8*)(OUT + ((tt - 4) << 12));
#pragma unroll
      for (int ks = 0; ks < 4; ks++) {
        const int kgl = 2 * ks + hw;
        f16x8 a0 = cb[lane31 * 8 + (kgl ^ sw)];
        f16x8 a1 = cb[(lane31 + 32) * 8 + (kgl ^ sw)];
        acc[0][0] = MFMA16(a0, wb0[ks], acc[0][0]);
        acc[0][1] = MFMA16(a0, wb1[ks], acc[0][1]);
        acc[1][0] = MFMA16(a1, wb0[ks], acc[1][0]);
        acc[1][1] = MFMA16(a1, wb1[ks], acc[1][1]);
        acc2[0][0] = MFMA16(a0, wc0[ks], acc2[0][0]);
        acc2[0][1] = MFMA16(a0, wc1[ks], acc2[0][1]);
        acc2[1][0] = MFMA16(a1, wc0[ks], acc2[1][0]);
        acc2[1][1] = MFMA16(a1, wc1[ks], acc2[1][1]);
      }
      __syncthreads();
    }
#pragma unroll
    for (int rf = 0; rf < 2; rf++)
#pragma unroll
      for (int g = 0; g < 4; g++)
#pragma unroll
        for (int qq = 0; qq < 4; qq++) {
          int row = m0 + 32 * rf + qq + 8 * g + 4 * hw;
          if (row < M) {
            HEh16[(size_t)row * 256 + col0] = (_Float16)acc[rf][0][4 * g + qq];
            HEh16[(size_t)row * 256 + col1] = (_Float16)acc[rf][1][4 * g + qq];
            HEt16[(size_t)row * 256 + col0] = (_Float16)acc2[rf][0][4 * g + qq];
            HEt16[(size_t)row * 256 + col1] = (_Float16)acc2[rf][1][4 * g + qq];
          }
        }
  }
}

extern "C" void kernel_launch(void* const* d_in, const int* in_sizes, int n_in,
                              void* d_out, int out_size, void* d_ws, size_t ws_size,
                              hipStream_t stream) {
  const float* entity = (const float*)d_in[0];
  const float* ea     = (const float*)d_in[1];
  const float* q      = (const float*)d_in[2];
  const float* noise  = (const float*)d_in[3];
  const float* W_pr1  = (const float*)d_in[4];
  const float* b_pr1  = (const float*)d_in[5];
  const float* W_pr2  = (const float*)d_in[6];
  const float* b_pr2  = (const float*)d_in[7];
  const float* sW0    = (const float*)d_in[8];
  const float* sb0    = (const float*)d_in[9];
  const float* sW1    = (const float*)d_in[10];
  const float* sb1    = (const float*)d_in[11];
  const float* pW1    = (const float*)d_in[12];
  const float* pb1    = (const float*)d_in[13];
  const float* pW2    = (const float*)d_in[14];
  const float* pb2    = (const float*)d_in[15];
  const void*  ei_raw = d_in[16];

  char* ws = (char*)d_ws;
  const size_t EDH = (size_t)E * D * 2;    // 102.4 MB f16 edge matrix
  const size_t NDH = (size_t)NV * D * 2;   // 25.6 MB f16 node matrix
  const size_t PAD = 64 * 256 * 2;         // OOB tile-read slack (32 KB)
  size_t off_b = 0;
  char* r0  = ws + off_b; off_b += EDH + PAD;        // ea16
  char* r1a = ws + off_b; off_b += EDH + PAD;        // tmp16
  char* r2  = ws + off_b; off_b += 2 * NDH + PAD;    // hsum16 -> HEh16|HEt16
  char* r3  = ws + off_b; off_b += NDH + PAD;        // hid16 -> agg16
  char* r4  = ws + off_b; off_b += NDH + PAD;        // ent16
  char* r5  = ws + off_b; off_b += NDH + PAD;        // out016
  char* r6  = ws + off_b; off_b += NDH + PAD;        // xsum16
  auto alloc_w = [&](int K) { _Float16* p = (_Float16*)(ws + off_b);
                              off_b += (size_t)K * 256 * 2; return p; };
  _Float16* Wpr1f = alloc_w(256);
  _Float16* Wpr2f = alloc_w(256);
  _Float16* sW0f  = alloc_w(512);
  _Float16* sW1f  = alloc_w(512);
  _Float16* Whehf = alloc_w(512);
  _Float16* Whetf = alloc_w(512);
  _Float16* Weaf  = alloc_w(256);
  float* rinv   = (float*)(ws + off_b); off_b += (size_t)NV * 4;
  float* degrev = (float*)(ws + off_b); off_b += (size_t)NV * 4;
  float* qW     = (float*)(ws + off_b); off_b += 1024;
  int*   ei32   = (int*)(ws + off_b);   off_b += (size_t)TWOE * 4;
  int*   eidA   = (int*)(ws + off_b);   off_b += (size_t)TWOE * 4;
  int*   srcA   = (int*)(ws + off_b);   off_b += (size_t)TWOE * 4;
  int*   offA   = (int*)(ws + off_b);   off_b += (size_t)(NV + 1) * 4;
  int*   deg    = (int*)(ws + off_b);   off_b += (size_t)NV * 4;
  int*   cursor = (int*)(ws + off_b);   off_b += (size_t)NV * 4;
  int*   flag   = (int*)(ws + off_b);   off_b += 64;

  // lifetime aliases
  _Float16* ea16   = (_Float16*)r0;          // conv -> projt/gath_h/projedge
  _Float16* tmp16  = (_Float16*)r1a;         // projt -> gath_h
  _Float16* hsum16 = (_Float16*)r2;          // gath -> fuse0(in-place) -> agg1
  _Float16* HEh16  = (_Float16*)r2;          // fuse1 -> projedge (hsum dead)
  _Float16* HEt16  = (_Float16*)(r2 + NDH);
  _Float16* hid16  = (_Float16*)r3;          // gath -> fuse0 P1
  _Float16* agg16  = (_Float16*)r3;          // k_agg -> fuse1 P1 (hid dead)
  _Float16* ent16  = (_Float16*)r4;          // conv -> gath/fuse0 P2
  _Float16* out016 = (_Float16*)r5;          // fuse0 -> agg1/fuse1
  _Float16* xsum16 = (_Float16*)r6;          // gath -> fuse0 epi

  // ---- indices & CSR ----
  k_detect<<<1, 256, 0, stream>>>(ei_raw, flag);
  k_convert<<<(TWOE + 255) / 256, 256, 0, stream>>>(ei_raw, flag, ei32);
  hipMemsetAsync(deg, 0, (size_t)NV * 4, stream);
  hipMemsetAsync(cursor, 0, (size_t)NV * 4, stream);
  k_deg<<<(TWOE + 255) / 256, 256, 0, stream>>>(ei32, deg);
  k_scan<<<1, 1024, 0, stream>>>(deg, offA);
  k_fill<<<(TWOE + 255) / 256, 256, 0, stream>>>(ei32, offA, cursor, eidA, srcA);
  k_rinv<<<(NV + 255) / 256, 256, 0, stream>>>(offA, rinv);

  // ---- weight prep + f16 shadows ----
  k_wprep<<<256 / 32, 256, 0, stream>>>(W_pr1, Wpr1f);
  k_wprep<<<256 / 32, 256, 0, stream>>>(W_pr2, Wpr2f);
  k_wprep<<<512 / 32, 256, 0, stream>>>(sW0, sW0f);
  k_wprep<<<512 / 32, 256, 0, stream>>>(sW1, sW1f);
  k_wprep<<<512 / 32, 256, 0, stream>>>(pW1 + 256 * 256, Whehf);
  k_wprep<<<512 / 32, 256, 0, stream>>>(pW1 + 1024 * 256, Whetf);
  k_wprep<<<256 / 32, 256, 0, stream>>>(pW1 + 768 * 256, Weaf);
  k_conv16<<<(NV * D / 8 + 255) / 256, 256, 0, stream>>>(entity, ent16, NV * D / 8);
  k_conv16<<<(E * D / 8 + 255) / 256, 256, 0, stream>>>(ea, ea16, E * D / 8);
  k_qw<<<1, 256, 0, stream>>>(q, pW1, pb1, qW);

  // ---- proj pass 1: tmp16 = relu(ea16 @ Wpr1 + b_pr1) ----
  k_projt<<<E / 64, 256, 0, stream>>>(ea16, Wpr1f, b_pr1, tmp16, E);

  // ---- merged gather: hsum16, hid16, xsum16, degrev ----
  k_gath_h<<<(NV + 7) / 8, 256, 0, stream>>>(
      ea16, tmp16, ent16, eidA, srcA, offA, hsum16, hid16, xsum16, degrev);

  // ---- fused ADDC + sage0 ----
  k_fuse0<<<(NV + 63) / 64, 256, 0, stream>>>(
      hid16, ent16, hsum16, xsum16, degrev, rinv, Wpr2f, b_pr2,
      sW0f, sb0, out016, NV);

  // ---- layer-1 aggregate ----
  k_agg<<<(NV + 7) / 8, 256, 0, stream>>>(out016, srcA, offA, hsum16, rinv, agg16);

  // ---- fused sage1 + HE2 ----
  k_fuse1<<<(NV + 63) / 64, 256, 0, stream>>>(
      out016, agg16, sW1f, sb1, Whehf, Whetf, HEh16, HEt16, NV);

  // ---- proj pass 2 fused with edge combine + sampling ----
  k_projedge<<<E / 64, 256, 0, stream>>>(
      ea16, Weaf, qW, HEh16, HEt16, ei32, pW2, pb2, noise, (float*)d_out);
}

// Round 15
// 591.198 us; speedup vs baseline: 1.2603x; 1.0215x over previous
//
#include <hip/hip_runtime.h>
#include <math.h>

// FineGrainedRetriever round 15: ea->ea16 conversion pass fused into the proj
// GEMM (k_projea): reg-stage from f32 ea (raw loads issued after W-preload,
// converted+ds_written+stored to ea16 after the MFMA burst). Deletes the
// 307MB k_conv16(ea) copy pass. Everything else = round 14.

namespace {
constexpr int E    = 200000;
constexpr int NV   = 50000;
constexpr int D    = 256;
constexpr int TWOE = 2 * E;
}

typedef __attribute__((ext_vector_type(8))) _Float16 f16x8;
typedef __attribute__((ext_vector_type(4))) _Float16 f16x4;
typedef __attribute__((ext_vector_type(16))) float f32x16;

#define MFMA16(a, b, c) __builtin_amdgcn_mfma_f32_32x32x16_f16((a), (b), (c), 0, 0, 0)

typedef const __attribute__((address_space(1))) void* gas_t;
typedef __attribute__((address_space(3))) void* las_t;

__device__ inline void gload16(const void* g, void* l) {
  __builtin_amdgcn_global_load_lds((gas_t)g, (las_t)l, 16, 0, 0);
}

// ---- edge_index dtype probe (int64 vs int32) -------------------------------
__global__ void k_detect(const void* ei_raw, int* flag) {
  __shared__ int bad;
  if (threadIdx.x == 0) bad = 0;
  __syncthreads();
  const long long* p = (const long long*)ei_raw;
  long long v = p[threadIdx.x];
  if (v < 0 || v >= (long long)NV) atomicOr(&bad, 1);
  __syncthreads();
  if (threadIdx.x == 0) *flag = bad ? 0 : 1;  // 1 => int64
}

__global__ void k_convert(const void* ei_raw, const int* __restrict__ flag,
                          int* __restrict__ ei32) {
  int i = blockIdx.x * 256 + threadIdx.x;
  if (i >= TWOE) return;
  if (*flag) ei32[i] = (int)((const long long*)ei_raw)[i];
  else       ei32[i] = ((const int*)ei_raw)[i];
}

// ---- CSR build -------------------------------------------------------------
__global__ void k_deg(const int* __restrict__ ei32, int* __restrict__ deg) {
  int de = blockIdx.x * 256 + threadIdx.x;
  if (de >= TWOE) return;
  int dst = (de < E) ? ei32[E + de] : ei32[de - E];
  atomicAdd(&deg[dst], 1);
}

__global__ __launch_bounds__(1024) void k_scan(const int* __restrict__ deg,
                                               int* __restrict__ off) {
  __shared__ int wsum[16];
  __shared__ int carryS;
  int tid = threadIdx.x;
  int lane = tid & 63, wv = tid >> 6;
  if (tid == 0) carryS = 0;
  __syncthreads();
  for (int base = 0; base < NV; base += 1024) {
    int i = base + tid;
    int v = (i < NV) ? deg[i] : 0;
    int s = v;
#pragma unroll
    for (int d = 1; d < 64; d <<= 1) {
      int t = __shfl_up(s, d);
      if (lane >= d) s += t;
    }
    if (lane == 63) wsum[wv] = s;
    int carry = carryS;
    __syncthreads();
    if (wv == 0) {
      int ws = (lane < 16) ? wsum[lane] : 0;
#pragma unroll
      for (int d = 1; d < 16; d <<= 1) {
        int t = __shfl_up(ws, d);
        if (lane >= d) ws += t;
      }
      if (lane < 16) wsum[lane] = ws;
    }
    __syncthreads();
    int wexcl = (wv == 0) ? 0 : wsum[wv - 1];
    if (i < NV) off[i] = carry + wexcl + s - v;
    if (tid == 1023) carryS = carry + wsum[15];
    __syncthreads();
  }
  if (tid == 0) off[NV] = carryS;
}

__global__ void k_fill(const int* __restrict__ ei32, const int* __restrict__ off,
                       int* __restrict__ cursor, int* __restrict__ eidA,
                       int* __restrict__ srcA) {
  int de = blockIdx.x * 256 + threadIdx.x;
  if (de >= TWOE) return;
  int dst = (de < E) ? ei32[E + de] : ei32[de - E];
  int p = atomicAdd(&cursor[dst], 1);
  int idx = off[dst] + p;
  eidA[idx] = de;
  srcA[idx] = ei32[de];
}

__global__ void k_rinv(const int* __restrict__ off, float* __restrict__ rinv) {
  int n = blockIdx.x * 256 + threadIdx.x;
  if (n < NV) {
    int d = off[n + 1] - off[n];
    rinv[n] = 1.f / fmaxf((float)d, 1.f);
  }
}

// ---- f32 -> f16 copy (8 elems/thread) --------------------------------------
__global__ void k_conv16(const float* __restrict__ x, _Float16* __restrict__ y,
                         int n8) {
  int i = blockIdx.x * 256 + threadIdx.x;
  if (i >= n8) return;
  const float4* p = (const float4*)x;
  float4 a = p[2 * i], b = p[2 * i + 1];
  f16x8 o;
  o[0] = (_Float16)a.x; o[1] = (_Float16)a.y; o[2] = (_Float16)a.z; o[3] = (_Float16)a.w;
  o[4] = (_Float16)b.x; o[5] = (_Float16)b.y; o[6] = (_Float16)b.z; o[7] = (_Float16)b.w;
  ((f16x8*)y)[i] = o;
}

// ---- merged gather: per node n (half-wave): hsum (fwd ea), hid (rev tmp),
// ---- xsum0 (ent16[src] over ALL list entries), degrev -----------------------
__global__ __launch_bounds__(256) void k_gath_h(
    const _Float16* __restrict__ ea16, const _Float16* __restrict__ tmp16,
    const _Float16* __restrict__ ent16,
    const int* __restrict__ eidA, const int* __restrict__ srcA,
    const int* __restrict__ off,
    _Float16* __restrict__ hsum16, _Float16* __restrict__ hid16,
    _Float16* __restrict__ xsum16, float* __restrict__ degrev) {
  int n = blockIdx.x * 8 + (threadIdx.x >> 5);
  if (n >= NV) return;
  int l = threadIdx.x & 31;
  float fs[8], hv[8], xs[8];
#pragma unroll
  for (int k2 = 0; k2 < 8; k2++) { fs[k2] = 0.f; hv[k2] = 0.f; xs[k2] = 0.f; }
  int o0 = off[n], o1 = off[n + 1];
  int dr = 0;
#pragma unroll 2
  for (int j = o0; j < o1; j++) {
    int de = eidA[j];
    int src = srcA[j];
    f16x8 xv = ((const f16x8*)(ent16 + (size_t)src * D))[l];
#pragma unroll
    for (int k2 = 0; k2 < 8; k2++) xs[k2] += (float)xv[k2];
    if (de < E) {
      f16x8 v = ((const f16x8*)(ea16 + (size_t)de * D))[l];
#pragma unroll
      for (int k2 = 0; k2 < 8; k2++) fs[k2] += (float)v[k2];
    } else {
      f16x8 v = ((const f16x8*)(tmp16 + (size_t)(de - E) * D))[l];
#pragma unroll
      for (int k2 = 0; k2 < 8; k2++) hv[k2] += (float)v[k2];
      dr++;
    }
  }
  f16x8 of, oh, ox;
#pragma unroll
  for (int k2 = 0; k2 < 8; k2++) {
    of[k2] = (_Float16)fs[k2]; oh[k2] = (_Float16)hv[k2]; ox[k2] = (_Float16)xs[k2];
  }
  ((f16x8*)(hsum16 + (size_t)n * D))[l] = of;
  ((f16x8*)(hid16 + (size_t)n * D))[l] = oh;
  ((f16x8*)(xsum16 + (size_t)n * D))[l] = ox;
  if (l == 0) degrev[n] = (float)dr;
}

// ---- layer-1 aggregate: agg16[n] = (sum_j x16[src_j] + hsum16[n])*rinv[n] --
__global__ __launch_bounds__(256) void k_agg(
    const _Float16* __restrict__ x16, const int* __restrict__ srcA,
    const int* __restrict__ off, const _Float16* __restrict__ hsum16,
    const float* __restrict__ rinv, _Float16* __restrict__ agg16) {
  int n = blockIdx.x * 8 + (threadIdx.x >> 5);
  if (n >= NV) return;
  int l = threadIdx.x & 31;
  f16x8 h = ((const f16x8*)(hsum16 + (size_t)n * D))[l];
  float s[8];
#pragma unroll
  for (int k2 = 0; k2 < 8; k2++) s[k2] = (float)h[k2];
  int o0 = off[n], o1 = off[n + 1];
#pragma unroll 4
  for (int j = o0; j < o1; j++) {
    int src = srcA[j];
    f16x8 v = ((const f16x8*)(x16 + (size_t)src * D))[l];
#pragma unroll
    for (int k2 = 0; k2 < 8; k2++) s[k2] += (float)v[k2];
  }
  float r = rinv[n];
  f16x8 o;
#pragma unroll
  for (int k2 = 0; k2 < 8; k2++) o[k2] = (_Float16)(s[k2] * r);
  ((f16x8*)(agg16 + (size_t)n * D))[l] = o;
}

// ---- weight prep: W[K][256] f32 -> Wf [K/8][256][8] f16 --------------------
__global__ __launch_bounds__(256) void k_wprep(const float* __restrict__ W,
                                               _Float16* __restrict__ Wf) {
  __shared__ float tl[32][260];
  int tid = threadIdx.x;
  int k0 = blockIdx.x * 32;
#pragma unroll
  for (int i = 0; i < 32; i++) tl[i][tid] = W[(size_t)(k0 + i) * 256 + tid];
  __syncthreads();
  f16x8* WfV = (f16x8*)Wf;
#pragma unroll
  for (int kg = 0; kg < 4; kg++) {
    f16x8 p;
#pragma unroll
    for (int j = 0; j < 8; j++) p[j] = (_Float16)tl[kg * 8 + j][tid];
    WfV[(size_t)((k0 >> 3) + kg) * 256 + tid] = p;
  }
}

// ---- qW[n] = q @ pred_W1[:256,n] + pred_b1[n] ------------------------------
__global__ void k_qw(const float* __restrict__ q, const float* __restrict__ W1,
                     const float* __restrict__ b1, float* __restrict__ qW) {
  __shared__ float ql[D];
  int n = threadIdx.x;
  ql[n] = q[n];
  __syncthreads();
  float s = b1[n];
  for (int k = 0; k < D; k++) s += ql[k] * W1[(size_t)k * D + n];
  qW[n] = s;
}

// ---- staging: one 64x64 f16 K-step tile into ldsbuf (8KB), src-XOR-swizzled
enum AM { AF16, AF16D };

template<int AMODE>
__device__ inline void stageA(const _Float16* __restrict__ A0,
                              const _Float16* __restrict__ A1,
                              int m0, int t, int tid, _Float16* ldsbuf) {
  const _Float16* src;
  int kbase;
  if (AMODE == AF16D && t >= 4) { src = A1; kbase = (t - 4) * 64; }
  else                          { src = A0; kbase = t * 64; }
  const int l  = tid & 63;
  const int w  = tid >> 6;
  const int r8 = l >> 3;                 // row within 8-row chunk
  const int kg = (l & 7) ^ r8;           // swizzled source k-group (0..7)
#pragma unroll
  for (int j = 0; j < 2; j++) {
    const int c = w * 2 + j;             // chunk 0..7 (8 rows, 1KB each)
    const int row = c * 8 + r8;
    gload16(src + (size_t)(m0 + row) * 256 + kbase + kg * 8,
            ldsbuf + c * 512);           // wave-uniform LDS base, lane*16B
  }
}

// ---- fused proj + ea16 conversion: reg-stage from f32 ea -------------------
// tmp16 = relu(ea @ Wpr1 + b_pr1); ea16 = (f16)ea written as staging byproduct.
__global__ __launch_bounds__(256, 3) void k_projea(
    const float* __restrict__ ea, const _Float16* __restrict__ Wf,
    const float* __restrict__ bias, _Float16* __restrict__ tmp16,
    _Float16* __restrict__ ea16, int M) {
  __shared__ _Float16 AS[2 * 4096];
  const int tid = threadIdx.x;
  const int w = tid >> 6;
  const int lane31 = tid & 31;
  const int hw = (tid >> 5) & 1;
  const int m0 = blockIdx.x * 64;
  const int col0 = (w << 6) + lane31;
  const int col1 = col0 + 32;
  const int sw = lane31 & 7;
  // staging geometry (matches stageA's swizzle)
  const int l63 = tid & 63;
  const int r8 = l63 >> 3;
  const int kg = (l63 & 7) ^ r8;

  f32x16 acc[2][2];
#pragma unroll
  for (int a = 0; a < 2; a++)
#pragma unroll
    for (int b = 0; b < 2; b++)
#pragma unroll
      for (int i = 0; i < 16; i++) acc[a][b][i] = 0.f;

  const f16x8* WV = (const f16x8*)Wf;

  float4 ra[4];
  auto loadRaw = [&](int t) {
#pragma unroll
    for (int j = 0; j < 2; j++) {
      const int c = w * 2 + j;
      const int row = c * 8 + r8;
      const float4* src = (const float4*)(ea + (size_t)(m0 + row) * 256 + t * 64 + kg * 8);
      ra[2 * j]     = src[0];
      ra[2 * j + 1] = src[1];
    }
  };
  auto convStore = [&](int t, _Float16* buf) {
#pragma unroll
    for (int j = 0; j < 2; j++) {
      const int c = w * 2 + j;
      const int row = c * 8 + r8;
      f16x8 p;
      p[0] = (_Float16)ra[2 * j].x; p[1] = (_Float16)ra[2 * j].y;
      p[2] = (_Float16)ra[2 * j].z; p[3] = (_Float16)ra[2 * j].w;
      p[4] = (_Float16)ra[2 * j + 1].x; p[5] = (_Float16)ra[2 * j + 1].y;
      p[6] = (_Float16)ra[2 * j + 1].z; p[7] = (_Float16)ra[2 * j + 1].w;
      ((f16x8*)buf)[c * 64 + l63] = p;                                   // LDS (swizzled slot)
      *(f16x8*)(ea16 + (size_t)(m0 + row) * 256 + t * 64 + kg * 8) = p;  // linear shadow
    }
  };

  loadRaw(0);
  convStore(0, AS);
  __syncthreads();
  for (int t = 0; t < 4; ++t) {
    f16x8 wb0[4], wb1[4];
#pragma unroll
    for (int ks = 0; ks < 4; ks++) {
      const int kgl = 2 * ks + hw;
      size_t wi = (size_t)(t * 8 + kgl) * 256;
      wb0[ks] = WV[wi + col0]; wb1[ks] = WV[wi + col1];
    }
    __builtin_amdgcn_sched_barrier(0);
    if (t + 1 < 4) loadRaw(t + 1);      // raw f32 loads in flight across MFMA
    __builtin_amdgcn_sched_barrier(0);
    const f16x8* cb = (const f16x8*)(AS + (t & 1) * 4096);
#pragma unroll
    for (int ks = 0; ks < 4; ks++) {
      const int kgl = 2 * ks + hw;
      f16x8 a0 = cb[lane31 * 8 + (kgl ^ sw)];
      f16x8 a1 = cb[(lane31 + 32) * 8 + (kgl ^ sw)];
      acc[0][0] = MFMA16(a0, wb0[ks], acc[0][0]);
      acc[0][1] = MFMA16(a0, wb1[ks], acc[0][1]);
      acc[1][0] = MFMA16(a1, wb0[ks], acc[1][0]);
      acc[1][1] = MFMA16(a1, wb1[ks], acc[1][1]);
    }
    if (t + 1 < 4) convStore(t + 1, AS + ((t + 1) & 1) * 4096);
    __syncthreads();
  }
  float b0v = bias[col0], b1v = bias[col1];
#pragma unroll
  for (int rf = 0; rf < 2; rf++)
#pragma unroll
    for (int g = 0; g < 4; g++)
#pragma unroll
      for (int qq = 0; qq < 4; qq++) {
        int row = m0 + 32 * rf + qq + 8 * g + 4 * hw;
        if (row < M) {
          tmp16[(size_t)row * 256 + col0] =
              (_Float16)fmaxf(acc[rf][0][4 * g + qq] + b0v, 0.f);
          tmp16[(size_t)row * 256 + col1] =
              (_Float16)fmaxf(acc[rf][1][4 * g + qq] + b1v, 0.f);
        }
      }
}

// ---- proj pass 2 + edge combine: EA2 GEMM -> LDS -> gather+dot+sample ------
__global__ __launch_bounds__(256, 3) void k_projedge(
    const _Float16* __restrict__ A0, const _Float16* __restrict__ Wf,
    const float* __restrict__ qW,
    const _Float16* __restrict__ HEh, const _Float16* __restrict__ HEt,
    const int* __restrict__ ei32, const float* __restrict__ pW2,
    const float* __restrict__ pb2, const float* __restrict__ noise,
    float* __restrict__ dout) {
  __shared__ _Float16 AS[2 * 4096];      // 16 KB staging dbuf
  __shared__ _Float16 ELDS[64 * 256];    // 32 KB EA2 tile
  __shared__ int ehS[64], etS[64];
  const int tid = threadIdx.x;
  const int w = tid >> 6;
  const int lane31 = tid & 31;
  const int hw = (tid >> 5) & 1;
  const int m0 = blockIdx.x * 64;        // edge base (E % 64 == 0)
  const int col0 = (w << 6) + lane31;
  const int col1 = col0 + 32;
  const int sw = lane31 & 7;

  if (tid < 64) { ehS[tid] = ei32[m0 + tid]; etS[tid] = ei32[E + m0 + tid]; }

  f32x16 acc[2][2];
#pragma unroll
  for (int a = 0; a < 2; a++)
#pragma unroll
    for (int b = 0; b < 2; b++)
#pragma unroll
      for (int i = 0; i < 16; i++) acc[a][b][i] = 0.f;

  const f16x8* WV = (const f16x8*)Wf;
  stageA<AF16>(A0, nullptr, m0, 0, tid, AS);
  __syncthreads();
  for (int t = 0; t < 4; ++t) {
    const int k0 = t * 64;
    f16x8 wb0[4], wb1[4];
#pragma unroll
    for (int ks = 0; ks < 4; ks++) {
      const int kgl = 2 * ks + hw;
      size_t wi = (size_t)((k0 >> 3) + kgl) * 256;
      wb0[ks] = WV[wi + col0]; wb1[ks] = WV[wi + col1];
    }
    __builtin_amdgcn_sched_barrier(0);
    if (t + 1 < 4) stageA<AF16>(A0, nullptr, m0, t + 1, tid, AS + ((t + 1) & 1) * 4096);
    __builtin_amdgcn_sched_barrier(0);
    const f16x8* cb = (const f16x8*)(AS + (t & 1) * 4096);
#pragma unroll
    for (int ks = 0; ks < 4; ks++) {
      const int kgl = 2 * ks + hw;
      f16x8 a0 = cb[lane31 * 8 + (kgl ^ sw)];
      f16x8 a1 = cb[(lane31 + 32) * 8 + (kgl ^ sw)];
      acc[0][0] = MFMA16(a0, wb0[ks], acc[0][0]);
      acc[0][1] = MFMA16(a0, wb1[ks], acc[0][1]);
      acc[1][0] = MFMA16(a1, wb0[ks], acc[1][0]);
      acc[1][1] = MFMA16(a1, wb1[ks], acc[1][1]);
    }
    __syncthreads();
  }
  // dump acc + qW into ELDS
  {
    float q0 = qW[col0], q1 = qW[col1];
#pragma unroll
    for (int rf = 0; rf < 2; rf++)
#pragma unroll
      for (int g = 0; g < 4; g++)
#pragma unroll
        for (int qq = 0; qq < 4; qq++) {
          int rowloc = 32 * rf + qq + 8 * g + 4 * hw;
          ELDS[rowloc * 256 + col0] = (_Float16)(acc[rf][0][4 * g + qq] + q0);
          ELDS[rowloc * 256 + col1] = (_Float16)(acc[rf][1][4 * g + qq] + q1);
        }
  }
  __syncthreads();
  // edge combine: half-wave per edge, 8 edges per half-wave
  const int hwv = tid >> 5;              // 0..7
  const int l = tid & 31;
  const float4* wp = (const float4*)(pW2 + l * 8);
  float4 w0 = wp[0], w1 = wp[1];
  float wv[8] = {w0.x, w0.y, w0.z, w0.w, w1.x, w1.y, w1.z, w1.w};
  float b2v = pb2[0];
#pragma unroll 2
  for (int i = 0; i < 8; i++) {
    int el = hwv * 8 + i;
    int h = ehS[el], t = etS[el];
    f16x8 a  = ((const f16x8*)(ELDS + el * 256))[l];
    f16x8 hv = ((const f16x8*)(HEh + (size_t)h * 256))[l];
    f16x8 tv = ((const f16x8*)(HEt + (size_t)t * 256))[l];
    float s = 0.f;
#pragma unroll
    for (int j = 0; j < 8; j++)
      s += fmaxf((float)a[j] + (float)hv[j] + (float)tv[j], 0.f) * wv[j];
#pragma unroll
    for (int m = 1; m <= 16; m <<= 1) s += __shfl_xor(s, m);
    if (l == 0) {
      int e = m0 + el;
      float lg = s + b2v;
      float nz = noise[e];
      float rn = logf(nz) - logf(1.f - nz);
      dout[e] = lg;
      dout[E + e] = 1.f / (1.f + expf(-(lg + rn)));
    }
  }
}

// ---- fused ADDC + sage0 (single-weight phases -> 3 waves/SIMD) -------------
__global__ __launch_bounds__(256, 3) void k_fuse0(
    const _Float16* __restrict__ hid16, const _Float16* __restrict__ ent16,
    _Float16* __restrict__ hsum16, const _Float16* __restrict__ xsum16,
    const float* __restrict__ degrev, const float* __restrict__ rinv,
    const _Float16* __restrict__ Wpr2f, const float* __restrict__ bpr2,
    const _Float16* __restrict__ sW0f, const float* __restrict__ sb0,
    _Float16* __restrict__ out016, int M) {
  __shared__ _Float16 AS[2 * 4096];      // 16 KB staging dbuf
  __shared__ _Float16 AGG[4 * 4096];     // 32 KB: 4 K-tiles of agg0
  const int tid = threadIdx.x;
  const int w = tid >> 6;
  const int lane31 = tid & 31;
  const int hw = (tid >> 5) & 1;
  const int m0 = blockIdx.x * 64;
  const int col0 = (w << 6) + lane31;
  const int col1 = col0 + 32;
  const int sw = lane31 & 7;
  const int kgA = lane31 >> 3, kjA = lane31 & 7;

  f32x16 acc[2][2];
#pragma unroll
  for (int a = 0; a < 2; a++)
#pragma unroll
    for (int b = 0; b < 2; b++)
#pragma unroll
      for (int i = 0; i < 16; i++) acc[a][b][i] = 0.f;

  // ---- P1: hid16 @ Wpr2 ----
  {
    const f16x8* WV = (const f16x8*)Wpr2f;
    stageA<AF16>(hid16, nullptr, m0, 0, tid, AS);
    __syncthreads();
    for (int t = 0; t < 4; ++t) {
      const int k0 = t * 64;
      f16x8 wb0[4], wb1[4];
#pragma unroll
      for (int ks = 0; ks < 4; ks++) {
        const int kgl = 2 * ks + hw;
        size_t wi = (size_t)((k0 >> 3) + kgl) * 256;
        wb0[ks] = WV[wi + col0]; wb1[ks] = WV[wi + col1];
      }
      __builtin_amdgcn_sched_barrier(0);
      if (t + 1 < 4) stageA<AF16>(hid16, nullptr, m0, t + 1, tid, AS + ((t + 1) & 1) * 4096);
      __builtin_amdgcn_sched_barrier(0);
      const f16x8* cb = (const f16x8*)(AS + (t & 1) * 4096);
#pragma unroll
      for (int ks = 0; ks < 4; ks++) {
        const int kgl = 2 * ks + hw;
        f16x8 a0 = cb[lane31 * 8 + (kgl ^ sw)];
        f16x8 a1 = cb[(lane31 + 32) * 8 + (kgl ^ sw)];
        acc[0][0] = MFMA16(a0, wb0[ks], acc[0][0]);
        acc[0][1] = MFMA16(a0, wb1[ks], acc[0][1]);
        acc[1][0] = MFMA16(a1, wb0[ks], acc[1][0]);
        acc[1][1] = MFMA16(a1, wb1[ks], acc[1][1]);
      }
      __syncthreads();
    }
  }
  // prologue-stage P2 tile0 early (overlaps with epilogue below)
  stageA<AF16>(ent16, nullptr, m0, 0, tid, AS);
  // ---- P1 epilogue: hsum16 (global) + agg0 (LDS, staged layout) ----
  {
    float b0v = bpr2[col0], b1v = bpr2[col1];
    _Float16* AGGw = AGG + (w << 12);    // tile w (4096 f16)
#pragma unroll
    for (int rf = 0; rf < 2; rf++)
#pragma unroll
      for (int g = 0; g < 4; g++)
#pragma unroll
        for (int qq = 0; qq < 4; qq++) {
          int rowloc = 32 * rf + qq + 8 * g + 4 * hw;
          int row = m0 + rowloc;
          float a0 = 0.f, a1 = 0.f;
          if (row < M) {
            float dr = degrev[row], rv = rinv[row];
            size_t i0 = (size_t)row * 256 + col0;
            size_t i1 = (size_t)row * 256 + col1;
            float h0 = acc[rf][0][4 * g + qq] + (float)hsum16[i0] + dr * b0v;
            float h1 = acc[rf][1][4 * g + qq] + (float)hsum16[i1] + dr * b1v;
            hsum16[i0] = (_Float16)h0;
            hsum16[i1] = (_Float16)h1;
            a0 = (h0 + (float)xsum16[i0]) * rv;
            a1 = (h1 + (float)xsum16[i1]) * rv;
          }
          int rsw = rowloc & 7;
          AGGw[rowloc * 64 + ((kgA ^ rsw) << 3) + kjA] = (_Float16)a0;
          AGGw[rowloc * 64 + (((kgA + 4) ^ rsw) << 3) + kjA] = (_Float16)a1;
          acc[rf][0][4 * g + qq] = 0.f;
          acc[rf][1][4 * g + qq] = 0.f;
        }
  }
  __syncthreads();
  // ---- P2: [ent16 | agg0] @ sW0, K=512 ----
  {
    const f16x8* WV = (const f16x8*)sW0f;
    for (int tt = 0; tt < 8; ++tt) {
      f16x8 wb0[4], wb1[4];
#pragma unroll
      for (int ks = 0; ks < 4; ks++) {
        const int kgl = 2 * ks + hw;
        size_t wi = (size_t)(tt * 8 + kgl) * 256;
        wb0[ks] = WV[wi + col0]; wb1[ks] = WV[wi + col1];
      }
      __builtin_amdgcn_sched_barrier(0);
      if (tt + 1 < 4) stageA<AF16>(ent16, nullptr, m0, tt + 1, tid, AS + ((tt + 1) & 1) * 4096);
      __builtin_amdgcn_sched_barrier(0);
      const f16x8* cb = (tt < 4) ? (const f16x8*)(AS + (tt & 1) * 4096)
                                 : (const f16x8*)(AGG + ((tt - 4) << 12));
#pragma unroll
      for (int ks = 0; ks < 4; ks++) {
        const int kgl = 2 * ks + hw;
        f16x8 a0 = cb[lane31 * 8 + (kgl ^ sw)];
        f16x8 a1 = cb[(lane31 + 32) * 8 + (kgl ^ sw)];
        acc[0][0] = MFMA16(a0, wb0[ks], acc[0][0]);
        acc[0][1] = MFMA16(a0, wb1[ks], acc[0][1]);
        acc[1][0] = MFMA16(a1, wb0[ks], acc[1][0]);
        acc[1][1] = MFMA16(a1, wb1[ks], acc[1][1]);
      }
      __syncthreads();
    }
    float b0v = sb0[col0], b1v = sb0[col1];
#pragma unroll
    for (int rf = 0; rf < 2; rf++)
#pragma unroll
      for (int g = 0; g < 4; g++)
#pragma unroll
        for (int qq = 0; qq < 4; qq++) {
          int row = m0 + 32 * rf + qq + 8 * g + 4 * hw;
          if (row < M) {
            out016[(size_t)row * 256 + col0] =
                (_Float16)fmaxf(acc[rf][0][4 * g + qq] + b0v, 0.f);
            out016[(size_t)row * 256 + col1] =
                (_Float16)fmaxf(acc[rf][1][4 * g + qq] + b1v, 0.f);
          }
        }
  }
}

// ---- fused sage1 + HE2 (dual P2 -> stays 2 waves/SIMD) ---------------------
__global__ __launch_bounds__(256, 2) void k_fuse1(
    const _Float16* __restrict__ out016, const _Float16* __restrict__ agg16,
    const _Float16* __restrict__ sW1f, const float* __restrict__ sb1,
    const _Float16* __restrict__ Whehf, const _Float16* __restrict__ Whetf,
    _Float16* __restrict__ HEh16, _Float16* __restrict__ HEt16, int M) {
  __shared__ _Float16 AS[2 * 4096];      // 16 KB staging dbuf
  __shared__ _Float16 OUT[4 * 4096];     // 32 KB: 4 K-tiles of out116
  const int tid = threadIdx.x;
  const int w = tid >> 6;
  const int lane31 = tid & 31;
  const int hw = (tid >> 5) & 1;
  const int m0 = blockIdx.x * 64;
  const int col0 = (w << 6) + lane31;
  const int col1 = col0 + 32;
  const int sw = lane31 & 7;
  const int kgA = lane31 >> 3, kjA = lane31 & 7;

  f32x16 acc[2][2], acc2[2][2];
#pragma unroll
  for (int a = 0; a < 2; a++)
#pragma unroll
    for (int b = 0; b < 2; b++)
#pragma unroll
      for (int i = 0; i < 16; i++) { acc[a][b][i] = 0.f; acc2[a][b][i] = 0.f; }

  // ---- P1: [out016|agg16] @ sW1, K=512 ----
  {
    const f16x8* WV = (const f16x8*)sW1f;
    stageA<AF16D>(out016, agg16, m0, 0, tid, AS);
    __syncthreads();
    for (int t = 0; t < 8; ++t) {
      f16x8 wb0[4], wb1[4];
#pragma unroll
      for (int ks = 0; ks < 4; ks++) {
        const int kgl = 2 * ks + hw;
        size_t wi = (size_t)(t * 8 + kgl) * 256;
        wb0[ks] = WV[wi + col0]; wb1[ks] = WV[wi + col1];
      }
      __builtin_amdgcn_sched_barrier(0);
      if (t + 1 < 8) stageA<AF16D>(out016, agg16, m0, t + 1, tid, AS + ((t + 1) & 1) * 4096);
      __builtin_amdgcn_sched_barrier(0);
      const f16x8* cb = (const f16x8*)(AS + (t & 1) * 4096);
#pragma unroll
      for (int ks = 0; ks < 4; ks++) {
        const int kgl = 2 * ks + hw;
        f16x8 a0 = cb[lane31 * 8 + (kgl ^ sw)];
        f16x8 a1 = cb[(lane31 + 32) * 8 + (kgl ^ sw)];
        acc[0][0] = MFMA16(a0, wb0[ks], acc[0][0]);
        acc[0][1] = MFMA16(a0, wb1[ks], acc[0][1]);
        acc[1][0] = MFMA16(a1, wb0[ks], acc[1][0]);
        acc[1][1] = MFMA16(a1, wb1[ks], acc[1][1]);
      }
      __syncthreads();
    }
  }
  // prologue-stage P2 tile0 early
  stageA<AF16>(out016, nullptr, m0, 0, tid, AS);
  // ---- P1 epilogue: out116 -> LDS tiles only ----
  {
    float b0v = sb1[col0], b1v = sb1[col1];
    _Float16* OUTw = OUT + (w << 12);
#pragma unroll
    for (int rf = 0; rf < 2; rf++)
#pragma unroll
      for (int g = 0; g < 4; g++)
#pragma unroll
        for (int qq = 0; qq < 4; qq++) {
          int rowloc = 32 * rf + qq + 8 * g + 4 * hw;
          float v0 = fmaxf(acc[rf][0][4 * g + qq] + b0v, 0.f);
          float v1 = fmaxf(acc[rf][1][4 * g + qq] + b1v, 0.f);
          int rsw = rowloc & 7;
          OUTw[rowloc * 64 + ((kgA ^ rsw) << 3) + kjA] = (_Float16)v0;
          OUTw[rowloc * 64 + (((kgA + 4) ^ rsw) << 3) + kjA] = (_Float16)v1;
          acc[rf][0][4 * g + qq] = 0.f;
          acc[rf][1][4 * g + qq] = 0.f;
        }
  }
  __syncthreads();
  // ---- P2: [out016 | out116] @ {Wheh, Whet}, K=512, dual ----
  {
    const f16x8* WV  = (const f16x8*)Whehf;
    const f16x8* WV2 = (const f16x8*)Whetf;
    for (int tt = 0; tt < 8; ++tt) {
      f16x8 wb0[4], wb1[4], wc0[4], wc1[4];
#pragma unroll
      for (int ks = 0; ks < 4; ks++) {
        const int kgl = 2 * ks + hw;
        size_t wi = (size_t)(tt * 8 + kgl) * 256;
        wb0[ks] = WV[wi + col0];  wb1[ks] = WV[wi + col1];
        wc0[ks] = WV2[wi + col0]; wc1[ks] = WV2[wi + col1];
      }
      __builtin_amdgcn_sched_barrier(0);
      if (tt + 1 < 4) stageA<AF16>(out016, nullptr, m0, tt + 1, tid, AS + ((tt + 1) & 1) * 4096);
      __builtin_amdgcn_sched_barrier(0);
      const f16x8* cb = (tt < 4) ? (const f16x8*)(AS + (tt & 1) * 4096)
                                 : (const f16x8*)(OUT + ((tt - 4) << 12));
#pragma unroll
      for (int ks = 0; ks < 4; ks++) {
        const int kgl = 2 * ks + hw;
        f16x8 a0 = cb[lane31 * 8 + (kgl ^ sw)];
        f16x8 a1 = cb[(lane31 + 32) * 8 + (kgl ^ sw)];
        acc[0][0] = MFMA16(a0, wb0[ks], acc[0][0]);
        acc[0][1] = MFMA16(a0, wb1[ks], acc[0][1]);
        acc[1][0] = MFMA16(a1, wb0[ks], acc[1][0]);
        acc[1][1] = MFMA16(a1, wb1[ks], acc[1][1]);
        acc2[0][0] = MFMA16(a0, wc0[ks], acc2[0][0]);
        acc2[0][1] = MFMA16(a0, wc1[ks], acc2[0][1]);
        acc2[1][0] = MFMA16(a1, wc0[ks], acc2[1][0]);
        acc2[1][1] = MFMA16(a1, wc1[ks], acc2[1][1]);
      }
      __syncthreads();
    }
#pragma unroll
    for (int rf = 0; rf < 2; rf++)
#pragma unroll
      for (int g = 0; g < 4; g++)
#pragma unroll
        for (int qq = 0; qq < 4; qq++) {
          int row = m0 + 32 * rf + qq + 8 * g + 4 * hw;
          if (row < M) {
            HEh16[(size_t)row * 256 + col0] = (_Float16)acc[rf][0][4 * g + qq];
            HEh16[(size_t)row * 256 + col1] = (_Float16)acc[rf][1][4 * g + qq];
            HEt16[(size_t)row * 256 + col0] = (_Float16)acc2[rf][0][4 * g + qq];
            HEt16[(size_t)row * 256 + col1] = (_Float16)acc2[rf][1][4 * g + qq];
          }
        }
  }
}

extern "C" void kernel_launch(void* const* d_in, const int* in_sizes, int n_in,
                              void* d_out, int out_size, void* d_ws, size_t ws_size,
                              hipStream_t stream) {
  const float* entity = (const float*)d_in[0];
  const float* ea     = (const float*)d_in[1];
  const float* q      = (const float*)d_in[2];
  const float* noise  = (const float*)d_in[3];
  const float* W_pr1  = (const float*)d_in[4];
  const float* b_pr1  = (const float*)d_in[5];
  const float* W_pr2  = (const float*)d_in[6];
  const float* b_pr2  = (const float*)d_in[7];
  const float* sW0    = (const float*)d_in[8];
  const float* sb0    = (const float*)d_in[9];
  const float* sW1    = (const float*)d_in[10];
  const float* sb1    = (const float*)d_in[11];
  const float* pW1    = (const float*)d_in[12];
  const float* pb1    = (const float*)d_in[13];
  const float* pW2    = (const float*)d_in[14];
  const float* pb2    = (const float*)d_in[15];
  const void*  ei_raw = d_in[16];

  char* ws = (char*)d_ws;
  const size_t EDH = (size_t)E * D * 2;    // 102.4 MB f16 edge matrix
  const size_t NDH = (size_t)NV * D * 2;   // 25.6 MB f16 node matrix
  const size_t PAD = 64 * 256 * 2;         // OOB tile-read slack (32 KB)
  size_t off_b = 0;
  char* r0  = ws + off_b; off_b += EDH + PAD;        // ea16
  char* r1a = ws + off_b; off_b += EDH + PAD;        // tmp16
  char* r2  = ws + off_b; off_b += 2 * NDH + PAD;    // hsum16 -> HEh16|HEt16
  char* r3  = ws + off_b; off_b += NDH + PAD;        // hid16 -> agg16
  char* r4  = ws + off_b; off_b += NDH + PAD;        // ent16
  char* r5  = ws + off_b; off_b += NDH + PAD;        // out016
  char* r6  = ws + off_b; off_b += NDH + PAD;        // xsum16
  auto alloc_w = [&](int K) { _Float16* p = (_Float16*)(ws + off_b);
                              off_b += (size_t)K * 256 * 2; return p; };
  _Float16* Wpr1f = alloc_w(256);
  _Float16* Wpr2f = alloc_w(256);
  _Float16* sW0f  = alloc_w(512);
  _Float16* sW1f  = alloc_w(512);
  _Float16* Whehf = alloc_w(512);
  _Float16* Whetf = alloc_w(512);
  _Float16* Weaf  = alloc_w(256);
  float* rinv   = (float*)(ws + off_b); off_b += (size_t)NV * 4;
  float* degrev = (float*)(ws + off_b); off_b += (size_t)NV * 4;
  float* qW     = (float*)(ws + off_b); off_b += 1024;
  int*   ei32   = (int*)(ws + off_b);   off_b += (size_t)TWOE * 4;
  int*   eidA   = (int*)(ws + off_b);   off_b += (size_t)TWOE * 4;
  int*   srcA   = (int*)(ws + off_b);   off_b += (size_t)TWOE * 4;
  int*   offA   = (int*)(ws + off_b);   off_b += (size_t)(NV + 1) * 4;
  int*   deg    = (int*)(ws + off_b);   off_b += (size_t)NV * 4;
  int*   cursor = (int*)(ws + off_b);   off_b += (size_t)NV * 4;
  int*   flag   = (int*)(ws + off_b);   off_b += 64;

  // lifetime aliases
  _Float16* ea16   = (_Float16*)r0;          // projea byproduct -> gath/projedge
  _Float16* tmp16  = (_Float16*)r1a;         // projea -> gath_h
  _Float16* hsum16 = (_Float16*)r2;          // gath -> fuse0(in-place) -> agg1
  _Float16* HEh16  = (_Float16*)r2;          // fuse1 -> projedge (hsum dead)
  _Float16* HEt16  = (_Float16*)(r2 + NDH);
  _Float16* hid16  = (_Float16*)r3;          // gath -> fuse0 P1
  _Float16* agg16  = (_Float16*)r3;          // k_agg -> fuse1 P1 (hid dead)
  _Float16* ent16  = (_Float16*)r4;          // conv -> gath/fuse0 P2
  _Float16* out016 = (_Float16*)r5;          // fuse0 -> agg1/fuse1
  _Float16* xsum16 = (_Float16*)r6;          // gath -> fuse0 epi

  // ---- indices & CSR ----
  k_detect<<<1, 256, 0, stream>>>(ei_raw, flag);
  k_convert<<<(TWOE + 255) / 256, 256, 0, stream>>>(ei_raw, flag, ei32);
  hipMemsetAsync(deg, 0, (size_t)NV * 4, stream);
  hipMemsetAsync(cursor, 0, (size_t)NV * 4, stream);
  k_deg<<<(TWOE + 255) / 256, 256, 0, stream>>>(ei32, deg);
  k_scan<<<1, 1024, 0, stream>>>(deg, offA);
  k_fill<<<(TWOE + 255) / 256, 256, 0, stream>>>(ei32, offA, cursor, eidA, srcA);
  k_rinv<<<(NV + 255) / 256, 256, 0, stream>>>(offA, rinv);

  // ---- weight prep + f16 shadows ----
  k_wprep<<<256 / 32, 256, 0, stream>>>(W_pr1, Wpr1f);
  k_wprep<<<256 / 32, 256, 0, stream>>>(W_pr2, Wpr2f);
  k_wprep<<<512 / 32, 256, 0, stream>>>(sW0, sW0f);
  k_wprep<<<512 / 32, 256, 0, stream>>>(sW1, sW1f);
  k_wprep<<<512 / 32, 256, 0, stream>>>(pW1 + 256 * 256, Whehf);
  k_wprep<<<512 / 32, 256, 0, stream>>>(pW1 + 1024 * 256, Whetf);
  k_wprep<<<256 / 32, 256, 0, stream>>>(pW1 + 768 * 256, Weaf);
  k_conv16<<<(NV * D / 8 + 255) / 256, 256, 0, stream>>>(entity, ent16, NV * D / 8);
  k_qw<<<1, 256, 0, stream>>>(q, pW1, pb1, qW);

  // ---- fused proj + ea16 conversion: tmp16, ea16 ----
  k_projea<<<E / 64, 256, 0, stream>>>(ea, Wpr1f, b_pr1, tmp16, ea16, E);

  // ---- merged gather: hsum16, hid16, xsum16, degrev ----
  k_gath_h<<<(NV + 7) / 8, 256, 0, stream>>>(
      ea16, tmp16, ent16, eidA, srcA, offA, hsum16, hid16, xsum16, degrev);

  // ---- fused ADDC + sage0 ----
  k_fuse0<<<(NV + 63) / 64, 256, 0, stream>>>(
      hid16, ent16, hsum16, xsum16, degrev, rinv, Wpr2f, b_pr2,
      sW0f, sb0, out016, NV);

  // ---- layer-1 aggregate ----
  k_agg<<<(NV + 7) / 8, 256, 0, stream>>>(out016, srcA, offA, hsum16, rinv, agg16);

  // ---- fused sage1 + HE2 ----
  k_fuse1<<<(NV + 63) / 64, 256, 0, stream>>>(
      out016, agg16, sW1f, sb1, Whehf, Whetf, HEh16, HEt16, NV);

  // ---- proj pass 2 fused with edge combine + sampling ----
  k_projedge<<<E / 64, 256, 0, stream>>>(
      ea16, Weaf, qW, HEh16, HEt16, ei32, pW2, pb2, noise, (float*)d_out);
}

// Round 16
// 569.811 us; speedup vs baseline: 1.3076x; 1.0375x over previous
//
#include <hip/hip_runtime.h>
#include <math.h>

// FineGrainedRetriever round 16: launch-count reduction. All 7 weight-prep
// passes + qW fused into one k_wprep_all (blockIdx.y selects); deg/cursor
// zeroing folded into k_convert (deletes 2 memsets); k_rinv folded into
// k_scan tail. 21 dispatches -> 11. Compute kernels identical to round 15.

namespace {
constexpr int E    = 200000;
constexpr int NV   = 50000;
constexpr int D    = 256;
constexpr int TWOE = 2 * E;
}

typedef __attribute__((ext_vector_type(8))) _Float16 f16x8;
typedef __attribute__((ext_vector_type(4))) _Float16 f16x4;
typedef __attribute__((ext_vector_type(16))) float f32x16;

#define MFMA16(a, b, c) __builtin_amdgcn_mfma_f32_32x32x16_f16((a), (b), (c), 0, 0, 0)

typedef const __attribute__((address_space(1))) void* gas_t;
typedef __attribute__((address_space(3))) void* las_t;

__device__ inline void gload16(const void* g, void* l) {
  __builtin_amdgcn_global_load_lds((gas_t)g, (las_t)l, 16, 0, 0);
}

// ---- edge_index dtype probe (int64 vs int32) -------------------------------
__global__ void k_detect(const void* ei_raw, int* flag) {
  __shared__ int bad;
  if (threadIdx.x == 0) bad = 0;
  __syncthreads();
  const long long* p = (const long long*)ei_raw;
  long long v = p[threadIdx.x];
  if (v < 0 || v >= (long long)NV) atomicOr(&bad, 1);
  __syncthreads();
  if (threadIdx.x == 0) *flag = bad ? 0 : 1;  // 1 => int64
}

// ---- convert + zero deg/cursor ----------------------------------------------
__global__ void k_convert(const void* ei_raw, const int* __restrict__ flag,
                          int* __restrict__ ei32, int* __restrict__ deg,
                          int* __restrict__ cursor) {
  int i = blockIdx.x * 256 + threadIdx.x;
  if (i < NV) { deg[i] = 0; cursor[i] = 0; }
  if (i >= TWOE) return;
  if (*flag) ei32[i] = (int)((const long long*)ei_raw)[i];
  else       ei32[i] = ((const int*)ei_raw)[i];
}

// ---- CSR build -------------------------------------------------------------
__global__ void k_deg(const int* __restrict__ ei32, int* __restrict__ deg) {
  int de = blockIdx.x * 256 + threadIdx.x;
  if (de >= TWOE) return;
  int dst = (de < E) ? ei32[E + de] : ei32[de - E];
  atomicAdd(&deg[dst], 1);
}

__global__ __launch_bounds__(1024) void k_scan(const int* __restrict__ deg,
                                               int* __restrict__ off,
                                               float* __restrict__ rinv) {
  __shared__ int wsum[16];
  __shared__ int carryS;
  int tid = threadIdx.x;
  int lane = tid & 63, wv = tid >> 6;
  if (tid == 0) carryS = 0;
  __syncthreads();
  for (int base = 0; base < NV; base += 1024) {
    int i = base + tid;
    int v = (i < NV) ? deg[i] : 0;
    int s = v;
#pragma unroll
    for (int d = 1; d < 64; d <<= 1) {
      int t = __shfl_up(s, d);
      if (lane >= d) s += t;
    }
    if (lane == 63) wsum[wv] = s;
    int carry = carryS;
    __syncthreads();
    if (wv == 0) {
      int ws = (lane < 16) ? wsum[lane] : 0;
#pragma unroll
      for (int d = 1; d < 16; d <<= 1) {
        int t = __shfl_up(ws, d);
        if (lane >= d) ws += t;
      }
      if (lane < 16) wsum[lane] = ws;
    }
    __syncthreads();
    int wexcl = (wv == 0) ? 0 : wsum[wv - 1];
    if (i < NV) off[i] = carry + wexcl + s - v;
    if (tid == 1023) carryS = carry + wsum[15];
    __syncthreads();
  }
  if (tid == 0) off[NV] = carryS;
  __syncthreads();
  // fold k_rinv: same block already owns off
  for (int i = tid; i < NV; i += 1024) {
    int d = off[i + 1] - off[i];
    rinv[i] = 1.f / fmaxf((float)d, 1.f);
  }
}

__global__ void k_fill(const int* __restrict__ ei32, const int* __restrict__ off,
                       int* __restrict__ cursor, int* __restrict__ eidA,
                       int* __restrict__ srcA) {
  int de = blockIdx.x * 256 + threadIdx.x;
  if (de >= TWOE) return;
  int dst = (de < E) ? ei32[E + de] : ei32[de - E];
  int p = atomicAdd(&cursor[dst], 1);
  int idx = off[dst] + p;
  eidA[idx] = de;
  srcA[idx] = ei32[de];
}

// ---- f32 -> f16 copy (8 elems/thread) --------------------------------------
__global__ void k_conv16(const float* __restrict__ x, _Float16* __restrict__ y,
                         int n8) {
  int i = blockIdx.x * 256 + threadIdx.x;
  if (i >= n8) return;
  const float4* p = (const float4*)x;
  float4 a = p[2 * i], b = p[2 * i + 1];
  f16x8 o;
  o[0] = (_Float16)a.x; o[1] = (_Float16)a.y; o[2] = (_Float16)a.z; o[3] = (_Float16)a.w;
  o[4] = (_Float16)b.x; o[5] = (_Float16)b.y; o[6] = (_Float16)b.z; o[7] = (_Float16)b.w;
  ((f16x8*)y)[i] = o;
}

// ---- merged gather: per node n (half-wave): hsum (fwd ea), hid (rev tmp),
// ---- xsum0 (ent16[src] over ALL list entries), degrev -----------------------
__global__ __launch_bounds__(256) void k_gath_h(
    const _Float16* __restrict__ ea16, const _Float16* __restrict__ tmp16,
    const _Float16* __restrict__ ent16,
    const int* __restrict__ eidA, const int* __restrict__ srcA,
    const int* __restrict__ off,
    _Float16* __restrict__ hsum16, _Float16* __restrict__ hid16,
    _Float16* __restrict__ xsum16, float* __restrict__ degrev) {
  int n = blockIdx.x * 8 + (threadIdx.x >> 5);
  if (n >= NV) return;
  int l = threadIdx.x & 31;
  float fs[8], hv[8], xs[8];
#pragma unroll
  for (int k2 = 0; k2 < 8; k2++) { fs[k2] = 0.f; hv[k2] = 0.f; xs[k2] = 0.f; }
  int o0 = off[n], o1 = off[n + 1];
  int dr = 0;
#pragma unroll 2
  for (int j = o0; j < o1; j++) {
    int de = eidA[j];
    int src = srcA[j];
    f16x8 xv = ((const f16x8*)(ent16 + (size_t)src * D))[l];
#pragma unroll
    for (int k2 = 0; k2 < 8; k2++) xs[k2] += (float)xv[k2];
    if (de < E) {
      f16x8 v = ((const f16x8*)(ea16 + (size_t)de * D))[l];
#pragma unroll
      for (int k2 = 0; k2 < 8; k2++) fs[k2] += (float)v[k2];
    } else {
      f16x8 v = ((const f16x8*)(tmp16 + (size_t)(de - E) * D))[l];
#pragma unroll
      for (int k2 = 0; k2 < 8; k2++) hv[k2] += (float)v[k2];
      dr++;
    }
  }
  f16x8 of, oh, ox;
#pragma unroll
  for (int k2 = 0; k2 < 8; k2++) {
    of[k2] = (_Float16)fs[k2]; oh[k2] = (_Float16)hv[k2]; ox[k2] = (_Float16)xs[k2];
  }
  ((f16x8*)(hsum16 + (size_t)n * D))[l] = of;
  ((f16x8*)(hid16 + (size_t)n * D))[l] = oh;
  ((f16x8*)(xsum16 + (size_t)n * D))[l] = ox;
  if (l == 0) degrev[n] = (float)dr;
}

// ---- layer-1 aggregate: agg16[n] = (sum_j x16[src_j] + hsum16[n])*rinv[n] --
__global__ __launch_bounds__(256) void k_agg(
    const _Float16* __restrict__ x16, const int* __restrict__ srcA,
    const int* __restrict__ off, const _Float16* __restrict__ hsum16,
    const float* __restrict__ rinv, _Float16* __restrict__ agg16) {
  int n = blockIdx.x * 8 + (threadIdx.x >> 5);
  if (n >= NV) return;
  int l = threadIdx.x & 31;
  f16x8 h = ((const f16x8*)(hsum16 + (size_t)n * D))[l];
  float s[8];
#pragma unroll
  for (int k2 = 0; k2 < 8; k2++) s[k2] = (float)h[k2];
  int o0 = off[n], o1 = off[n + 1];
#pragma unroll 4
  for (int j = o0; j < o1; j++) {
    int src = srcA[j];
    f16x8 v = ((const f16x8*)(x16 + (size_t)src * D))[l];
#pragma unroll
    for (int k2 = 0; k2 < 8; k2++) s[k2] += (float)v[k2];
  }
  float r = rinv[n];
  f16x8 o;
#pragma unroll
  for (int k2 = 0; k2 < 8; k2++) o[k2] = (_Float16)(s[k2] * r);
  ((f16x8*)(agg16 + (size_t)n * D))[l] = o;
}

// ---- fused weight prep (y=0..6) + qW (y=7) ---------------------------------
__global__ __launch_bounds__(256) void k_wprep_all(
    const float* __restrict__ W_pr1, const float* __restrict__ W_pr2,
    const float* __restrict__ sW0, const float* __restrict__ sW1,
    const float* __restrict__ pW1, const float* __restrict__ q,
    const float* __restrict__ pb1,
    _Float16* __restrict__ Wpr1f, _Float16* __restrict__ Wpr2f,
    _Float16* __restrict__ sW0f, _Float16* __restrict__ sW1f,
    _Float16* __restrict__ Whehf, _Float16* __restrict__ Whetf,
    _Float16* __restrict__ Weaf, float* __restrict__ qW) {
  __shared__ float tl[32][260];
  const int y = blockIdx.y;
  const int tid = threadIdx.x;
  if (y == 7) {               // qW[n] = q @ pW1[:256,n] + pb1[n]
    if (blockIdx.x != 0) return;
    __shared__ float ql[D];
    ql[tid] = q[tid];
    __syncthreads();
    float s = pb1[tid];
    for (int k = 0; k < D; k++) s += ql[k] * pW1[(size_t)k * D + tid];
    qW[tid] = s;
    return;
  }
  const float* W; _Float16* Wf; int K;
  switch (y) {
    case 0:  W = W_pr1;            Wf = Wpr1f; K = 256; break;
    case 1:  W = W_pr2;            Wf = Wpr2f; K = 256; break;
    case 2:  W = sW0;              Wf = sW0f;  K = 512; break;
    case 3:  W = sW1;              Wf = sW1f;  K = 512; break;
    case 4:  W = pW1 + 256 * 256;  Wf = Whehf; K = 512; break;
    case 5:  W = pW1 + 1024 * 256; Wf = Whetf; K = 512; break;
    default: W = pW1 + 768 * 256;  Wf = Weaf;  K = 256; break;
  }
  const int k0 = blockIdx.x * 32;
  if (k0 >= K) return;
#pragma unroll
  for (int i = 0; i < 32; i++) tl[i][tid] = W[(size_t)(k0 + i) * 256 + tid];
  __syncthreads();
  f16x8* WfV = (f16x8*)Wf;
#pragma unroll
  for (int kg = 0; kg < 4; kg++) {
    f16x8 p;
#pragma unroll
    for (int j = 0; j < 8; j++) p[j] = (_Float16)tl[kg * 8 + j][tid];
    WfV[(size_t)((k0 >> 3) + kg) * 256 + tid] = p;
  }
}

// ---- staging: one 64x64 f16 K-step tile into ldsbuf (8KB), src-XOR-swizzled
enum AM { AF16, AF16D };

template<int AMODE>
__device__ inline void stageA(const _Float16* __restrict__ A0,
                              const _Float16* __restrict__ A1,
                              int m0, int t, int tid, _Float16* ldsbuf) {
  const _Float16* src;
  int kbase;
  if (AMODE == AF16D && t >= 4) { src = A1; kbase = (t - 4) * 64; }
  else                          { src = A0; kbase = t * 64; }
  const int l  = tid & 63;
  const int w  = tid >> 6;
  const int r8 = l >> 3;                 // row within 8-row chunk
  const int kg = (l & 7) ^ r8;           // swizzled source k-group (0..7)
#pragma unroll
  for (int j = 0; j < 2; j++) {
    const int c = w * 2 + j;             // chunk 0..7 (8 rows, 1KB each)
    const int row = c * 8 + r8;
    gload16(src + (size_t)(m0 + row) * 256 + kbase + kg * 8,
            ldsbuf + c * 512);           // wave-uniform LDS base, lane*16B
  }
}

// ---- fused proj + ea16 conversion: reg-stage from f32 ea -------------------
__global__ __launch_bounds__(256, 3) void k_projea(
    const float* __restrict__ ea, const _Float16* __restrict__ Wf,
    const float* __restrict__ bias, _Float16* __restrict__ tmp16,
    _Float16* __restrict__ ea16, int M) {
  __shared__ _Float16 AS[2 * 4096];
  const int tid = threadIdx.x;
  const int w = tid >> 6;
  const int lane31 = tid & 31;
  const int hw = (tid >> 5) & 1;
  const int m0 = blockIdx.x * 64;
  const int col0 = (w << 6) + lane31;
  const int col1 = col0 + 32;
  const int sw = lane31 & 7;
  const int l63 = tid & 63;
  const int r8 = l63 >> 3;
  const int kg = (l63 & 7) ^ r8;

  f32x16 acc[2][2];
#pragma unroll
  for (int a = 0; a < 2; a++)
#pragma unroll
    for (int b = 0; b < 2; b++)
#pragma unroll
      for (int i = 0; i < 16; i++) acc[a][b][i] = 0.f;

  const f16x8* WV = (const f16x8*)Wf;

  float4 ra[4];
  auto loadRaw = [&](int t) {
#pragma unroll
    for (int j = 0; j < 2; j++) {
      const int c = w * 2 + j;
      const int row = c * 8 + r8;
      const float4* src = (const float4*)(ea + (size_t)(m0 + row) * 256 + t * 64 + kg * 8);
      ra[2 * j]     = src[0];
      ra[2 * j + 1] = src[1];
    }
  };
  auto convStore = [&](int t, _Float16* buf) {
#pragma unroll
    for (int j = 0; j < 2; j++) {
      const int c = w * 2 + j;
      const int row = c * 8 + r8;
      f16x8 p;
      p[0] = (_Float16)ra[2 * j].x; p[1] = (_Float16)ra[2 * j].y;
      p[2] = (_Float16)ra[2 * j].z; p[3] = (_Float16)ra[2 * j].w;
      p[4] = (_Float16)ra[2 * j + 1].x; p[5] = (_Float16)ra[2 * j + 1].y;
      p[6] = (_Float16)ra[2 * j + 1].z; p[7] = (_Float16)ra[2 * j + 1].w;
      ((f16x8*)buf)[c * 64 + l63] = p;
      *(f16x8*)(ea16 + (size_t)(m0 + row) * 256 + t * 64 + kg * 8) = p;
    }
  };

  loadRaw(0);
  convStore(0, AS);
  __syncthreads();
  for (int t = 0; t < 4; ++t) {
    f16x8 wb0[4], wb1[4];
#pragma unroll
    for (int ks = 0; ks < 4; ks++) {
      const int kgl = 2 * ks + hw;
      size_t wi = (size_t)(t * 8 + kgl) * 256;
      wb0[ks] = WV[wi + col0]; wb1[ks] = WV[wi + col1];
    }
    __builtin_amdgcn_sched_barrier(0);
    if (t + 1 < 4) loadRaw(t + 1);
    __builtin_amdgcn_sched_barrier(0);
    const f16x8* cb = (const f16x8*)(AS + (t & 1) * 4096);
#pragma unroll
    for (int ks = 0; ks < 4; ks++) {
      const int kgl = 2 * ks + hw;
      f16x8 a0 = cb[lane31 * 8 + (kgl ^ sw)];
      f16x8 a1 = cb[(lane31 + 32) * 8 + (kgl ^ sw)];
      acc[0][0] = MFMA16(a0, wb0[ks], acc[0][0]);
      acc[0][1] = MFMA16(a0, wb1[ks], acc[0][1]);
      acc[1][0] = MFMA16(a1, wb0[ks], acc[1][0]);
      acc[1][1] = MFMA16(a1, wb1[ks], acc[1][1]);
    }
    if (t + 1 < 4) convStore(t + 1, AS + ((t + 1) & 1) * 4096);
    __syncthreads();
  }
  float b0v = bias[col0], b1v = bias[col1];
#pragma unroll
  for (int rf = 0; rf < 2; rf++)
#pragma unroll
    for (int g = 0; g < 4; g++)
#pragma unroll
      for (int qq = 0; qq < 4; qq++) {
        int row = m0 + 32 * rf + qq + 8 * g + 4 * hw;
        if (row < M) {
          tmp16[(size_t)row * 256 + col0] =
              (_Float16)fmaxf(acc[rf][0][4 * g + qq] + b0v, 0.f);
          tmp16[(size_t)row * 256 + col1] =
              (_Float16)fmaxf(acc[rf][1][4 * g + qq] + b1v, 0.f);
        }
      }
}

// ---- proj pass 2 + edge combine: EA2 GEMM -> LDS -> gather+dot+sample ------
__global__ __launch_bounds__(256, 3) void k_projedge(
    const _Float16* __restrict__ A0, const _Float16* __restrict__ Wf,
    const float* __restrict__ qW,
    const _Float16* __restrict__ HEh, const _Float16* __restrict__ HEt,
    const int* __restrict__ ei32, const float* __restrict__ pW2,
    const float* __restrict__ pb2, const float* __restrict__ noise,
    float* __restrict__ dout) {
  __shared__ _Float16 AS[2 * 4096];
  __shared__ _Float16 ELDS[64 * 256];
  __shared__ int ehS[64], etS[64];
  const int tid = threadIdx.x;
  const int w = tid >> 6;
  const int lane31 = tid & 31;
  const int hw = (tid >> 5) & 1;
  const int m0 = blockIdx.x * 64;
  const int col0 = (w << 6) + lane31;
  const int col1 = col0 + 32;
  const int sw = lane31 & 7;

  if (tid < 64) { ehS[tid] = ei32[m0 + tid]; etS[tid] = ei32[E + m0 + tid]; }

  f32x16 acc[2][2];
#pragma unroll
  for (int a = 0; a < 2; a++)
#pragma unroll
    for (int b = 0; b < 2; b++)
#pragma unroll
      for (int i = 0; i < 16; i++) acc[a][b][i] = 0.f;

  const f16x8* WV = (const f16x8*)Wf;
  stageA<AF16>(A0, nullptr, m0, 0, tid, AS);
  __syncthreads();
  for (int t = 0; t < 4; ++t) {
    const int k0 = t * 64;
    f16x8 wb0[4], wb1[4];
#pragma unroll
    for (int ks = 0; ks < 4; ks++) {
      const int kgl = 2 * ks + hw;
      size_t wi = (size_t)((k0 >> 3) + kgl) * 256;
      wb0[ks] = WV[wi + col0]; wb1[ks] = WV[wi + col1];
    }
    __builtin_amdgcn_sched_barrier(0);
    if (t + 1 < 4) stageA<AF16>(A0, nullptr, m0, t + 1, tid, AS + ((t + 1) & 1) * 4096);
    __builtin_amdgcn_sched_barrier(0);
    const f16x8* cb = (const f16x8*)(AS + (t & 1) * 4096);
#pragma unroll
    for (int ks = 0; ks < 4; ks++) {
      const int kgl = 2 * ks + hw;
      f16x8 a0 = cb[lane31 * 8 + (kgl ^ sw)];
      f16x8 a1 = cb[(lane31 + 32) * 8 + (kgl ^ sw)];
      acc[0][0] = MFMA16(a0, wb0[ks], acc[0][0]);
      acc[0][1] = MFMA16(a0, wb1[ks], acc[0][1]);
      acc[1][0] = MFMA16(a1, wb0[ks], acc[1][0]);
      acc[1][1] = MFMA16(a1, wb1[ks], acc[1][1]);
    }
    __syncthreads();
  }
  {
    float q0 = qW[col0], q1 = qW[col1];
#pragma unroll
    for (int rf = 0; rf < 2; rf++)
#pragma unroll
      for (int g = 0; g < 4; g++)
#pragma unroll
        for (int qq = 0; qq < 4; qq++) {
          int rowloc = 32 * rf + qq + 8 * g + 4 * hw;
          ELDS[rowloc * 256 + col0] = (_Float16)(acc[rf][0][4 * g + qq] + q0);
          ELDS[rowloc * 256 + col1] = (_Float16)(acc[rf][1][4 * g + qq] + q1);
        }
  }
  __syncthreads();
  const int hwv = tid >> 5;
  const int l = tid & 31;
  const float4* wp = (const float4*)(pW2 + l * 8);
  float4 w0 = wp[0], w1 = wp[1];
  float wv[8] = {w0.x, w0.y, w0.z, w0.w, w1.x, w1.y, w1.z, w1.w};
  float b2v = pb2[0];
#pragma unroll 2
  for (int i = 0; i < 8; i++) {
    int el = hwv * 8 + i;
    int h = ehS[el], t = etS[el];
    f16x8 a  = ((const f16x8*)(ELDS + el * 256))[l];
    f16x8 hv = ((const f16x8*)(HEh + (size_t)h * 256))[l];
    f16x8 tv = ((const f16x8*)(HEt + (size_t)t * 256))[l];
    float s = 0.f;
#pragma unroll
    for (int j = 0; j < 8; j++)
      s += fmaxf((float)a[j] + (float)hv[j] + (float)tv[j], 0.f) * wv[j];
#pragma unroll
    for (int m = 1; m <= 16; m <<= 1) s += __shfl_xor(s, m);
    if (l == 0) {
      int e = m0 + el;
      float lg = s + b2v;
      float nz = noise[e];
      float rn = logf(nz) - logf(1.f - nz);
      dout[e] = lg;
      dout[E + e] = 1.f / (1.f + expf(-(lg + rn)));
    }
  }
}

// ---- fused ADDC + sage0 (single-weight phases -> 3 waves/SIMD) -------------
__global__ __launch_bounds__(256, 3) void k_fuse0(
    const _Float16* __restrict__ hid16, const _Float16* __restrict__ ent16,
    _Float16* __restrict__ hsum16, const _Float16* __restrict__ xsum16,
    const float* __restrict__ degrev, const float* __restrict__ rinv,
    const _Float16* __restrict__ Wpr2f, const float* __restrict__ bpr2,
    const _Float16* __restrict__ sW0f, const float* __restrict__ sb0,
    _Float16* __restrict__ out016, int M) {
  __shared__ _Float16 AS[2 * 4096];
  __shared__ _Float16 AGG[4 * 4096];
  const int tid = threadIdx.x;
  const int w = tid >> 6;
  const int lane31 = tid & 31;
  const int hw = (tid >> 5) & 1;
  const int m0 = blockIdx.x * 64;
  const int col0 = (w << 6) + lane31;
  const int col1 = col0 + 32;
  const int sw = lane31 & 7;
  const int kgA = lane31 >> 3, kjA = lane31 & 7;

  f32x16 acc[2][2];
#pragma unroll
  for (int a = 0; a < 2; a++)
#pragma unroll
    for (int b = 0; b < 2; b++)
#pragma unroll
      for (int i = 0; i < 16; i++) acc[a][b][i] = 0.f;

  {
    const f16x8* WV = (const f16x8*)Wpr2f;
    stageA<AF16>(hid16, nullptr, m0, 0, tid, AS);
    __syncthreads();
    for (int t = 0; t < 4; ++t) {
      const int k0 = t * 64;
      f16x8 wb0[4], wb1[4];
#pragma unroll
      for (int ks = 0; ks < 4; ks++) {
        const int kgl = 2 * ks + hw;
        size_t wi = (size_t)((k0 >> 3) + kgl) * 256;
        wb0[ks] = WV[wi + col0]; wb1[ks] = WV[wi + col1];
      }
      __builtin_amdgcn_sched_barrier(0);
      if (t + 1 < 4) stageA<AF16>(hid16, nullptr, m0, t + 1, tid, AS + ((t + 1) & 1) * 4096);
      __builtin_amdgcn_sched_barrier(0);
      const f16x8* cb = (const f16x8*)(AS + (t & 1) * 4096);
#pragma unroll
      for (int ks = 0; ks < 4; ks++) {
        const int kgl = 2 * ks + hw;
        f16x8 a0 = cb[lane31 * 8 + (kgl ^ sw)];
        f16x8 a1 = cb[(lane31 + 32) * 8 + (kgl ^ sw)];
        acc[0][0] = MFMA16(a0, wb0[ks], acc[0][0]);
        acc[0][1] = MFMA16(a0, wb1[ks], acc[0][1]);
        acc[1][0] = MFMA16(a1, wb0[ks], acc[1][0]);
        acc[1][1] = MFMA16(a1, wb1[ks], acc[1][1]);
      }
      __syncthreads();
    }
  }
  stageA<AF16>(ent16, nullptr, m0, 0, tid, AS);
  {
    float b0v = bpr2[col0], b1v = bpr2[col1];
    _Float16* AGGw = AGG + (w << 12);
#pragma unroll
    for (int rf = 0; rf < 2; rf++)
#pragma unroll
      for (int g = 0; g < 4; g++)
#pragma unroll
        for (int qq = 0; qq < 4; qq++) {
          int rowloc = 32 * rf + qq + 8 * g + 4 * hw;
          int row = m0 + rowloc;
          float a0 = 0.f, a1 = 0.f;
          if (row < M) {
            float dr = degrev[row], rv = rinv[row];
            size_t i0 = (size_t)row * 256 + col0;
            size_t i1 = (size_t)row * 256 + col1;
            float h0 = acc[rf][0][4 * g + qq] + (float)hsum16[i0] + dr * b0v;
            float h1 = acc[rf][1][4 * g + qq] + (float)hsum16[i1] + dr * b1v;
            hsum16[i0] = (_Float16)h0;
            hsum16[i1] = (_Float16)h1;
            a0 = (h0 + (float)xsum16[i0]) * rv;
            a1 = (h1 + (float)xsum16[i1]) * rv;
          }
          int rsw = rowloc & 7;
          AGGw[rowloc * 64 + ((kgA ^ rsw) << 3) + kjA] = (_Float16)a0;
          AGGw[rowloc * 64 + (((kgA + 4) ^ rsw) << 3) + kjA] = (_Float16)a1;
          acc[rf][0][4 * g + qq] = 0.f;
          acc[rf][1][4 * g + qq] = 0.f;
        }
  }
  __syncthreads();
  {
    const f16x8* WV = (const f16x8*)sW0f;
    for (int tt = 0; tt < 8; ++tt) {
      f16x8 wb0[4], wb1[4];
#pragma unroll
      for (int ks = 0; ks < 4; ks++) {
        const int kgl = 2 * ks + hw;
        size_t wi = (size_t)(tt * 8 + kgl) * 256;
        wb0[ks] = WV[wi + col0]; wb1[ks] = WV[wi + col1];
      }
      __builtin_amdgcn_sched_barrier(0);
      if (tt + 1 < 4) stageA<AF16>(ent16, nullptr, m0, tt + 1, tid, AS + ((tt + 1) & 1) * 4096);
      __builtin_amdgcn_sched_barrier(0);
      const f16x8* cb = (tt < 4) ? (const f16x8*)(AS + (tt & 1) * 4096)
                                 : (const f16x8*)(AGG + ((tt - 4) << 12));
#pragma unroll
      for (int ks = 0; ks < 4; ks++) {
        const int kgl = 2 * ks + hw;
        f16x8 a0 = cb[lane31 * 8 + (kgl ^ sw)];
        f16x8 a1 = cb[(lane31 + 32) * 8 + (kgl ^ sw)];
        acc[0][0] = MFMA16(a0, wb0[ks], acc[0][0]);
        acc[0][1] = MFMA16(a0, wb1[ks], acc[0][1]);
        acc[1][0] = MFMA16(a1, wb0[ks], acc[1][0]);
        acc[1][1] = MFMA16(a1, wb1[ks], acc[1][1]);
      }
      __syncthreads();
    }
    float b0v = sb0[col0], b1v = sb0[col1];
#pragma unroll
    for (int rf = 0; rf < 2; rf++)
#pragma unroll
      for (int g = 0; g < 4; g++)
#pragma unroll
        for (int qq = 0; qq < 4; qq++) {
          int row = m0 + 32 * rf + qq + 8 * g + 4 * hw;
          if (row < M) {
            out016[(size_t)row * 256 + col0] =
                (_Float16)fmaxf(acc[rf][0][4 * g + qq] + b0v, 0.f);
            out016[(size_t)row * 256 + col1] =
                (_Float16)fmaxf(acc[rf][1][4 * g + qq] + b1v, 0.f);
          }
        }
  }
}

// ---- fused sage1 + HE2 (dual P2 -> stays 2 waves/SIMD) ---------------------
__global__ __launch_bounds__(256, 2) void k_fuse1(
    const _Float16* __restrict__ out016, const _Float16* __restrict__ agg16,
    const _Float16* __restrict__ sW1f, const float* __restrict__ sb1,
    const _Float16* __restrict__ Whehf, const _Float16* __restrict__ Whetf,
    _Float16* __restrict__ HEh16, _Float16* __restrict__ HEt16, int M) {
  __shared__ _Float16 AS[2 * 4096];
  __shared__ _Float16 OUT[4 * 4096];
  const int tid = threadIdx.x;
  const int w = tid >> 6;
  const int lane31 = tid & 31;
  const int hw = (tid >> 5) & 1;
  const int m0 = blockIdx.x * 64;
  const int col0 = (w << 6) + lane31;
  const int col1 = col0 + 32;
  const int sw = lane31 & 7;
  const int kgA = lane31 >> 3, kjA = lane31 & 7;

  f32x16 acc[2][2], acc2[2][2];
#pragma unroll
  for (int a = 0; a < 2; a++)
#pragma unroll
    for (int b = 0; b < 2; b++)
#pragma unroll
      for (int i = 0; i < 16; i++) { acc[a][b][i] = 0.f; acc2[a][b][i] = 0.f; }

  {
    const f16x8* WV = (const f16x8*)sW1f;
    stageA<AF16D>(out016, agg16, m0, 0, tid, AS);
    __syncthreads();
    for (int t = 0; t < 8; ++t) {
      f16x8 wb0[4], wb1[4];
#pragma unroll
      for (int ks = 0; ks < 4; ks++) {
        const int kgl = 2 * ks + hw;
        size_t wi = (size_t)(t * 8 + kgl) * 256;
        wb0[ks] = WV[wi + col0]; wb1[ks] = WV[wi + col1];
      }
      __builtin_amdgcn_sched_barrier(0);
      if (t + 1 < 8) stageA<AF16D>(out016, agg16, m0, t + 1, tid, AS + ((t + 1) & 1) * 4096);
      __builtin_amdgcn_sched_barrier(0);
      const f16x8* cb = (const f16x8*)(AS + (t & 1) * 4096);
#pragma unroll
      for (int ks = 0; ks < 4; ks++) {
        const int kgl = 2 * ks + hw;
        f16x8 a0 = cb[lane31 * 8 + (kgl ^ sw)];
        f16x8 a1 = cb[(lane31 + 32) * 8 + (kgl ^ sw)];
        acc[0][0] = MFMA16(a0, wb0[ks], acc[0][0]);
        acc[0][1] = MFMA16(a0, wb1[ks], acc[0][1]);
        acc[1][0] = MFMA16(a1, wb0[ks], acc[1][0]);
        acc[1][1] = MFMA16(a1, wb1[ks], acc[1][1]);
      }
      __syncthreads();
    }
  }
  stageA<AF16>(out016, nullptr, m0, 0, tid, AS);
  {
    float b0v = sb1[col0], b1v = sb1[col1];
    _Float16* OUTw = OUT + (w << 12);
#pragma unroll
    for (int rf = 0; rf < 2; rf++)
#pragma unroll
      for (int g = 0; g < 4; g++)
#pragma unroll
        for (int qq = 0; qq < 4; qq++) {
          int rowloc = 32 * rf + qq + 8 * g + 4 * hw;
          float v0 = fmaxf(acc[rf][0][4 * g + qq] + b0v, 0.f);
          float v1 = fmaxf(acc[rf][1][4 * g + qq] + b1v, 0.f);
          int rsw = rowloc & 7;
          OUTw[rowloc * 64 + ((kgA ^ rsw) << 3) + kjA] = (_Float16)v0;
          OUTw[rowloc * 64 + (((kgA + 4) ^ rsw) << 3) + kjA] = (_Float16)v1;
          acc[rf][0][4 * g + qq] = 0.f;
          acc[rf][1][4 * g + qq] = 0.f;
        }
  }
  __syncthreads();
  {
    const f16x8* WV  = (const f16x8*)Whehf;
    const f16x8* WV2 = (const f16x8*)Whetf;
    for (int tt = 0; tt < 8; ++tt) {
      f16x8 wb0[4], wb1[4], wc0[4], wc1[4];
#pragma unroll
      for (int ks = 0; ks < 4; ks++) {
        const int kgl = 2 * ks + hw;
        size_t wi = (size_t)(tt * 8 + kgl) * 256;
        wb0[ks] = WV[wi + col0];  wb1[ks] = WV[wi + col1];
        wc0[ks] = WV2[wi + col0]; wc1[ks] = WV2[wi + col1];
      }
      __builtin_amdgcn_sched_barrier(0);
      if (tt + 1 < 4) stageA<AF16>(out016, nullptr, m0, tt + 1, tid, AS + ((tt + 1) & 1) * 4096);
      __builtin_amdgcn_sched_barrier(0);
      const f16x8* cb = (tt < 4) ? (const f16x8*)(AS + (tt & 1) * 4096)
                                 : (const f16x8*)(OUT + ((tt - 4) << 12));
#pragma unroll
      for (int ks = 0; ks < 4; ks++) {
        const int kgl = 2 * ks + hw;
        f16x8 a0 = cb[lane31 * 8 + (kgl ^ sw)];
        f16x8 a1 = cb[(lane31 + 32) * 8 + (kgl ^ sw)];
        acc[0][0] = MFMA16(a0, wb0[ks], acc[0][0]);
        acc[0][1] = MFMA16(a0, wb1[ks], acc[0][1]);
        acc[1][0] = MFMA16(a1, wb0[ks], acc[1][0]);
        acc[1][1] = MFMA16(a1, wb1[ks], acc[1][1]);
        acc2[0][0] = MFMA16(a0, wc0[ks], acc2[0][0]);
        acc2[0][1] = MFMA16(a0, wc1[ks], acc2[0][1]);
        acc2[1][0] = MFMA16(a1, wc0[ks], acc2[1][0]);
        acc2[1][1] = MFMA16(a1, wc1[ks], acc2[1][1]);
      }
      __syncthreads();
    }
#pragma unroll
    for (int rf = 0; rf < 2; rf++)
#pragma unroll
      for (int g = 0; g < 4; g++)
#pragma unroll
        for (int qq = 0; qq < 4; qq++) {
          int row = m0 + 32 * rf + qq + 8 * g + 4 * hw;
          if (row < M) {
            HEh16[(size_t)row * 256 + col0] = (_Float16)acc[rf][0][4 * g + qq];
            HEh16[(size_t)row * 256 + col1] = (_Float16)acc[rf][1][4 * g + qq];
            HEt16[(size_t)row * 256 + col0] = (_Float16)acc2[rf][0][4 * g + qq];
            HEt16[(size_t)row * 256 + col1] = (_Float16)acc2[rf][1][4 * g + qq];
          }
        }
  }
}

extern "C" void kernel_launch(void* const* d_in, const int* in_sizes, int n_in,
                              void* d_out, int out_size, void* d_ws, size_t ws_size,
                              hipStream_t stream) {
  const float* entity = (const float*)d_in[0];
  const float* ea     = (const float*)d_in[1];
  const float* q      = (const float*)d_in[2];
  const float* noise  = (const float*)d_in[3];
  const float* W_pr1  = (const float*)d_in[4];
  const float* b_pr1  = (const float*)d_in[5];
  const float* W_pr2  = (const float*)d_in[6];
  const float* b_pr2  = (const float*)d_in[7];
  const float* sW0    = (const float*)d_in[8];
  const float* sb0    = (const float*)d_in[9];
  const float* sW1    = (const float*)d_in[10];
  const float* sb1    = (const float*)d_in[11];
  const float* pW1    = (const float*)d_in[12];
  const float* pb1    = (const float*)d_in[13];
  const float* pW2    = (const float*)d_in[14];
  const float* pb2    = (const float*)d_in[15];
  const void*  ei_raw = d_in[16];

  char* ws = (char*)d_ws;
  const size_t EDH = (size_t)E * D * 2;    // 102.4 MB f16 edge matrix
  const size_t NDH = (size_t)NV * D * 2;   // 25.6 MB f16 node matrix
  const size_t PAD = 64 * 256 * 2;         // OOB tile-read slack (32 KB)
  size_t off_b = 0;
  char* r0  = ws + off_b; off_b += EDH + PAD;        // ea16
  char* r1a = ws + off_b; off_b += EDH + PAD;        // tmp16
  char* r2  = ws + off_b; off_b += 2 * NDH + PAD;    // hsum16 -> HEh16|HEt16
  char* r3  = ws + off_b; off_b += NDH + PAD;        // hid16 -> agg16
  char* r4  = ws + off_b; off_b += NDH + PAD;        // ent16
  char* r5  = ws + off_b; off_b += NDH + PAD;        // out016
  char* r6  = ws + off_b; off_b += NDH + PAD;        // xsum16
  auto alloc_w = [&](int K) { _Float16* p = (_Float16*)(ws + off_b);
                              off_b += (size_t)K * 256 * 2; return p; };
  _Float16* Wpr1f = alloc_w(256);
  _Float16* Wpr2f = alloc_w(256);
  _Float16* sW0f  = alloc_w(512);
  _Float16* sW1f  = alloc_w(512);
  _Float16* Whehf = alloc_w(512);
  _Float16* Whetf = alloc_w(512);
  _Float16* Weaf  = alloc_w(256);
  float* rinv   = (float*)(ws + off_b); off_b += (size_t)NV * 4;
  float* degrev = (float*)(ws + off_b); off_b += (size_t)NV * 4;
  float* qW     = (float*)(ws + off_b); off_b += 1024;
  int*   ei32   = (int*)(ws + off_b);   off_b += (size_t)TWOE * 4;
  int*   eidA   = (int*)(ws + off_b);   off_b += (size_t)TWOE * 4;
  int*   srcA   = (int*)(ws + off_b);   off_b += (size_t)TWOE * 4;
  int*   offA   = (int*)(ws + off_b);   off_b += (size_t)(NV + 1) * 4;
  int*   deg    = (int*)(ws + off_b);   off_b += (size_t)NV * 4;
  int*   cursor = (int*)(ws + off_b);   off_b += (size_t)NV * 4;
  int*   flag   = (int*)(ws + off_b);   off_b += 64;

  // lifetime aliases
  _Float16* ea16   = (_Float16*)r0;          // projea byproduct -> gath/projedge
  _Float16* tmp16  = (_Float16*)r1a;         // projea -> gath_h
  _Float16* hsum16 = (_Float16*)r2;          // gath -> fuse0(in-place) -> agg1
  _Float16* HEh16  = (_Float16*)r2;          // fuse1 -> projedge (hsum dead)
  _Float16* HEt16  = (_Float16*)(r2 + NDH);
  _Float16* hid16  = (_Float16*)r3;          // gath -> fuse0 P1
  _Float16* agg16  = (_Float16*)r3;          // k_agg -> fuse1 P1 (hid dead)
  _Float16* ent16  = (_Float16*)r4;          // conv -> gath/fuse0 P2
  _Float16* out016 = (_Float16*)r5;          // fuse0 -> agg1/fuse1
  _Float16* xsum16 = (_Float16*)r6;          // gath -> fuse0 epi

  // ---- indices & CSR (deg/cursor zeroed inside k_convert) ----
  k_detect<<<1, 256, 0, stream>>>(ei_raw, flag);
  k_convert<<<(TWOE + 255) / 256, 256, 0, stream>>>(ei_raw, flag, ei32, deg, cursor);
  k_deg<<<(TWOE + 255) / 256, 256, 0, stream>>>(ei32, deg);
  k_scan<<<1, 1024, 0, stream>>>(deg, offA, rinv);
  k_fill<<<(TWOE + 255) / 256, 256, 0, stream>>>(ei32, offA, cursor, eidA, srcA);

  // ---- all weight preps + qW in one launch; entity f16 shadow ----
  k_wprep_all<<<dim3(16, 8), 256, 0, stream>>>(
      W_pr1, W_pr2, sW0, sW1, pW1, q, pb1,
      Wpr1f, Wpr2f, sW0f, sW1f, Whehf, Whetf, Weaf, qW);
  k_conv16<<<(NV * D / 8 + 255) / 256, 256, 0, stream>>>(entity, ent16, NV * D / 8);

  // ---- fused proj + ea16 conversion: tmp16, ea16 ----
  k_projea<<<E / 64, 256, 0, stream>>>(ea, Wpr1f, b_pr1, tmp16, ea16, E);

  // ---- merged gather: hsum16, hid16, xsum16, degrev ----
  k_gath_h<<<(NV + 7) / 8, 256, 0, stream>>>(
      ea16, tmp16, ent16, eidA, srcA, offA, hsum16, hid16, xsum16, degrev);

  // ---- fused ADDC + sage0 ----
  k_fuse0<<<(NV + 63) / 64, 256, 0, stream>>>(
      hid16, ent16, hsum16, xsum16, degrev, rinv, Wpr2f, b_pr2,
      sW0f, sb0, out016, NV);

  // ---- layer-1 aggregate ----
  k_agg<<<(NV + 7) / 8, 256, 0, stream>>>(out016, srcA, offA, hsum16, rinv, agg16);

  // ---- fused sage1 + HE2 ----
  k_fuse1<<<(NV + 63) / 64, 256, 0, stream>>>(
      out016, agg16, sW1f, sb1, Whehf, Whetf, HEh16, HEt16, NV);

  // ---- proj pass 2 fused with edge combine + sampling ----
  k_projedge<<<E / 64, 256, 0, stream>>>(
      ea16, Weaf, qW, HEh16, HEt16, ei32, pW2, pb2, noise, (float*)d_out);
}